// Round 19
// baseline (3267.709 us; speedup 1.0000x reference)
//
#include <hip/hip_runtime.h>
#include <hip/hip_bf16.h>

// GraphBertEncoder: T=32768 tokens, S=6, D=256, H=8 (hd=32), L=4.
// Round 19 (final): round-18 champion (3.18ms) + two low-risk upsides:
//  (1) mk_attn used only tc/32=128 blocks (half the GPU idle) -> 16 tokens/
//      block, 256 threads = (token, head, rowgroup of 3 q-rows), 2x grid.
//  (2) h1 stored in qkv's dead k-slot (cols 256..511, stride 768): per-token
//      ws 15360 -> 12288 B, enabling tc=8192 when ws >= 108.6MB (halves the
//      137-dispatch launch overhead). Falls back to tc=4096 = exact champion.

#define TB 4
#define NROW 24

typedef float f32x4 __attribute__((ext_vector_type(4)));
typedef short bfv8  __attribute__((ext_vector_type(8)));   // 8 bf16 = 4 VGPR

__device__ __forceinline__ float bf2f(__hip_bfloat16 v) { return __bfloat162float(v); }
__device__ __forceinline__ __hip_bfloat16 f2bf(float v) { return __float2bfloat16(v); }
__device__ __forceinline__ float bfs2f(short s) { return __uint_as_float(((unsigned)(unsigned short)s) << 16); }
__device__ __forceinline__ int swz(int row, int cb) { return row*512 + (cb ^ ((row & 7) << 4)); }
__device__ __forceinline__ float gelu_f(float v) { return 0.5f*v*(1.f + erff(v*0.70710678118654752f)); }
__device__ __forceinline__ float unpk(unsigned p, int hi) {
  return __uint_as_float(hi ? (p & 0xffff0000u) : (p << 16));
}

// packed-weight offsets (bf16 elements)
#define OWQ 0u
#define OWO 786432u
#define OW1 1048576u
#define OW2 2097152u
#define WS_ELEMS 3145728u      // weights: 6291456 bytes
#define RESOFF    6291456u     // res fp32 [1536][256] = 1572864 B
#define ACTOFF    7864320u

// ---------------------------------------------------------------------------
__global__ __launch_bounds__(256) void gb_prep_kernel(
    const float* __restrict__ Wqkv, const float* __restrict__ Wo,
    const float* __restrict__ W1,   const float* __restrict__ W2,
    __hip_bfloat16* __restrict__ ws)
{
  int fg   = blockIdx.x * 4 + (threadIdx.x >> 6);
  int lane = threadIdx.x & 63;
  int layer = fg / 1536, r = fg % 1536;
  const float* src; int K, N, fl; unsigned dstbase;
  if (r < 384)       { src = Wqkv + layer*196608; K = 256;  N = 768;  fl = r;       dstbase = OWQ + layer*196608u; }
  else if (r < 512)  { src = Wo   + layer*65536;  K = 256;  N = 256;  fl = r - 384; dstbase = OWO + layer*65536u;  }
  else if (r < 1024) { src = W1   + layer*262144; K = 256;  N = 1024; fl = r - 512; dstbase = OW1 + layer*262144u; }
  else               { src = W2   + layer*262144; K = 1024; N = 256;  fl = r - 1024;dstbase = OW2 + layer*262144u; }
  int nk = K >> 5;
  int nt = fl / nk, ks = fl % nk;
  int n  = nt*16 + (lane & 15);
  int k0 = ks*32 + (lane >> 4)*8;
  __align__(16) __hip_bfloat16 tmp[8];
  #pragma unroll
  for (int j = 0; j < 8; ++j) tmp[j] = f2bf(src[(size_t)(k0 + j)*N + n]);
  *(uint4*)(ws + dstbase + (unsigned)fl*512u + lane*8) = *(const uint4*)tmp;
}

// ---------------------------------------------------------------------------
// K-split GEMM, 4 n-tiles/wave (4-wave blocks). Peak ~112 regs. (mk_qkv)
template<int NKTOT, class LoadA>
__device__ __forceinline__ void gemm_ks(const __hip_bfloat16* __restrict__ p,
                                        LoadA loadA, f32x4 (&C)[4][2])
{
  const unsigned ST = 4u*(unsigned)NKTOT*512u;
  bfv8 B[3][4];
  bfv8 a[2][4];
  #pragma unroll
  for (int i = 0; i < 4; ++i) {
    C[i][0] = (f32x4){0.f,0.f,0.f,0.f};
    C[i][1] = (f32x4){0.f,0.f,0.f,0.f};
  }
  #pragma unroll
  for (int k = 0; k < 4; ++k) B[0][k] = *(const bfv8*)(p + k*512);
  {
    const __hip_bfloat16* q = p + ST;
    #pragma unroll
    for (int k = 0; k < 4; ++k) B[1][k] = *(const bfv8*)(q + k*512);
  }
  loadA(0, a);
  #pragma unroll
  for (int s = 0; s < 8; ++s) {
    if (s + 2 < 8) {
      const __hip_bfloat16* q = p + (unsigned)((s+2) & 3)*ST + (unsigned)((s+2) >> 2)*2048u;
      #pragma unroll
      for (int k = 0; k < 4; ++k) B[(s+2)%3][k] = *(const bfv8*)(q + k*512);
    }
    if (s == 4) loadA(1, a);
    #pragma unroll
    for (int k = 0; k < 4; ++k) {
      C[s&3][0] = __builtin_amdgcn_mfma_f32_16x16x32_bf16(a[0][k], B[s%3][k], C[s&3][0], 0,0,0);
      C[s&3][1] = __builtin_amdgcn_mfma_f32_16x16x32_bf16(a[1][k], B[s%3][k], C[s&3][1], 0,0,0);
    }
  }
}

// K-quarter streaming GEMM, 2 n-tiles/wave (8-wave blocks). Demand ~48 regs.
template<int NKTOT, class LoadA>
__device__ __forceinline__ void gemm_ksq(const __hip_bfloat16* __restrict__ p,
                                         LoadA loadA, f32x4 (&C)[2][2])
{
  const unsigned ST = 8u*(unsigned)NKTOT*512u;
  bfv8 a[2][2];
  #pragma unroll
  for (int i = 0; i < 2; ++i) {
    C[i][0] = (f32x4){0.f,0.f,0.f,0.f};
    C[i][1] = (f32x4){0.f,0.f,0.f,0.f};
  }
  #pragma unroll
  for (int q = 0; q < 4; ++q) {
    loadA(q, a);
    #pragma unroll
    for (int i = 0; i < 2; ++i) {
      const __hip_bfloat16* b = p + (unsigned)i*ST + (unsigned)q*1024u;
      bfv8 B0 = *(const bfv8*)(b);
      bfv8 B1 = *(const bfv8*)(b + 512);
      C[i][0] = __builtin_amdgcn_mfma_f32_16x16x32_bf16(a[0][0], B0, C[i][0], 0,0,0);
      C[i][1] = __builtin_amdgcn_mfma_f32_16x16x32_bf16(a[1][0], B0, C[i][1], 0,0,0);
      C[i][0] = __builtin_amdgcn_mfma_f32_16x16x32_bf16(a[0][1], B1, C[i][0], 0,0,0);
      C[i][1] = __builtin_amdgcn_mfma_f32_16x16x32_bf16(a[1][1], B1, C[i][1], 0,0,0);
    }
  }
}

// ---------------------------------------------------------------------------
// one-pass LayerNorm helper (register version, used only by fallback kernels)
__device__ __forceinline__ void ln24_norm(float* z, float* redbuf, float g, float b, int tid) {
  const int lane = tid & 63, wid = tid >> 6;
  float s1[NROW], s2[NROW];
  #pragma unroll
  for (int r = 0; r < NROW; ++r) { float v = z[r]; s1[r] = v; s2[r] = v*v; }
  #pragma unroll
  for (int off = 32; off; off >>= 1) {
    #pragma unroll
    for (int r = 0; r < NROW; ++r) {
      s1[r] += __shfl_down(s1[r], off, 64);
      s2[r] += __shfl_down(s2[r], off, 64);
    }
  }
  if (lane == 0) {
    #pragma unroll
    for (int r = 0; r < NROW; ++r) { redbuf[wid*48 + r] = s1[r]; redbuf[wid*48 + 24 + r] = s2[r]; }
  }
  __syncthreads();
  #pragma unroll
  for (int r = 0; r < NROW; ++r) {
    float S1 = redbuf[r] + redbuf[48+r] + redbuf[96+r] + redbuf[144+r];
    float S2 = redbuf[24+r] + redbuf[72+r] + redbuf[120+r] + redbuf[168+r];
    float m  = S1 * (1.0f/256.0f);
    float var = S2 * (1.0f/256.0f) - m*m;
    float iv = rsqrtf(var + 1e-5f);
    z[r] = (z[r] - m) * iv * g + b;
  }
  __syncthreads();
}

// ===========================================================================
// ============ multi-kernel path ============================================
// ===========================================================================

// embed: block = 4 tokens (24 rows). LDS-resident z + LDS-partial LN.
__global__ __launch_bounds__(256) void mk_embed(
    const float* __restrict__ x,
    const float* __restrict__ W_raw, const float* __restrict__ b_raw,
    const float* __restrict__ wl_emb, const float* __restrict__ pos_emb,
    const float* __restrict__ hop_emb,
    const float* __restrict__ ln_g, const float* __restrict__ ln_b,
    const float* __restrict__ W_res, const float* __restrict__ b_res,
    __hip_bfloat16* __restrict__ h0, float* __restrict__ res, int t0)
{
  __shared__ float xbuf[24][128];     // 12 KB
  __shared__ float zb[24][256];       // 24 KB
  __shared__ float part[2][24][8];
  __shared__ float stat[24][2];
  const int tid = threadIdx.x;
  const int bt  = blockIdx.x;

  for (int idx = tid; idx < 24*128; idx += 256) {
    int tt = idx / 768, rem = idx % 768;
    int s = rem >> 7, f = rem & 127;
    int t = t0 + bt*4 + tt, g = t >> 7, i = t & 127;
    int node;
    if (s < 2) node = i;
    else { int j = s - 2; node = (j < i) ? j : (j + 1); }
    xbuf[tt*6+s][f] = x[(g*128 + node)*128 + f];
  }
  __syncthreads();

  {
    float z[NROW];
    #pragma unroll
    for (int r = 0; r < NROW; ++r) z[r] = 0.f;
    #pragma unroll 2
    for (int f4 = 0; f4 < 32; ++f4) {
      float w0 = W_raw[(f4*4+0)*256 + tid];
      float w1 = W_raw[(f4*4+1)*256 + tid];
      float w2 = W_raw[(f4*4+2)*256 + tid];
      float w3 = W_raw[(f4*4+3)*256 + tid];
      #pragma unroll
      for (int r = 0; r < NROW; ++r) {
        float4 xv = *(const float4*)(&xbuf[r][f4*4]);
        z[r] += xv.x*w0 + xv.y*w1 + xv.z*w2 + xv.w*w3;
      }
    }
    float br  = b_raw[tid];
    float wl  = wl_emb[tid];
    float hp0 = hop_emb[5*256 + tid];
    float hp1 = hop_emb[511*256 + tid];
    float p[6];
    #pragma unroll
    for (int s = 0; s < 6; ++s) p[s] = pos_emb[s*256 + tid];
    #pragma unroll
    for (int r = 0; r < NROW; ++r) {
      int s = r % 6;
      zb[r][tid] = z[r] + br + p[s] + wl + ((s < 2) ? hp0 : hp1);
    }
  }
  __syncthreads();

  if (tid < 192) {
    int row = tid >> 3, seg = tid & 7;
    float s1 = 0.f, s2 = 0.f;
    #pragma unroll
    for (int i = 0; i < 32; ++i) {
      int col = seg*32 + ((i + tid) & 31);
      float v = zb[row][col];
      s1 += v; s2 += v*v;
    }
    part[0][row][seg] = s1; part[1][row][seg] = s2;
  }
  __syncthreads();
  if (tid < 24) {
    float S1 = 0.f, S2 = 0.f;
    #pragma unroll
    for (int k = 0; k < 8; ++k) { S1 += part[0][tid][k]; S2 += part[1][tid][k]; }
    float m = S1 * (1.0f/256.0f);
    float var = S2 * (1.0f/256.0f) - m*m;
    stat[tid][0] = m; stat[tid][1] = rsqrtf(var + 1e-5f);
  }
  __syncthreads();
  {
    float g = ln_g[tid], b = ln_b[tid];
    #pragma unroll
    for (int r = 0; r < NROW; ++r) {
      float v = (zb[r][tid] - stat[r][0]) * stat[r][1] * g + b;
      h0[(size_t)(bt*24 + r)*256 + tid] = f2bf(v);
    }
  }

  if (t0 + bt*4 < 256) {
    __syncthreads();
    for (int idx = tid; idx < 24*128; idx += 256) {
      int tt = idx / 768, rem = idx % 768;
      int s = rem >> 7, f = rem & 127;
      int t = t0 + bt*4 + tt;
      xbuf[tt*6+s][f] = x[(t*128 + s)*128 + f];
    }
    __syncthreads();
    float resv[NROW];
    float brr = b_res[tid];
    #pragma unroll
    for (int r = 0; r < NROW; ++r) resv[r] = brr;
    #pragma unroll 2
    for (int f4 = 0; f4 < 32; ++f4) {
      float w0 = W_res[(f4*4+0)*256 + tid];
      float w1 = W_res[(f4*4+1)*256 + tid];
      float w2 = W_res[(f4*4+2)*256 + tid];
      float w3 = W_res[(f4*4+3)*256 + tid];
      #pragma unroll
      for (int r = 0; r < NROW; ++r) {
        float4 xv = *(const float4*)(&xbuf[r][f4*4]);
        resv[r] += xv.x*w0 + xv.y*w1 + xv.z*w2 + xv.w*w3;
      }
    }
    #pragma unroll
    for (int r = 0; r < NROW; ++r)
      res[(size_t)((t0 + bt*4)*6 + r)*256 + tid] = resv[r];
  }
}

// stage 32x256 bf16 rows into swz LDS -- 256-thread version
__device__ __forceinline__ void stageA(const __hip_bfloat16* __restrict__ src,
                                       int row0, int stride, char* aT, int tid) {
  #pragma unroll
  for (int k = 0; k < 4; ++k) {
    int cid = tid + k*256;
    int row = cid >> 5, cc = cid & 31;
    uint4 v = *(const uint4*)(src + (size_t)(row0 + row)*stride + cc*8);
    *(uint4*)(aT + swz(row, cc*16)) = v;
  }
}
// 512-thread version
__device__ __forceinline__ void stageA512(const __hip_bfloat16* __restrict__ src,
                                          int row0, int stride, char* aT, int tid) {
  #pragma unroll
  for (int k = 0; k < 2; ++k) {
    int cid = tid + k*512;
    int row = cid >> 5, cc = cid & 31;
    uint4 v = *(const uint4*)(src + (size_t)(row0 + row)*stride + cc*8);
    *(uint4*)(aT + swz(row, cc*16)) = v;
  }
}

// qkv GEMM: 256 threads, M=32, N=768.
__global__ __launch_bounds__(256) void mk_qkv(
    const __hip_bfloat16* __restrict__ h, const __hip_bfloat16* __restrict__ Wf,
    const float* __restrict__ bqkv_l, __hip_bfloat16* __restrict__ qkv)
{
  __shared__ __align__(16) char aT[16384];
  const int tid = threadIdx.x;
  const int lane = tid & 63, wid = tid >> 6;
  const int l15 = lane & 15, l4 = lane >> 4;
  const int row0 = blockIdx.x * 32;

  stageA(h, row0, 256, aT, tid);
  __syncthreads();

  auto lA = [&](int kh, bfv8 (&a)[2][4]) {
    #pragma unroll
    for (int k = 0; k < 4; ++k) {
      a[0][k] = *(const bfv8*)(aT + swz(l15,      (kh*4 + k)*64 + l4*16));
      a[1][k] = *(const bfv8*)(aT + swz(16 + l15, (kh*4 + k)*64 + l4*16));
    }
  };

  #pragma unroll 1
  for (int sub = 0; sub < 3; ++sub) {
    f32x4 C[4][2];
    gemm_ks<8>(Wf + (unsigned)(sub*16 + wid)*8u*512u + lane*8, lA, C);
    #pragma unroll
    for (int i = 0; i < 4; ++i) {
      int col = sub*256 + (wid + i*4)*16 + l15;
      float bb = bqkv_l[col];
      #pragma unroll
      for (int j = 0; j < 4; ++j) {
        qkv[(size_t)(row0 + l4*4 + j)*768 + col]      = f2bf(C[i][0][j] + bb);
        qkv[(size_t)(row0 + 16 + l4*4 + j)*768 + col] = f2bf(C[i][1][j] + bb);
      }
    }
  }
}

// attention: 16 tokens/block, 256 threads = (token, head, rowgroup of 3 rows).
// 2x grid vs the old 32-token/256-thread version (which left half the GPU idle).
__global__ __launch_bounds__(256) void mk_attn(__hip_bfloat16* __restrict__ qkv)
{
  const int tid = threadIdx.x;
  const int tl = tid >> 4;           // token 0..15
  const int hh = (tid >> 1) & 7;     // head 0..7
  const int rg = tid & 1;            // row group: q rows rg*3 .. rg*3+2
  const size_t rowbase = (size_t)(blockIdx.x*16 + tl)*6;
  const int cb = hh*32;

  #pragma unroll 1
  for (int qi = 0; qi < 3; ++qi) {
    int q = rg*3 + qi;
    const __hip_bfloat16* qr = qkv + (rowbase + q)*768 + cb;
    bfv8 qv[4];
    #pragma unroll
    for (int p4 = 0; p4 < 4; ++p4) qv[p4] = *(const bfv8*)(qr + p4*8);
    float a[6]; float mx = -1e30f;
    #pragma unroll
    for (int sp = 0; sp < 6; ++sp) {
      const __hip_bfloat16* kr = qkv + (rowbase + sp)*768 + 256 + cb;
      float s = 0.f;
      #pragma unroll
      for (int p4 = 0; p4 < 4; ++p4) {
        bfv8 kv = *(const bfv8*)(kr + p4*8);
        #pragma unroll
        for (int j = 0; j < 8; ++j) s += bfs2f(qv[p4][j]) * bfs2f(kv[j]);
      }
      a[sp] = s * 0.17677669529663687f;
      mx = fmaxf(mx, a[sp]);
    }
    float sum = 0.f;
    #pragma unroll
    for (int sp = 0; sp < 6; ++sp) { a[sp] = __expf(a[sp] - mx); sum += a[sp]; }
    float inv = 1.f / sum;
    #pragma unroll
    for (int sp = 0; sp < 6; ++sp) a[sp] *= inv;
    float oc[32];
    #pragma unroll
    for (int j = 0; j < 32; ++j) oc[j] = 0.f;
    #pragma unroll
    for (int sp = 0; sp < 6; ++sp) {
      const __hip_bfloat16* vr = qkv + (rowbase + sp)*768 + 512 + cb;
      float asp = a[sp];
      #pragma unroll
      for (int p4 = 0; p4 < 4; ++p4) {
        bfv8 vv = *(const bfv8*)(vr + p4*8);
        #pragma unroll
        for (int j = 0; j < 8; ++j) oc[p4*8 + j] += asp * bfs2f(vv[j]);
      }
    }
    __hip_bfloat16* orow = qkv + (rowbase + q)*768 + cb;   // o over own q cols
    #pragma unroll
    for (int p4 = 0; p4 < 4; ++p4) {
      __align__(16) __hip_bfloat16 ob[8];
      #pragma unroll
      for (int j = 0; j < 8; ++j) ob[j] = f2bf(oc[p4*8 + j]);
      *(uint4*)(orow + p4*8) = *(const uint4*)ob;
    }
  }
}

// Wo GEMM + residual + LN1: 512 threads. h1 lives in qkv's k-slot
// (base = qkv + 256, row stride 768; k/v are dead after mk_attn).
__global__ __launch_bounds__(512) void mk_wo_ln(
    const __hip_bfloat16* __restrict__ qkv /* o at stride 768 */,
    const __hip_bfloat16* __restrict__ h,
    const float* __restrict__ res,
    const __hip_bfloat16* __restrict__ Wf, const float* __restrict__ bo_l,
    const float* __restrict__ gln, const float* __restrict__ bln,
    __hip_bfloat16* __restrict__ h1 /* = qkv + 256, stride 768 */, int t0)
{
  __shared__ __align__(16) char aT[16384];
  __shared__ float zb[32][256];
  __shared__ float part[2][32][16];
  __shared__ float stat[32][2];
  const int tid = threadIdx.x;
  const int lane = tid & 63, wid = tid >> 6;      // wid 0..7
  const int l15 = lane & 15, l4 = lane >> 4;
  const int row0 = blockIdx.x * 32;

  stageA512(qkv, row0, 768, aT, tid);
  __syncthreads();

  auto lAq = [&](int q, bfv8 (&a)[2][2]) {
    #pragma unroll
    for (int k = 0; k < 2; ++k) {
      a[0][k] = *(const bfv8*)(aT + swz(l15,      (q*2 + k)*64 + l4*16));
      a[1][k] = *(const bfv8*)(aT + swz(16 + l15, (q*2 + k)*64 + l4*16));
    }
  };

  {
    f32x4 C[2][2];
    gemm_ksq<8>(Wf + (unsigned)wid*8u*512u + lane*8, lAq, C);
    #pragma unroll
    for (int i = 0; i < 2; ++i) {
      int col = (wid + i*8)*16 + l15;
      #pragma unroll
      for (int j = 0; j < 4; ++j) {
        zb[l4*4 + j][col]      = C[i][0][j];
        zb[16 + l4*4 + j][col] = C[i][1][j];
      }
    }
  }
  __syncthreads();

  #pragma unroll 4
  for (int it = 0; it < 16; ++it) {
    int idx = tid + it*512, row = idx >> 8, col = idx & 255;
    float v = zb[row][col] + bf2f(h[(size_t)(row0 + row)*256 + col]) + bo_l[col];
    int grow = t0*6 + row0 + row;
    if (grow < 1536) v += res[(size_t)grow*256 + col];
    zb[row][col] = v;
  }
  __syncthreads();

  {
    int row = tid >> 4, seg = tid & 15;
    float s1 = 0.f, s2 = 0.f;
    #pragma unroll
    for (int i = 0; i < 16; ++i) {
      int col = seg*16 + ((i + tid) & 15);
      float v = zb[row][col];
      s1 += v; s2 += v*v;
    }
    part[0][row][seg] = s1; part[1][row][seg] = s2;
  }
  __syncthreads();
  if (tid < 32) {
    float S1 = 0.f, S2 = 0.f;
    #pragma unroll
    for (int k = 0; k < 16; ++k) { S1 += part[0][tid][k]; S2 += part[1][tid][k]; }
    float m = S1 * (1.0f/256.0f);
    float var = S2 * (1.0f/256.0f) - m*m;
    stat[tid][0] = m; stat[tid][1] = rsqrtf(var + 1e-5f);
  }
  __syncthreads();
  #pragma unroll 4
  for (int it = 0; it < 16; ++it) {
    int idx = tid + it*512, row = idx >> 8, col = idx & 255;
    float v = (zb[row][col] - stat[row][0]) * stat[row][1] * gln[col] + bln[col];
    h1[(size_t)(row0 + row)*768 + col] = f2bf(v);   // stride 768 (k-slot)
  }
}

// FFN fused + residual + LN2: 512 threads, spill-proof gemm_ksq.
// h1 read at stride 768 (qkv k-slot).
__global__ __launch_bounds__(512) void mk_ffn(
    const __hip_bfloat16* __restrict__ h1 /* = qkv + 256, stride 768 */,
    const __hip_bfloat16* __restrict__ W1f, const __hip_bfloat16* __restrict__ W2f,
    const float* __restrict__ b1_l, const float* __restrict__ b2_l,
    const float* __restrict__ gln, const float* __restrict__ bln,
    const float* __restrict__ res, __hip_bfloat16* __restrict__ hout,
    float* __restrict__ outp, int t0)
{
  __shared__ __align__(16) char aT[16384];
  __shared__ __align__(16) char gT[16384];
  __shared__ float ff[32][256];
  __shared__ float part[2][32][16];
  __shared__ float stat[32][2];
  const int tid = threadIdx.x;
  const int lane = tid & 63, wid = tid >> 6;      // wid 0..7
  const int l15 = lane & 15, l4 = lane >> 4;
  const int row0 = blockIdx.x * 32;

  stageA512(h1, row0, 768, aT, tid);
  #pragma unroll 4
  for (int it = 0; it < 16; ++it) {
    int idx = tid + it*512;
    ff[idx >> 8][idx & 255] = 0.f;
  }
  __syncthreads();

  auto lAq = [&](int q, bfv8 (&a)[2][2]) {
    #pragma unroll
    for (int k = 0; k < 2; ++k) {
      a[0][k] = *(const bfv8*)(aT + swz(l15,      (q*2 + k)*64 + l4*16));
      a[1][k] = *(const bfv8*)(aT + swz(16 + l15, (q*2 + k)*64 + l4*16));
    }
  };
  auto lGq = [&](int q, bfv8 (&a)[2][2]) {
    #pragma unroll
    for (int k = 0; k < 2; ++k) {
      a[0][k] = *(const bfv8*)(gT + swz(l15,      (q*2 + k)*64 + l4*16));
      a[1][k] = *(const bfv8*)(gT + swz(16 + l15, (q*2 + k)*64 + l4*16));
    }
  };

  #pragma unroll 1
  for (int ch = 0; ch < 4; ++ch) {
    {
      f32x4 C[2][2];
      gemm_ksq<8>(W1f + (unsigned)(ch*16 + wid)*8u*512u + lane*8, lAq, C);
      #pragma unroll
      for (int i = 0; i < 2; ++i) {
        int colR = (wid + i*8)*16 + l15;
        float bb = b1_l[ch*256 + colR];
        int col2 = colR*2;
        #pragma unroll
        for (int j = 0; j < 4; ++j) {
          *(__hip_bfloat16*)(gT + swz(l4*4 + j, col2))      = f2bf(gelu_f(C[i][0][j] + bb));
          *(__hip_bfloat16*)(gT + swz(16 + l4*4 + j, col2)) = f2bf(gelu_f(C[i][1][j] + bb));
        }
      }
    }
    __syncthreads();   // g visible
    {
      f32x4 C[2][2];
      gemm_ksq<32>(W2f + (unsigned)(wid*32 + ch*8)*512u + lane*8, lGq, C);
      #pragma unroll
      for (int i = 0; i < 2; ++i) {
        int col = (wid + i*8)*16 + l15;
        #pragma unroll
        for (int j = 0; j < 4; ++j) {
          ff[l4*4 + j][col]      += C[i][0][j];
          ff[16 + l4*4 + j][col] += C[i][1][j];
        }
      }
    }
    __syncthreads();   // g reads done
  }

  #pragma unroll 4
  for (int it = 0; it < 16; ++it) {
    int idx = tid + it*512, row = idx >> 8, col = idx & 255;
    float v = ff[row][col] + bf2f(h1[(size_t)(row0 + row)*768 + col]) + b2_l[col];
    int grow = t0*6 + row0 + row;
    if (grow < 1536) v += res[(size_t)grow*256 + col];
    ff[row][col] = v;
  }
  __syncthreads();
  {
    int row = tid >> 4, seg = tid & 15;
    float s1 = 0.f, s2 = 0.f;
    #pragma unroll
    for (int i = 0; i < 16; ++i) {
      int col = seg*16 + ((i + tid) & 15);
      float v = ff[row][col];
      s1 += v; s2 += v*v;
    }
    part[0][row][seg] = s1; part[1][row][seg] = s2;
  }
  __syncthreads();
  if (tid < 32) {
    float S1 = 0.f, S2 = 0.f;
    #pragma unroll
    for (int k = 0; k < 16; ++k) { S1 += part[0][tid][k]; S2 += part[1][tid][k]; }
    float m = S1 * (1.0f/256.0f);
    float var = S2 * (1.0f/256.0f) - m*m;
    stat[tid][0] = m; stat[tid][1] = rsqrtf(var + 1e-5f);
  }
  __syncthreads();
  #pragma unroll 4
  for (int it = 0; it < 16; ++it) {
    int idx = tid + it*512, row = idx >> 8, col = idx & 255;
    float v = (ff[row][col] - stat[row][0]) * stat[row][1] * gln[col] + bln[col];
    hout[(size_t)(row0 + row)*256 + col] = f2bf(v);
    if (outp && ((row0 + row) % 6 == 0)) {
      int gtok = t0 + (row0 + row) / 6;
      outp[(size_t)gtok*256 + col] = v;
    }
  }
}

// ===========================================================================
// ============ round-10 fused champion (fallback) ===========================
// ===========================================================================
__global__ __launch_bounds__(256, 2) void gb_mfma_kernel(
    const float* __restrict__ x,
    const float* __restrict__ W_raw, const float* __restrict__ b_raw,
    const float* __restrict__ wl_emb, const float* __restrict__ pos_emb,
    const float* __restrict__ hop_emb,
    const float* __restrict__ ln_g, const float* __restrict__ ln_b,
    const float* __restrict__ bqkv, const float* __restrict__ bo,
    const float* __restrict__ n1g,  const float* __restrict__ n1b,
    const float* __restrict__ b1,   const float* __restrict__ b2,
    const float* __restrict__ n2g,  const float* __restrict__ n2b,
    const float* __restrict__ W_res, const float* __restrict__ b_res,
    const __hip_bfloat16* __restrict__ wf,
    float* __restrict__ out)
{
  __shared__ __align__(16) char smem[75392];
  char* hsb = smem;
  char* uA  = smem + 16384;
  char* uB  = smem + 53632;
  float (*attw)[24][6] = (float (*)[24][6])(smem + 70016);
  float* redbuf = (float*)(smem + 74624);

  __hip_bfloat16 (*qkvs)[776] = (__hip_bfloat16 (*)[776])uA;
  float (*fbuf)[264] = (float (*)[264])uA;
  float (*xbuf)[128] = (float (*)[128])uA;

  const int tid  = threadIdx.x;
  const int bt   = blockIdx.x;
  const int lane = tid & 63, wid = tid >> 6;
  const int l15  = lane & 15, l4 = lane >> 4;

  auto mkA = [l15, l4](const char* buf) {
    return [buf, l15, l4](int kh, bfv8 (&a)[2][4]) {
      #pragma unroll
      for (int k = 0; k < 4; ++k) {
        a[0][k] = *(const bfv8*)(buf + swz(l15,      (kh*4 + k)*64 + l4*16));
        a[1][k] = *(const bfv8*)(buf + swz(16 + l15, (kh*4 + k)*64 + l4*16));
      }
    };
  };

  {
    uint4 zz = {0u,0u,0u,0u};
    *(uint4*)(hsb + 24*512 + tid*16) = zz;
    *(uint4*)(uB  + 24*512 + tid*16) = zz;
  }

  for (int idx = tid; idx < TB*6*128; idx += 256) {
    int tt = idx / 768, rem = idx % 768;
    int s = rem >> 7, f = rem & 127;
    int t = bt*TB + tt, g = t >> 7, i = t & 127;
    int node;
    if (s < 2) node = i;
    else { int j = s - 2; node = (j < i) ? j : (j + 1); }
    xbuf[tt*6+s][f] = x[(g*128 + node)*128 + f];
  }
  __syncthreads();

  {
    float z[NROW];
    #pragma unroll
    for (int r = 0; r < NROW; ++r) z[r] = 0.f;
    #pragma unroll 2
    for (int f4 = 0; f4 < 32; ++f4) {
      float w0 = W_raw[(f4*4+0)*256 + tid];
      float w1 = W_raw[(f4*4+1)*256 + tid];
      float w2 = W_raw[(f4*4+2)*256 + tid];
      float w3 = W_raw[(f4*4+3)*256 + tid];
      #pragma unroll
      for (int r = 0; r < NROW; ++r) {
        float4 xv = *(const float4*)(&xbuf[r][f4*4]);
        z[r] += xv.x*w0 + xv.y*w1 + xv.z*w2 + xv.w*w3;
      }
    }
    float br  = b_raw[tid];
    float wl  = wl_emb[tid];
    float hp0 = hop_emb[5*256 + tid];
    float hp1 = hop_emb[511*256 + tid];
    float p[6];
    #pragma unroll
    for (int s = 0; s < 6; ++s) p[s] = pos_emb[s*256 + tid];
    #pragma unroll
    for (int r = 0; r < NROW; ++r) {
      int s = r % 6;
      z[r] += br + p[s] + wl + ((s < 2) ? hp0 : hp1);
    }
    ln24_norm(z, redbuf, ln_g[tid], ln_b[tid], tid);
    #pragma unroll
    for (int r = 0; r < NROW; ++r)
      *(__hip_bfloat16*)(hsb + swz(r, tid*2)) = f2bf(z[r]);
  }

  unsigned resp[12];
  #pragma unroll
  for (int k = 0; k < 12; ++k) resp[k] = 0u;
  if (bt < 64) {
    __syncthreads();
    for (int idx = tid; idx < TB*6*128; idx += 256) {
      int tt = idx / 768, rem = idx % 768;
      int s = rem >> 7, f = rem & 127;
      int t = bt*TB + tt;
      xbuf[tt*6+s][f] = x[(t*128 + s)*128 + f];
    }
    __syncthreads();
    float resv[NROW];
    float brr = b_res[tid];
    #pragma unroll
    for (int r = 0; r < NROW; ++r) resv[r] = brr;
    #pragma unroll 2
    for (int f4 = 0; f4 < 32; ++f4) {
      float w0 = W_res[(f4*4+0)*256 + tid];
      float w1 = W_res[(f4*4+1)*256 + tid];
      float w2 = W_res[(f4*4+2)*256 + tid];
      float w3 = W_res[(f4*4+3)*256 + tid];
      #pragma unroll
      for (int r = 0; r < NROW; ++r) {
        float4 xv = *(const float4*)(&xbuf[r][f4*4]);
        resv[r] += xv.x*w0 + xv.y*w1 + xv.z*w2 + xv.w*w3;
      }
    }
    #pragma unroll
    for (int k = 0; k < 12; ++k) {
      unsigned lo = __float_as_uint(resv[2*k])   >> 16;
      unsigned hi = __float_as_uint(resv[2*k+1]) & 0xffff0000u;
      resp[k] = hi | lo;
    }
  }

  float z[NROW];

  #pragma unroll 1
  for (int l = 0; l < 4; ++l) {
    const __hip_bfloat16* WQf = wf + OWQ + (unsigned)l*196608u;
    const __hip_bfloat16* WOf = wf + OWO + (unsigned)l*65536u;
    const __hip_bfloat16* W1f = wf + OW1 + (unsigned)l*262144u;
    const __hip_bfloat16* W2f = wf + OW2 + (unsigned)l*262144u;

    __syncthreads();

    {
      auto lA = mkA(hsb);
      #pragma unroll 1
      for (int sub = 0; sub < 3; ++sub) {
        f32x4 C[4][2];
        gemm_ks<8>(WQf + (unsigned)(sub*16 + wid)*8u*512u + lane*8, lA, C);
        #pragma unroll
        for (int i = 0; i < 4; ++i) {
          int gcol = sub*256 + (wid + i*4)*16 + l15;
          float bbv = bqkv[l*768 + gcol];
          #pragma unroll
          for (int j = 0; j < 4; ++j) {
            qkvs[l4*4 + j][gcol] = f2bf(C[i][0][j] + bbv);
            int r1 = 16 + l4*4 + j;
            if (r1 < NROW) qkvs[r1][gcol] = f2bf(C[i][1][j] + bbv);
          }
        }
      }
    }
    __syncthreads();

    if (tid < 192) {
      int hh = tid / 24, r = tid % 24;
      int tt6 = (r / 6) * 6;
      bfv8 qv[4];
      #pragma unroll
      for (int p4 = 0; p4 < 4; ++p4) qv[p4] = *(const bfv8*)(&qkvs[r][hh*32 + p4*8]);
      float sc[6];
      #pragma unroll
      for (int sp = 0; sp < 6; ++sp) {
        float s = 0.f;
        #pragma unroll
        for (int p4 = 0; p4 < 4; ++p4) {
          bfv8 kv = *(const bfv8*)(&qkvs[tt6 + sp][256 + hh*32 + p4*8]);
          #pragma unroll
          for (int j = 0; j < 8; ++j) s += bfs2f(qv[p4][j]) * bfs2f(kv[j]);
        }
        sc[sp] = s * 0.17677669529663687f;
      }
      float mx = sc[0];
      #pragma unroll
      for (int sp = 1; sp < 6; ++sp) mx = fmaxf(mx, sc[sp]);
      float sum = 0.f;
      #pragma unroll
      for (int sp = 0; sp < 6; ++sp) { sc[sp] = __expf(sc[sp] - mx); sum += sc[sp]; }
      float inv = 1.f / sum;
      #pragma unroll
      for (int sp = 0; sp < 6; ++sp) attw[hh][r][sp] = sc[sp] * inv;
    }
    __syncthreads();

    {
      int hh = tid >> 5, c = tid & 31;
      int col2 = (hh*32 + c)*2;
      #pragma unroll
      for (int tt = 0; tt < 4; ++tt) {
        float vv[6];
        #pragma unroll
        for (int sp = 0; sp < 6; ++sp) vv[sp] = bf2f(qkvs[tt*6 + sp][512 + hh*32 + c]);
        #pragma unroll
        for (int q = 0; q < 6; ++q) {
          float o = 0.f;
          #pragma unroll
          for (int sp = 0; sp < 6; ++sp) o += attw[hh][tt*6 + q][sp] * vv[sp];
          *(__hip_bfloat16*)(uB + swz(tt*6 + q, col2)) = f2bf(o);
        }
      }
    }
    __syncthreads();

    {
      f32x4 C[4][2];
      gemm_ks<8>(WOf + (unsigned)wid*8u*512u + lane*8, mkA(uB), C);
      #pragma unroll
      for (int i = 0; i < 4; ++i) {
        int col = (wid + i*4)*16 + l15;
        #pragma unroll
        for (int j = 0; j < 4; ++j) {
          fbuf[l4*4 + j][col] = C[i][0][j];
          int r1 = 16 + l4*4 + j;
          if (r1 < NROW) fbuf[r1][col] = C[i][1][j];
        }
      }
    }
    __syncthreads();

    {
      float bov = bo[l*256 + tid];
      #pragma unroll
      for (int r = 0; r < NROW; ++r)
        z[r] = bf2f(*(const __hip_bfloat16*)(hsb + swz(r, tid*2)))
             + unpk(resp[r >> 1], r & 1) + fbuf[r][tid] + bov;
    }
    #pragma unroll
    for (int k = 0; k < 12; ++k) *(unsigned*)(uB + (k*256 + tid)*4) = 0u;
    ln24_norm(z, redbuf, n1g[l*256 + tid], n1b[l*256 + tid], tid);
    #pragma unroll
    for (int r = 0; r < NROW; ++r)
      *(__hip_bfloat16*)(hsb + swz(r, tid*2)) = f2bf(z[r]);
    {
      uint4 zz = {0u,0u,0u,0u};
      *(uint4*)(uA + 24*512 + tid*16) = zz;
      *(uint4*)(uA + 16384 + 24*512 + tid*16) = zz;
    }
    __syncthreads();

    {
      auto lAh = mkA(hsb);
      #pragma unroll 1
      for (int ch = 0; ch < 4; ++ch) {
        char* gb = uA + (ch & 1)*16384;
        {
          f32x4 C[4][2];
          gemm_ks<8>(W1f + (unsigned)(ch*128 + wid*8)*512u + lane*8, lAh, C);
          #pragma unroll
          for (int i = 0; i < 4; ++i) {
            float bbv = b1[l*1024 + ch*256 + (wid + i*4)*16 + l15];
            int col2 = ((wid + i*4)*16 + l15)*2;
            #pragma unroll
            for (int j = 0; j < 4; ++j) {
              *(__hip_bfloat16*)(gb + swz(l4*4 + j, col2)) = f2bf(gelu_f(C[i][0][j] + bbv));
              int r1 = 16 + l4*4 + j;
              if (r1 < NROW)
                *(__hip_bfloat16*)(gb + swz(r1, col2)) = f2bf(gelu_f(C[i][1][j] + bbv));
            }
          }
        }
        __syncthreads();
        {
          f32x4 C[4][2];
          gemm_ks<32>(W2f + (unsigned)(wid*32 + ch*8)*512u + lane*8, mkA(gb), C);
          #pragma unroll
          for (int i = 0; i < 4; ++i) {
            int col2 = ((wid + i*4)*16 + l15)*2;
            #pragma unroll
            for (int j = 0; j < 4; ++j) {
              {
                __hip_bfloat16* pp = (__hip_bfloat16*)(uB + (l4*4 + j)*512 + col2);
                *pp = f2bf(bf2f(*pp) + C[i][0][j]);
              }
              int r1 = 16 + l4*4 + j;
              if (r1 < NROW) {
                __hip_bfloat16* pp = (__hip_bfloat16*)(uB + r1*512 + col2);
                *pp = f2bf(bf2f(*pp) + C[i][1][j]);
              }
            }
          }
        }
      }
    }
    __syncthreads();

    {
      float b2v = b2[l*256 + tid];
      #pragma unroll
      for (int r = 0; r < NROW; ++r)
        z[r] = bf2f(*(const __hip_bfloat16*)(hsb + swz(r, tid*2)))
             + unpk(resp[r >> 1], r & 1)
             + bf2f(*(const __hip_bfloat16*)(uB + r*512 + tid*2)) + b2v;
    }
    ln24_norm(z, redbuf, n2g[l*256 + tid], n2b[l*256 + tid], tid);
    #pragma unroll
    for (int r = 0; r < NROW; ++r)
      *(__hip_bfloat16*)(hsb + swz(r, tid*2)) = f2bf(z[r]);
  }

  #pragma unroll
  for (int tt = 0; tt < TB; ++tt)
    out[(bt*TB + tt)*256 + tid] = z[tt*6];
}

// ---------------------------------------------------------------------------
// Pure-VALU fallback (round-2 proven).
__global__ __launch_bounds__(256, 2) void gb_fused_fallback(
    const float* __restrict__ x,
    const float* __restrict__ W_raw, const float* __restrict__ b_raw,
    const float* __restrict__ wl_emb, const float* __restrict__ pos_emb,
    const float* __restrict__ hop_emb,
    const float* __restrict__ ln_g, const float* __restrict__ ln_b,
    const float* __restrict__ Wqkv, const float* __restrict__ bqkv,
    const float* __restrict__ Wo,   const float* __restrict__ bo,
    const float* __restrict__ n1g,  const float* __restrict__ n1b,
    const float* __restrict__ W1,   const float* __restrict__ b1,
    const float* __restrict__ W2,   const float* __restrict__ b2,
    const float* __restrict__ n2g,  const float* __restrict__ n2b,
    const float* __restrict__ W_res, const float* __restrict__ b_res,
    float* __restrict__ out)
{
  __shared__ float hs[NROW][256];
  __shared__ __align__(16) char bufraw[NROW*768*2];
  __shared__ float attw[8][NROW][8];
  __shared__ float redbuf[192];

  __hip_bfloat16 (*qkvs)[768] = (__hip_bfloat16 (*)[768])bufraw;
  float (*fbuf)[256] = (float (*)[256])bufraw;
  float (*xbuf)[128] = (float (*)[128])bufraw;

  const int tid = threadIdx.x;
  const int bt  = blockIdx.x;

  for (int idx = tid; idx < TB*6*128; idx += 256) {
    int tt = idx / 768, rem = idx % 768;
    int s = rem >> 7, f = rem & 127;
    int t = bt*TB + tt, g = t >> 7, i = t & 127;
    int node;
    if (s < 2) node = i;
    else { int j = s - 2; node = (j < i) ? j : (j + 1); }
    xbuf[tt*6+s][f] = x[(g*128 + node)*128 + f];
  }
  __syncthreads();

  float z[NROW];
  {
    #pragma unroll
    for (int r = 0; r < NROW; ++r) z[r] = 0.f;
    #pragma unroll 4
    for (int f = 0; f < 128; ++f) {
      float w = W_raw[f*256 + tid];
      #pragma unroll
      for (int r = 0; r < NROW; ++r) z[r] += xbuf[r][f] * w;
    }
    float br  = b_raw[tid];
    float wl  = wl_emb[tid];
    float hp0 = hop_emb[5*256 + tid];
    float hp1 = hop_emb[511*256 + tid];
    float p[6];
    #pragma unroll
    for (int s = 0; s < 6; ++s) p[s] = pos_emb[s*256 + tid];
    #pragma unroll
    for (int r = 0; r < NROW; ++r) {
      int s = r % 6;
      z[r] += br + p[s] + wl + ((s < 2) ? hp0 : hp1);
    }
  }
  ln24_norm(z, redbuf, ln_g[tid], ln_b[tid], tid);
  #pragma unroll
  for (int r = 0; r < NROW; ++r) hs[r][tid] = z[r];

  float resv[NROW];
  #pragma unroll
  for (int r = 0; r < NROW; ++r) resv[r] = 0.f;
  if (bt < 64) {
    __syncthreads();
    for (int idx = tid; idx < TB*6*128; idx += 256) {
      int tt = idx / 768, rem = idx % 768;
      int s = rem >> 7, f = rem & 127;
      int t = bt*TB + tt;
      xbuf[tt*6+s][f] = x[(t*128 + s)*128 + f];
    }
    __syncthreads();
    #pragma unroll 4
    for (int f = 0; f < 128; ++f) {
      float w = W_res[f*256 + tid];
      #pragma unroll
      for (int r = 0; r < NROW; ++r) resv[r] += xbuf[r][f] * w;
    }
    float brr = b_res[tid];
    #pragma unroll
    for (int r = 0; r < NROW; ++r) resv[r] += brr;
  }

  for (int l = 0; l < 4; ++l) {
    const float* Wqkv_l = Wqkv + l*196608;
    const float* bqkv_l = bqkv + l*768;
    const float* Wo_l   = Wo   + l*65536;
    const float* bo_l   = bo   + l*256;
    const float* W1_l   = W1   + l*262144;
    const float* b1_l   = b1   + l*1024;
    const float* W2_l   = W2   + l*262144;
    const float* b2_l   = b2   + l*256;

    __syncthreads();

    for (int cg = 0; cg < 3; ++cg) {
      int col = cg*256 + tid;
      float acc[NROW];
      #pragma unroll
      for (int r = 0; r < NROW; ++r) acc[r] = 0.f;
      #pragma unroll 4
      for (int kk = 0; kk < 256; ++kk) {
        float w = Wqkv_l[kk*768 + col];
        #pragma unroll
        for (int r = 0; r < NROW; ++r) acc[r] += hs[r][kk] * w;
      }
      float bbv = bqkv_l[col];
      #pragma unroll
      for (int r = 0; r < NROW; ++r) qkvs[r][col] = f2bf(acc[r] + bbv);
    }
    __syncthreads();

    #pragma unroll 1
    for (int it = 0; it < 5; ++it) {
      int idx = it*256 + tid;
      if (idx < 1152) {
        int hh = idx / 144, rem = idx % 144;
        int r = rem / 6, sp = rem % 6;
        int tt6 = (r / 6) * 6;
        float sc = 0.f;
        #pragma unroll
        for (int c = 0; c < 32; ++c)
          sc += bf2f(qkvs[r][hh*32 + c]) * bf2f(qkvs[tt6 + sp][256 + hh*32 + c]);
        attw[hh][r][sp] = sc * 0.17677669529663687f;
      }
    }
    __syncthreads();

    if (tid < 192) {
      int hh = tid / 24, r = tid % 24;
      float mx = attw[hh][r][0];
      #pragma unroll
      for (int sp = 1; sp < 6; ++sp) mx = fmaxf(mx, attw[hh][r][sp]);
      float e[6], sum = 0.f;
      #pragma unroll
      for (int sp = 0; sp < 6; ++sp) { e[sp] = expf(attw[hh][r][sp] - mx); sum += e[sp]; }
      float inv = 1.f / sum;
      #pragma unroll
      for (int sp = 0; sp < 6; ++sp) attw[hh][r][sp] = e[sp] * inv;
    }
    __syncthreads();

    float oreg[NROW];
    {
      int hh = tid >> 5, c = tid & 31;
      #pragma unroll
      for (int r = 0; r < NROW; ++r) {
        int tt6 = (r / 6) * 6;
        float o = 0.f;
        #pragma unroll
        for (int sp = 0; sp < 6; ++sp)
          o += attw[hh][r][sp] * bf2f(qkvs[tt6 + sp][512 + hh*32 + c]);
        oreg[r] = o;
      }
    }
    __syncthreads();
    #pragma unroll
    for (int r = 0; r < NROW; ++r) fbuf[r][tid] = oreg[r];
    __syncthreads();

    {
      float bod = bo_l[tid];
      float zz[NROW];
      #pragma unroll
      for (int r = 0; r < NROW; ++r) zz[r] = bod;
      #pragma unroll 4
      for (int kk = 0; kk < 256; ++kk) {
        float w = Wo_l[kk*256 + tid];
        #pragma unroll
        for (int r = 0; r < NROW; ++r) zz[r] += fbuf[r][kk] * w;
      }
      #pragma unroll
      for (int r = 0; r < NROW; ++r) z[r] += zz[r] + resv[r];
    }
    ln24_norm(z, redbuf, n1g[l*256 + tid], n1b[l*256 + tid], tid);
    #pragma unroll
    for (int r = 0; r < NROW; ++r) hs[r][tid] = z[r];
    __syncthreads();

    float ffv[NROW];
    {
      float b2d = b2_l[tid];
      #pragma unroll
      for (int r = 0; r < NROW; ++r) ffv[r] = b2d;
    }
    for (int ch = 0; ch < 4; ++ch) {
      int j = ch*256 + tid;
      float gvv[NROW];
      float b1j = b1_l[j];
      #pragma unroll
      for (int r = 0; r < NROW; ++r) gvv[r] = b1j;
      #pragma unroll 4
      for (int kk = 0; kk < 256; ++kk) {
        float w = W1_l[kk*1024 + j];
        #pragma unroll
        for (int r = 0; r < NROW; ++r) gvv[r] += hs[r][kk] * w;
      }
      __syncthreads();
      #pragma unroll
      for (int r = 0; r < NROW; ++r) fbuf[r][tid] = gelu_f(gvv[r]);
      __syncthreads();
      #pragma unroll 4
      for (int kk = 0; kk < 256; ++kk) {
        float w = W2_l[(ch*256 + kk)*256 + tid];
        #pragma unroll
        for (int r = 0; r < NROW; ++r) ffv[r] += fbuf[r][kk] * w;
      }
    }
    #pragma unroll
    for (int r = 0; r < NROW; ++r) z[r] += ffv[r] + resv[r];
    ln24_norm(z, redbuf, n2g[l*256 + tid], n2b[l*256 + tid], tid);
    #pragma unroll
    for (int r = 0; r < NROW; ++r) hs[r][tid] = z[r];
  }

  __syncthreads();
  #pragma unroll
  for (int tt = 0; tt < TB; ++tt)
    out[(bt*TB + tt)*256 + tid] = hs[tt*6][tid];
}

// ===========================================================================
extern "C" void kernel_launch(void* const* d_in, const int* in_sizes, int n_in,
                              void* d_out, int out_size, void* d_ws, size_t ws_size,
                              hipStream_t stream) {
  (void)in_sizes; (void)n_in; (void)out_size;
  const float* x      = (const float*)d_in[0];
  const float* W_raw  = (const float*)d_in[1];
  const float* b_raw  = (const float*)d_in[2];
  const float* wl_emb = (const float*)d_in[3];
  const float* pos_emb= (const float*)d_in[4];
  const float* hop_emb= (const float*)d_in[5];
  const float* ln_g   = (const float*)d_in[6];
  const float* ln_b   = (const float*)d_in[7];
  const float* Wqkv   = (const float*)d_in[8];
  const float* bqkv   = (const float*)d_in[9];
  const float* Wo     = (const float*)d_in[10];
  const float* bo     = (const float*)d_in[11];
  const float* n1g    = (const float*)d_in[12];
  const float* n1b    = (const float*)d_in[13];
  const float* W1     = (const float*)d_in[14];
  const float* b1     = (const float*)d_in[15];
  const float* W2     = (const float*)d_in[16];
  const float* b2     = (const float*)d_in[17];
  const float* n2g    = (const float*)d_in[18];
  const float* n2b    = (const float*)d_in[19];
  const float* W_res  = (const float*)d_in[20];
  const float* b_res  = (const float*)d_in[21];

  // per-token activation bytes: h0 (6*512) + qkv (6*1536, h1 lives in k-slot)
  int tc = 0;
  for (int cand = 32768; cand >= 4096; cand >>= 1) {
    size_t need = (size_t)ACTOFF + (size_t)cand * 12288u;
    if (ws_size >= need) { tc = cand; break; }
  }

  if (tc > 0) {
    char* wsb = (char*)d_ws;
    __hip_bfloat16* wf  = (__hip_bfloat16*)wsb;
    float*          res = (float*)(wsb + RESOFF);
    __hip_bfloat16* h0  = (__hip_bfloat16*)(wsb + ACTOFF);
    __hip_bfloat16* qkv = (__hip_bfloat16*)(wsb + ACTOFF + (size_t)tc*6*512);
    __hip_bfloat16* h1  = qkv + 256;     // k-slot, stride 768
    float* outp = (float*)d_out;

    gb_prep_kernel<<<1536, 256, 0, stream>>>(Wqkv, Wo, W1, W2, wf);

    int nchunk = 32768 / tc;
    for (int c = 0; c < nchunk; ++c) {
      int t0 = c * tc;
      mk_embed<<<tc/4, 256, 0, stream>>>(x, W_raw, b_raw, wl_emb, pos_emb,
          hop_emb, ln_g, ln_b, W_res, b_res, h0, res, t0);
      for (int l = 0; l < 4; ++l) {
        mk_qkv<<<tc*6/32, 256, 0, stream>>>(
            h0, wf + OWQ + (unsigned)l*196608u, bqkv + l*768, qkv);
        mk_attn<<<tc/16, 256, 0, stream>>>(qkv);
        mk_wo_ln<<<tc*6/32, 512, 0, stream>>>(
            qkv, h0, res, wf + OWO + (unsigned)l*65536u, bo + l*256,
            n1g + l*256, n1b + l*256, h1, t0);
        mk_ffn<<<tc*6/32, 512, 0, stream>>>(
            h1, wf + OW1 + (unsigned)l*262144u, wf + OW2 + (unsigned)l*262144u,
            b1 + l*1024, b2 + l*256, n2g + l*256, n2b + l*256,
            res, h0, (l == 3) ? outp : (float*)nullptr, t0);
      }
    }
  } else if (ws_size >= (size_t)WS_ELEMS * 2) {
    __hip_bfloat16* wsb = (__hip_bfloat16*)d_ws;
    gb_prep_kernel<<<1536, 256, 0, stream>>>(Wqkv, Wo, W1, W2, wsb);
    gb_mfma_kernel<<<8192, 256, 0, stream>>>(
        x, W_raw, b_raw, wl_emb, pos_emb, hop_emb, ln_g, ln_b,
        bqkv, bo, n1g, n1b, b1, b2, n2g, n2b, W_res, b_res,
        wsb, (float*)d_out);
  } else {
    gb_fused_fallback<<<8192, 256, 0, stream>>>(
        x, W_raw, b_raw, wl_emb, pos_emb, hop_emb, ln_g, ln_b,
        Wqkv, bqkv, Wo, bo, n1g, n1b, W1, b1, W2, b2, n2g, n2b,
        W_res, b_res, (float*)d_out);
  }
}

// Round 20
// 3196.848 us; speedup vs baseline: 1.0222x; 1.0222x over previous
//
#include <hip/hip_runtime.h>
#include <hip/hip_bf16.h>

// GraphBertEncoder: T=32768 tokens, S=6, D=256, H=8 (hd=32), L=4.
// FINAL (round-18 champion, 3.177ms, 8.3x over baseline): layer-outer
// multi-kernel. prep packs GEMM weights bf16 fragment-linear into d_ws;
// per 4096-token chunk: mk_embed -> 4x (mk_qkv, mk_attn, mk_wo_ln, mk_ffn).
// All GEMM kernels sized so register demand <= the allocator's observed
// VGPR choice (spill-proof by construction; r14-r17 showed no attribute
// reliably raises the allocation). Fallbacks: fused single-kernel (6.43ms)
// if ws only fits weights; pure-VALU if ws unavailable.

#define TB 4
#define NROW 24

typedef float f32x4 __attribute__((ext_vector_type(4)));
typedef short bfv8  __attribute__((ext_vector_type(8)));   // 8 bf16 = 4 VGPR

__device__ __forceinline__ float bf2f(__hip_bfloat16 v) { return __bfloat162float(v); }
__device__ __forceinline__ __hip_bfloat16 f2bf(float v) { return __float2bfloat16(v); }
__device__ __forceinline__ float bfs2f(short s) { return __uint_as_float(((unsigned)(unsigned short)s) << 16); }
__device__ __forceinline__ int swz(int row, int cb) { return row*512 + (cb ^ ((row & 7) << 4)); }
__device__ __forceinline__ float gelu_f(float v) { return 0.5f*v*(1.f + erff(v*0.70710678118654752f)); }
__device__ __forceinline__ float unpk(unsigned p, int hi) {
  return __uint_as_float(hi ? (p & 0xffff0000u) : (p << 16));
}

// packed-weight offsets (bf16 elements)
#define OWQ 0u
#define OWO 786432u
#define OW1 1048576u
#define OW2 2097152u
#define WS_ELEMS 3145728u      // weights: 6291456 bytes
#define RESOFF    6291456u     // res fp32 [1536][256] = 1572864 B
#define ACTOFF    7864320u

// ---------------------------------------------------------------------------
__global__ __launch_bounds__(256) void gb_prep_kernel(
    const float* __restrict__ Wqkv, const float* __restrict__ Wo,
    const float* __restrict__ W1,   const float* __restrict__ W2,
    __hip_bfloat16* __restrict__ ws)
{
  int fg   = blockIdx.x * 4 + (threadIdx.x >> 6);
  int lane = threadIdx.x & 63;
  int layer = fg / 1536, r = fg % 1536;
  const float* src; int K, N, fl; unsigned dstbase;
  if (r < 384)       { src = Wqkv + layer*196608; K = 256;  N = 768;  fl = r;       dstbase = OWQ + layer*196608u; }
  else if (r < 512)  { src = Wo   + layer*65536;  K = 256;  N = 256;  fl = r - 384; dstbase = OWO + layer*65536u;  }
  else if (r < 1024) { src = W1   + layer*262144; K = 256;  N = 1024; fl = r - 512; dstbase = OW1 + layer*262144u; }
  else               { src = W2   + layer*262144; K = 1024; N = 256;  fl = r - 1024;dstbase = OW2 + layer*262144u; }
  int nk = K >> 5;
  int nt = fl / nk, ks = fl % nk;
  int n  = nt*16 + (lane & 15);
  int k0 = ks*32 + (lane >> 4)*8;
  __align__(16) __hip_bfloat16 tmp[8];
  #pragma unroll
  for (int j = 0; j < 8; ++j) tmp[j] = f2bf(src[(size_t)(k0 + j)*N + n]);
  *(uint4*)(ws + dstbase + (unsigned)fl*512u + lane*8) = *(const uint4*)tmp;
}

// ---------------------------------------------------------------------------
// K-split GEMM, 4 n-tiles/wave (4-wave blocks). Peak ~112 regs. (mk_qkv)
template<int NKTOT, class LoadA>
__device__ __forceinline__ void gemm_ks(const __hip_bfloat16* __restrict__ p,
                                        LoadA loadA, f32x4 (&C)[4][2])
{
  const unsigned ST = 4u*(unsigned)NKTOT*512u;
  bfv8 B[3][4];
  bfv8 a[2][4];
  #pragma unroll
  for (int i = 0; i < 4; ++i) {
    C[i][0] = (f32x4){0.f,0.f,0.f,0.f};
    C[i][1] = (f32x4){0.f,0.f,0.f,0.f};
  }
  #pragma unroll
  for (int k = 0; k < 4; ++k) B[0][k] = *(const bfv8*)(p + k*512);
  {
    const __hip_bfloat16* q = p + ST;
    #pragma unroll
    for (int k = 0; k < 4; ++k) B[1][k] = *(const bfv8*)(q + k*512);
  }
  loadA(0, a);
  #pragma unroll
  for (int s = 0; s < 8; ++s) {
    if (s + 2 < 8) {
      const __hip_bfloat16* q = p + (unsigned)((s+2) & 3)*ST + (unsigned)((s+2) >> 2)*2048u;
      #pragma unroll
      for (int k = 0; k < 4; ++k) B[(s+2)%3][k] = *(const bfv8*)(q + k*512);
    }
    if (s == 4) loadA(1, a);
    #pragma unroll
    for (int k = 0; k < 4; ++k) {
      C[s&3][0] = __builtin_amdgcn_mfma_f32_16x16x32_bf16(a[0][k], B[s%3][k], C[s&3][0], 0,0,0);
      C[s&3][1] = __builtin_amdgcn_mfma_f32_16x16x32_bf16(a[1][k], B[s%3][k], C[s&3][1], 0,0,0);
    }
  }
}

// K-quarter streaming GEMM, 2 n-tiles/wave (8-wave blocks). Demand ~48 regs:
// a[2][2]=16 (reloaded per K-quarter from LDS), B streamed 2 frags (8),
// C[2][2]=16. Spill-proof at the allocator's observed 52-VGPR choice.
template<int NKTOT, class LoadA>
__device__ __forceinline__ void gemm_ksq(const __hip_bfloat16* __restrict__ p,
                                         LoadA loadA, f32x4 (&C)[2][2])
{
  const unsigned ST = 8u*(unsigned)NKTOT*512u;
  bfv8 a[2][2];
  #pragma unroll
  for (int i = 0; i < 2; ++i) {
    C[i][0] = (f32x4){0.f,0.f,0.f,0.f};
    C[i][1] = (f32x4){0.f,0.f,0.f,0.f};
  }
  #pragma unroll
  for (int q = 0; q < 4; ++q) {
    loadA(q, a);
    #pragma unroll
    for (int i = 0; i < 2; ++i) {
      const __hip_bfloat16* b = p + (unsigned)i*ST + (unsigned)q*1024u;
      bfv8 B0 = *(const bfv8*)(b);
      bfv8 B1 = *(const bfv8*)(b + 512);
      C[i][0] = __builtin_amdgcn_mfma_f32_16x16x32_bf16(a[0][0], B0, C[i][0], 0,0,0);
      C[i][1] = __builtin_amdgcn_mfma_f32_16x16x32_bf16(a[1][0], B0, C[i][1], 0,0,0);
      C[i][0] = __builtin_amdgcn_mfma_f32_16x16x32_bf16(a[0][1], B1, C[i][0], 0,0,0);
      C[i][1] = __builtin_amdgcn_mfma_f32_16x16x32_bf16(a[1][1], B1, C[i][1], 0,0,0);
    }
  }
}

// ---------------------------------------------------------------------------
// one-pass LayerNorm helper (register version, used only by fallback kernels)
__device__ __forceinline__ void ln24_norm(float* z, float* redbuf, float g, float b, int tid) {
  const int lane = tid & 63, wid = tid >> 6;
  float s1[NROW], s2[NROW];
  #pragma unroll
  for (int r = 0; r < NROW; ++r) { float v = z[r]; s1[r] = v; s2[r] = v*v; }
  #pragma unroll
  for (int off = 32; off; off >>= 1) {
    #pragma unroll
    for (int r = 0; r < NROW; ++r) {
      s1[r] += __shfl_down(s1[r], off, 64);
      s2[r] += __shfl_down(s2[r], off, 64);
    }
  }
  if (lane == 0) {
    #pragma unroll
    for (int r = 0; r < NROW; ++r) { redbuf[wid*48 + r] = s1[r]; redbuf[wid*48 + 24 + r] = s2[r]; }
  }
  __syncthreads();
  #pragma unroll
  for (int r = 0; r < NROW; ++r) {
    float S1 = redbuf[r] + redbuf[48+r] + redbuf[96+r] + redbuf[144+r];
    float S2 = redbuf[24+r] + redbuf[72+r] + redbuf[120+r] + redbuf[168+r];
    float m  = S1 * (1.0f/256.0f);
    float var = S2 * (1.0f/256.0f) - m*m;
    float iv = rsqrtf(var + 1e-5f);
    z[r] = (z[r] - m) * iv * g + b;
  }
  __syncthreads();
}

// ===========================================================================
// ============ multi-kernel path ============================================
// ===========================================================================

// embed: block = 4 tokens (24 rows). LDS-resident z + LDS-partial LN ->
// ~40 live regs, spill-proof at any VGPR allocation.
__global__ __launch_bounds__(256) void mk_embed(
    const float* __restrict__ x,
    const float* __restrict__ W_raw, const float* __restrict__ b_raw,
    const float* __restrict__ wl_emb, const float* __restrict__ pos_emb,
    const float* __restrict__ hop_emb,
    const float* __restrict__ ln_g, const float* __restrict__ ln_b,
    const float* __restrict__ W_res, const float* __restrict__ b_res,
    __hip_bfloat16* __restrict__ h0, float* __restrict__ res, int t0)
{
  __shared__ float xbuf[24][128];     // 12 KB
  __shared__ float zb[24][256];       // 24 KB
  __shared__ float part[2][24][8];
  __shared__ float stat[24][2];
  const int tid = threadIdx.x;
  const int bt  = blockIdx.x;

  for (int idx = tid; idx < 24*128; idx += 256) {
    int tt = idx / 768, rem = idx % 768;
    int s = rem >> 7, f = rem & 127;
    int t = t0 + bt*4 + tt, g = t >> 7, i = t & 127;
    int node;
    if (s < 2) node = i;
    else { int j = s - 2; node = (j < i) ? j : (j + 1); }
    xbuf[tt*6+s][f] = x[(g*128 + node)*128 + f];
  }
  __syncthreads();

  {
    float z[NROW];
    #pragma unroll
    for (int r = 0; r < NROW; ++r) z[r] = 0.f;
    #pragma unroll 2
    for (int f4 = 0; f4 < 32; ++f4) {
      float w0 = W_raw[(f4*4+0)*256 + tid];
      float w1 = W_raw[(f4*4+1)*256 + tid];
      float w2 = W_raw[(f4*4+2)*256 + tid];
      float w3 = W_raw[(f4*4+3)*256 + tid];
      #pragma unroll
      for (int r = 0; r < NROW; ++r) {
        float4 xv = *(const float4*)(&xbuf[r][f4*4]);
        z[r] += xv.x*w0 + xv.y*w1 + xv.z*w2 + xv.w*w3;
      }
    }
    float br  = b_raw[tid];
    float wl  = wl_emb[tid];
    float hp0 = hop_emb[5*256 + tid];
    float hp1 = hop_emb[511*256 + tid];
    float p[6];
    #pragma unroll
    for (int s = 0; s < 6; ++s) p[s] = pos_emb[s*256 + tid];
    #pragma unroll
    for (int r = 0; r < NROW; ++r) {
      int s = r % 6;
      zb[r][tid] = z[r] + br + p[s] + wl + ((s < 2) ? hp0 : hp1);
    }
  }
  __syncthreads();

  if (tid < 192) {
    int row = tid >> 3, seg = tid & 7;
    float s1 = 0.f, s2 = 0.f;
    #pragma unroll
    for (int i = 0; i < 32; ++i) {
      int col = seg*32 + ((i + tid) & 31);
      float v = zb[row][col];
      s1 += v; s2 += v*v;
    }
    part[0][row][seg] = s1; part[1][row][seg] = s2;
  }
  __syncthreads();
  if (tid < 24) {
    float S1 = 0.f, S2 = 0.f;
    #pragma unroll
    for (int k = 0; k < 8; ++k) { S1 += part[0][tid][k]; S2 += part[1][tid][k]; }
    float m = S1 * (1.0f/256.0f);
    float var = S2 * (1.0f/256.0f) - m*m;
    stat[tid][0] = m; stat[tid][1] = rsqrtf(var + 1e-5f);
  }
  __syncthreads();
  {
    float g = ln_g[tid], b = ln_b[tid];
    #pragma unroll
    for (int r = 0; r < NROW; ++r) {
      float v = (zb[r][tid] - stat[r][0]) * stat[r][1] * g + b;
      h0[(size_t)(bt*24 + r)*256 + tid] = f2bf(v);
    }
  }

  if (t0 + bt*4 < 256) {
    __syncthreads();
    for (int idx = tid; idx < 24*128; idx += 256) {
      int tt = idx / 768, rem = idx % 768;
      int s = rem >> 7, f = rem & 127;
      int t = t0 + bt*4 + tt;
      xbuf[tt*6+s][f] = x[(t*128 + s)*128 + f];
    }
    __syncthreads();
    float resv[NROW];
    float brr = b_res[tid];
    #pragma unroll
    for (int r = 0; r < NROW; ++r) resv[r] = brr;
    #pragma unroll 2
    for (int f4 = 0; f4 < 32; ++f4) {
      float w0 = W_res[(f4*4+0)*256 + tid];
      float w1 = W_res[(f4*4+1)*256 + tid];
      float w2 = W_res[(f4*4+2)*256 + tid];
      float w3 = W_res[(f4*4+3)*256 + tid];
      #pragma unroll
      for (int r = 0; r < NROW; ++r) {
        float4 xv = *(const float4*)(&xbuf[r][f4*4]);
        resv[r] += xv.x*w0 + xv.y*w1 + xv.z*w2 + xv.w*w3;
      }
    }
    #pragma unroll
    for (int r = 0; r < NROW; ++r)
      res[(size_t)((t0 + bt*4)*6 + r)*256 + tid] = resv[r];
  }
}

// stage 32x256 bf16 rows into swz LDS -- 256-thread version
__device__ __forceinline__ void stageA(const __hip_bfloat16* __restrict__ src,
                                       int row0, int stride, char* aT, int tid) {
  #pragma unroll
  for (int k = 0; k < 4; ++k) {
    int cid = tid + k*256;
    int row = cid >> 5, cc = cid & 31;
    uint4 v = *(const uint4*)(src + (size_t)(row0 + row)*stride + cc*8);
    *(uint4*)(aT + swz(row, cc*16)) = v;
  }
}
// 512-thread version
__device__ __forceinline__ void stageA512(const __hip_bfloat16* __restrict__ src,
                                          int row0, int stride, char* aT, int tid) {
  #pragma unroll
  for (int k = 0; k < 2; ++k) {
    int cid = tid + k*512;
    int row = cid >> 5, cc = cid & 31;
    uint4 v = *(const uint4*)(src + (size_t)(row0 + row)*stride + cc*8);
    *(uint4*)(aT + swz(row, cc*16)) = v;
  }
}

// qkv GEMM: 256 threads, M=32, N=768.
__global__ __launch_bounds__(256) void mk_qkv(
    const __hip_bfloat16* __restrict__ h, const __hip_bfloat16* __restrict__ Wf,
    const float* __restrict__ bqkv_l, __hip_bfloat16* __restrict__ qkv)
{
  __shared__ __align__(16) char aT[16384];
  const int tid = threadIdx.x;
  const int lane = tid & 63, wid = tid >> 6;
  const int l15 = lane & 15, l4 = lane >> 4;
  const int row0 = blockIdx.x * 32;

  stageA(h, row0, 256, aT, tid);
  __syncthreads();

  auto lA = [&](int kh, bfv8 (&a)[2][4]) {
    #pragma unroll
    for (int k = 0; k < 4; ++k) {
      a[0][k] = *(const bfv8*)(aT + swz(l15,      (kh*4 + k)*64 + l4*16));
      a[1][k] = *(const bfv8*)(aT + swz(16 + l15, (kh*4 + k)*64 + l4*16));
    }
  };

  #pragma unroll 1
  for (int sub = 0; sub < 3; ++sub) {
    f32x4 C[4][2];
    gemm_ks<8>(Wf + (unsigned)(sub*16 + wid)*8u*512u + lane*8, lA, C);
    #pragma unroll
    for (int i = 0; i < 4; ++i) {
      int col = sub*256 + (wid + i*4)*16 + l15;
      float bb = bqkv_l[col];
      #pragma unroll
      for (int j = 0; j < 4; ++j) {
        qkv[(size_t)(row0 + l4*4 + j)*768 + col]      = f2bf(C[i][0][j] + bb);
        qkv[(size_t)(row0 + 16 + l4*4 + j)*768 + col] = f2bf(C[i][1][j] + bb);
      }
    }
  }
}

// attention: 256 threads, VALU; 32 tokens/block, thread = (token, head).
__global__ __launch_bounds__(256) void mk_attn(__hip_bfloat16* __restrict__ qkv)
{
  const int tid = threadIdx.x;
  const int tl = tid >> 3, hh = tid & 7;
  const size_t rowbase = (size_t)(blockIdx.x*32 + tl)*6;
  const int cb = hh*32;

  #pragma unroll 1
  for (int q = 0; q < 6; ++q) {
    const __hip_bfloat16* qr = qkv + (rowbase + q)*768 + cb;
    bfv8 qv[4];
    #pragma unroll
    for (int p4 = 0; p4 < 4; ++p4) qv[p4] = *(const bfv8*)(qr + p4*8);
    float a[6]; float mx = -1e30f;
    #pragma unroll
    for (int sp = 0; sp < 6; ++sp) {
      const __hip_bfloat16* kr = qkv + (rowbase + sp)*768 + 256 + cb;
      float s = 0.f;
      #pragma unroll
      for (int p4 = 0; p4 < 4; ++p4) {
        bfv8 kv = *(const bfv8*)(kr + p4*8);
        #pragma unroll
        for (int j = 0; j < 8; ++j) s += bfs2f(qv[p4][j]) * bfs2f(kv[j]);
      }
      a[sp] = s * 0.17677669529663687f;
      mx = fmaxf(mx, a[sp]);
    }
    float sum = 0.f;
    #pragma unroll
    for (int sp = 0; sp < 6; ++sp) { a[sp] = __expf(a[sp] - mx); sum += a[sp]; }
    float inv = 1.f / sum;
    #pragma unroll
    for (int sp = 0; sp < 6; ++sp) a[sp] *= inv;
    float oc[32];
    #pragma unroll
    for (int j = 0; j < 32; ++j) oc[j] = 0.f;
    #pragma unroll
    for (int sp = 0; sp < 6; ++sp) {
      const __hip_bfloat16* vr = qkv + (rowbase + sp)*768 + 512 + cb;
      float asp = a[sp];
      #pragma unroll
      for (int p4 = 0; p4 < 4; ++p4) {
        bfv8 vv = *(const bfv8*)(vr + p4*8);
        #pragma unroll
        for (int j = 0; j < 8; ++j) oc[p4*8 + j] += asp * bfs2f(vv[j]);
      }
    }
    __hip_bfloat16* orow = qkv + (rowbase + q)*768 + cb;
    #pragma unroll
    for (int p4 = 0; p4 < 4; ++p4) {
      __align__(16) __hip_bfloat16 ob[8];
      #pragma unroll
      for (int j = 0; j < 8; ++j) ob[j] = f2bf(oc[p4*8 + j]);
      *(uint4*)(orow + p4*8) = *(const uint4*)ob;
    }
  }
}

// Wo GEMM + residual + LN1: 512 threads, spill-proof gemm_ksq.
__global__ __launch_bounds__(512) void mk_wo_ln(
    const __hip_bfloat16* __restrict__ qkv /* o at stride 768 */,
    const __hip_bfloat16* __restrict__ h,
    const float* __restrict__ res,
    const __hip_bfloat16* __restrict__ Wf, const float* __restrict__ bo_l,
    const float* __restrict__ gln, const float* __restrict__ bln,
    __hip_bfloat16* __restrict__ h1, int t0)
{
  __shared__ __align__(16) char aT[16384];
  __shared__ float zb[32][256];
  __shared__ float part[2][32][16];
  __shared__ float stat[32][2];
  const int tid = threadIdx.x;
  const int lane = tid & 63, wid = tid >> 6;      // wid 0..7
  const int l15 = lane & 15, l4 = lane >> 4;
  const int row0 = blockIdx.x * 32;

  stageA512(qkv, row0, 768, aT, tid);
  __syncthreads();

  auto lAq = [&](int q, bfv8 (&a)[2][2]) {
    #pragma unroll
    for (int k = 0; k < 2; ++k) {
      a[0][k] = *(const bfv8*)(aT + swz(l15,      (q*2 + k)*64 + l4*16));
      a[1][k] = *(const bfv8*)(aT + swz(16 + l15, (q*2 + k)*64 + l4*16));
    }
  };

  {
    f32x4 C[2][2];
    gemm_ksq<8>(Wf + (unsigned)wid*8u*512u + lane*8, lAq, C);
    #pragma unroll
    for (int i = 0; i < 2; ++i) {
      int col = (wid + i*8)*16 + l15;
      #pragma unroll
      for (int j = 0; j < 4; ++j) {
        zb[l4*4 + j][col]      = C[i][0][j];
        zb[16 + l4*4 + j][col] = C[i][1][j];
      }
    }
  }
  __syncthreads();

  #pragma unroll 4
  for (int it = 0; it < 16; ++it) {
    int idx = tid + it*512, row = idx >> 8, col = idx & 255;
    float v = zb[row][col] + bf2f(h[(size_t)(row0 + row)*256 + col]) + bo_l[col];
    int grow = t0*6 + row0 + row;
    if (grow < 1536) v += res[(size_t)grow*256 + col];
    zb[row][col] = v;
  }
  __syncthreads();

  {
    int row = tid >> 4, seg = tid & 15;
    float s1 = 0.f, s2 = 0.f;
    #pragma unroll
    for (int i = 0; i < 16; ++i) {
      int col = seg*16 + ((i + tid) & 15);
      float v = zb[row][col];
      s1 += v; s2 += v*v;
    }
    part[0][row][seg] = s1; part[1][row][seg] = s2;
  }
  __syncthreads();
  if (tid < 32) {
    float S1 = 0.f, S2 = 0.f;
    #pragma unroll
    for (int k = 0; k < 16; ++k) { S1 += part[0][tid][k]; S2 += part[1][tid][k]; }
    float m = S1 * (1.0f/256.0f);
    float var = S2 * (1.0f/256.0f) - m*m;
    stat[tid][0] = m; stat[tid][1] = rsqrtf(var + 1e-5f);
  }
  __syncthreads();
  #pragma unroll 4
  for (int it = 0; it < 16; ++it) {
    int idx = tid + it*512, row = idx >> 8, col = idx & 255;
    float v = (zb[row][col] - stat[row][0]) * stat[row][1] * gln[col] + bln[col];
    h1[(size_t)(row0 + row)*256 + col] = f2bf(v);
  }
}

// FFN fused + residual + LN2: 512 threads, spill-proof gemm_ksq.
__global__ __launch_bounds__(512) void mk_ffn(
    const __hip_bfloat16* __restrict__ h1,
    const __hip_bfloat16* __restrict__ W1f, const __hip_bfloat16* __restrict__ W2f,
    const float* __restrict__ b1_l, const float* __restrict__ b2_l,
    const float* __restrict__ gln, const float* __restrict__ bln,
    const float* __restrict__ res, __hip_bfloat16* __restrict__ hout,
    float* __restrict__ outp, int t0)
{
  __shared__ __align__(16) char aT[16384];
  __shared__ __align__(16) char gT[16384];
  __shared__ float ff[32][256];
  __shared__ float part[2][32][16];
  __shared__ float stat[32][2];
  const int tid = threadIdx.x;
  const int lane = tid & 63, wid = tid >> 6;      // wid 0..7
  const int l15 = lane & 15, l4 = lane >> 4;
  const int row0 = blockIdx.x * 32;

  stageA512(h1, row0, 256, aT, tid);
  #pragma unroll 4
  for (int it = 0; it < 16; ++it) {
    int idx = tid + it*512;
    ff[idx >> 8][idx & 255] = 0.f;
  }
  __syncthreads();

  auto lAq = [&](int q, bfv8 (&a)[2][2]) {
    #pragma unroll
    for (int k = 0; k < 2; ++k) {
      a[0][k] = *(const bfv8*)(aT + swz(l15,      (q*2 + k)*64 + l4*16));
      a[1][k] = *(const bfv8*)(aT + swz(16 + l15, (q*2 + k)*64 + l4*16));
    }
  };
  auto lGq = [&](int q, bfv8 (&a)[2][2]) {
    #pragma unroll
    for (int k = 0; k < 2; ++k) {
      a[0][k] = *(const bfv8*)(gT + swz(l15,      (q*2 + k)*64 + l4*16));
      a[1][k] = *(const bfv8*)(gT + swz(16 + l15, (q*2 + k)*64 + l4*16));
    }
  };

  #pragma unroll 1
  for (int ch = 0; ch < 4; ++ch) {
    {
      f32x4 C[2][2];
      gemm_ksq<8>(W1f + (unsigned)(ch*16 + wid)*8u*512u + lane*8, lAq, C);
      #pragma unroll
      for (int i = 0; i < 2; ++i) {
        int colR = (wid + i*8)*16 + l15;
        float bb = b1_l[ch*256 + colR];
        int col2 = colR*2;
        #pragma unroll
        for (int j = 0; j < 4; ++j) {
          *(__hip_bfloat16*)(gT + swz(l4*4 + j, col2))      = f2bf(gelu_f(C[i][0][j] + bb));
          *(__hip_bfloat16*)(gT + swz(16 + l4*4 + j, col2)) = f2bf(gelu_f(C[i][1][j] + bb));
        }
      }
    }
    __syncthreads();   // g visible
    {
      f32x4 C[2][2];
      gemm_ksq<32>(W2f + (unsigned)(wid*32 + ch*8)*512u + lane*8, lGq, C);
      #pragma unroll
      for (int i = 0; i < 2; ++i) {
        int col = (wid + i*8)*16 + l15;
        #pragma unroll
        for (int j = 0; j < 4; ++j) {
          ff[l4*4 + j][col]      += C[i][0][j];
          ff[16 + l4*4 + j][col] += C[i][1][j];
        }
      }
    }
    __syncthreads();   // g reads done
  }

  #pragma unroll 4
  for (int it = 0; it < 16; ++it) {
    int idx = tid + it*512, row = idx >> 8, col = idx & 255;
    float v = ff[row][col] + bf2f(h1[(size_t)(row0 + row)*256 + col]) + b2_l[col];
    int grow = t0*6 + row0 + row;
    if (grow < 1536) v += res[(size_t)grow*256 + col];
    ff[row][col] = v;
  }
  __syncthreads();
  {
    int row = tid >> 4, seg = tid & 15;
    float s1 = 0.f, s2 = 0.f;
    #pragma unroll
    for (int i = 0; i < 16; ++i) {
      int col = seg*16 + ((i + tid) & 15);
      float v = ff[row][col];
      s1 += v; s2 += v*v;
    }
    part[0][row][seg] = s1; part[1][row][seg] = s2;
  }
  __syncthreads();
  if (tid < 32) {
    float S1 = 0.f, S2 = 0.f;
    #pragma unroll
    for (int k = 0; k < 16; ++k) { S1 += part[0][tid][k]; S2 += part[1][tid][k]; }
    float m = S1 * (1.0f/256.0f);
    float var = S2 * (1.0f/256.0f) - m*m;
    stat[tid][0] = m; stat[tid][1] = rsqrtf(var + 1e-5f);
  }
  __syncthreads();
  #pragma unroll 4
  for (int it = 0; it < 16; ++it) {
    int idx = tid + it*512, row = idx >> 8, col = idx & 255;
    float v = (ff[row][col] - stat[row][0]) * stat[row][1] * gln[col] + bln[col];
    hout[(size_t)(row0 + row)*256 + col] = f2bf(v);
    if (outp && ((row0 + row) % 6 == 0)) {
      int gtok = t0 + (row0 + row) / 6;
      outp[(size_t)gtok*256 + col] = v;
    }
  }
}

// ===========================================================================
// ============ round-10 fused champion (fallback) ===========================
// ===========================================================================
__global__ __launch_bounds__(256, 2) void gb_mfma_kernel(
    const float* __restrict__ x,
    const float* __restrict__ W_raw, const float* __restrict__ b_raw,
    const float* __restrict__ wl_emb, const float* __restrict__ pos_emb,
    const float* __restrict__ hop_emb,
    const float* __restrict__ ln_g, const float* __restrict__ ln_b,
    const float* __restrict__ bqkv, const float* __restrict__ bo,
    const float* __restrict__ n1g,  const float* __restrict__ n1b,
    const float* __restrict__ b1,   const float* __restrict__ b2,
    const float* __restrict__ n2g,  const float* __restrict__ n2b,
    const float* __restrict__ W_res, const float* __restrict__ b_res,
    const __hip_bfloat16* __restrict__ wf,
    float* __restrict__ out)
{
  __shared__ __align__(16) char smem[75392];
  char* hsb = smem;
  char* uA  = smem + 16384;
  char* uB  = smem + 53632;
  float (*attw)[24][6] = (float (*)[24][6])(smem + 70016);
  float* redbuf = (float*)(smem + 74624);

  __hip_bfloat16 (*qkvs)[776] = (__hip_bfloat16 (*)[776])uA;
  float (*fbuf)[264] = (float (*)[264])uA;
  float (*xbuf)[128] = (float (*)[128])uA;

  const int tid  = threadIdx.x;
  const int bt   = blockIdx.x;
  const int lane = tid & 63, wid = tid >> 6;
  const int l15  = lane & 15, l4 = lane >> 4;

  auto mkA = [l15, l4](const char* buf) {
    return [buf, l15, l4](int kh, bfv8 (&a)[2][4]) {
      #pragma unroll
      for (int k = 0; k < 4; ++k) {
        a[0][k] = *(const bfv8*)(buf + swz(l15,      (kh*4 + k)*64 + l4*16));
        a[1][k] = *(const bfv8*)(buf + swz(16 + l15, (kh*4 + k)*64 + l4*16));
      }
    };
  };

  {
    uint4 zz = {0u,0u,0u,0u};
    *(uint4*)(hsb + 24*512 + tid*16) = zz;
    *(uint4*)(uB  + 24*512 + tid*16) = zz;
  }

  for (int idx = tid; idx < TB*6*128; idx += 256) {
    int tt = idx / 768, rem = idx % 768;
    int s = rem >> 7, f = rem & 127;
    int t = bt*TB + tt, g = t >> 7, i = t & 127;
    int node;
    if (s < 2) node = i;
    else { int j = s - 2; node = (j < i) ? j : (j + 1); }
    xbuf[tt*6+s][f] = x[(g*128 + node)*128 + f];
  }
  __syncthreads();

  {
    float z[NROW];
    #pragma unroll
    for (int r = 0; r < NROW; ++r) z[r] = 0.f;
    #pragma unroll 2
    for (int f4 = 0; f4 < 32; ++f4) {
      float w0 = W_raw[(f4*4+0)*256 + tid];
      float w1 = W_raw[(f4*4+1)*256 + tid];
      float w2 = W_raw[(f4*4+2)*256 + tid];
      float w3 = W_raw[(f4*4+3)*256 + tid];
      #pragma unroll
      for (int r = 0; r < NROW; ++r) {
        float4 xv = *(const float4*)(&xbuf[r][f4*4]);
        z[r] += xv.x*w0 + xv.y*w1 + xv.z*w2 + xv.w*w3;
      }
    }
    float br  = b_raw[tid];
    float wl  = wl_emb[tid];
    float hp0 = hop_emb[5*256 + tid];
    float hp1 = hop_emb[511*256 + tid];
    float p[6];
    #pragma unroll
    for (int s = 0; s < 6; ++s) p[s] = pos_emb[s*256 + tid];
    #pragma unroll
    for (int r = 0; r < NROW; ++r) {
      int s = r % 6;
      z[r] += br + p[s] + wl + ((s < 2) ? hp0 : hp1);
    }
    ln24_norm(z, redbuf, ln_g[tid], ln_b[tid], tid);
    #pragma unroll
    for (int r = 0; r < NROW; ++r)
      *(__hip_bfloat16*)(hsb + swz(r, tid*2)) = f2bf(z[r]);
  }

  unsigned resp[12];
  #pragma unroll
  for (int k = 0; k < 12; ++k) resp[k] = 0u;
  if (bt < 64) {
    __syncthreads();
    for (int idx = tid; idx < TB*6*128; idx += 256) {
      int tt = idx / 768, rem = idx % 768;
      int s = rem >> 7, f = rem & 127;
      int t = bt*TB + tt;
      xbuf[tt*6+s][f] = x[(t*128 + s)*128 + f];
    }
    __syncthreads();
    float resv[NROW];
    float brr = b_res[tid];
    #pragma unroll
    for (int r = 0; r < NROW; ++r) resv[r] = brr;
    #pragma unroll 2
    for (int f4 = 0; f4 < 32; ++f4) {
      float w0 = W_res[(f4*4+0)*256 + tid];
      float w1 = W_res[(f4*4+1)*256 + tid];
      float w2 = W_res[(f4*4+2)*256 + tid];
      float w3 = W_res[(f4*4+3)*256 + tid];
      #pragma unroll
      for (int r = 0; r < NROW; ++r) {
        float4 xv = *(const float4*)(&xbuf[r][f4*4]);
        resv[r] += xv.x*w0 + xv.y*w1 + xv.z*w2 + xv.w*w3;
      }
    }
    #pragma unroll
    for (int k = 0; k < 12; ++k) {
      unsigned lo = __float_as_uint(resv[2*k])   >> 16;
      unsigned hi = __float_as_uint(resv[2*k+1]) & 0xffff0000u;
      resp[k] = hi | lo;
    }
  }

  float z[NROW];

  #pragma unroll 1
  for (int l = 0; l < 4; ++l) {
    const __hip_bfloat16* WQf = wf + OWQ + (unsigned)l*196608u;
    const __hip_bfloat16* WOf = wf + OWO + (unsigned)l*65536u;
    const __hip_bfloat16* W1f = wf + OW1 + (unsigned)l*262144u;
    const __hip_bfloat16* W2f = wf + OW2 + (unsigned)l*262144u;

    __syncthreads();

    {
      auto lA = mkA(hsb);
      #pragma unroll 1
      for (int sub = 0; sub < 3; ++sub) {
        f32x4 C[4][2];
        gemm_ks<8>(WQf + (unsigned)(sub*16 + wid)*8u*512u + lane*8, lA, C);
        #pragma unroll
        for (int i = 0; i < 4; ++i) {
          int gcol = sub*256 + (wid + i*4)*16 + l15;
          float bbv = bqkv[l*768 + gcol];
          #pragma unroll
          for (int j = 0; j < 4; ++j) {
            qkvs[l4*4 + j][gcol] = f2bf(C[i][0][j] + bbv);
            int r1 = 16 + l4*4 + j;
            if (r1 < NROW) qkvs[r1][gcol] = f2bf(C[i][1][j] + bbv);
          }
        }
      }
    }
    __syncthreads();

    if (tid < 192) {
      int hh = tid / 24, r = tid % 24;
      int tt6 = (r / 6) * 6;
      bfv8 qv[4];
      #pragma unroll
      for (int p4 = 0; p4 < 4; ++p4) qv[p4] = *(const bfv8*)(&qkvs[r][hh*32 + p4*8]);
      float sc[6];
      #pragma unroll
      for (int sp = 0; sp < 6; ++sp) {
        float s = 0.f;
        #pragma unroll
        for (int p4 = 0; p4 < 4; ++p4) {
          bfv8 kv = *(const bfv8*)(&qkvs[tt6 + sp][256 + hh*32 + p4*8]);
          #pragma unroll
          for (int j = 0; j < 8; ++j) s += bfs2f(qv[p4][j]) * bfs2f(kv[j]);
        }
        sc[sp] = s * 0.17677669529663687f;
      }
      float mx = sc[0];
      #pragma unroll
      for (int sp = 1; sp < 6; ++sp) mx = fmaxf(mx, sc[sp]);
      float sum = 0.f;
      #pragma unroll
      for (int sp = 0; sp < 6; ++sp) { sc[sp] = __expf(sc[sp] - mx); sum += sc[sp]; }
      float inv = 1.f / sum;
      #pragma unroll
      for (int sp = 0; sp < 6; ++sp) attw[hh][r][sp] = sc[sp] * inv;
    }
    __syncthreads();

    {
      int hh = tid >> 5, c = tid & 31;
      int col2 = (hh*32 + c)*2;
      #pragma unroll
      for (int tt = 0; tt < 4; ++tt) {
        float vv[6];
        #pragma unroll
        for (int sp = 0; sp < 6; ++sp) vv[sp] = bf2f(qkvs[tt*6 + sp][512 + hh*32 + c]);
        #pragma unroll
        for (int q = 0; q < 6; ++q) {
          float o = 0.f;
          #pragma unroll
          for (int sp = 0; sp < 6; ++sp) o += attw[hh][tt*6 + q][sp] * vv[sp];
          *(__hip_bfloat16*)(uB + swz(tt*6 + q, col2)) = f2bf(o);
        }
      }
    }
    __syncthreads();

    {
      f32x4 C[4][2];
      gemm_ks<8>(WOf + (unsigned)wid*8u*512u + lane*8, mkA(uB), C);
      #pragma unroll
      for (int i = 0; i < 4; ++i) {
        int col = (wid + i*4)*16 + l15;
        #pragma unroll
        for (int j = 0; j < 4; ++j) {
          fbuf[l4*4 + j][col] = C[i][0][j];
          int r1 = 16 + l4*4 + j;
          if (r1 < NROW) fbuf[r1][col] = C[i][1][j];
        }
      }
    }
    __syncthreads();

    {
      float bov = bo[l*256 + tid];
      #pragma unroll
      for (int r = 0; r < NROW; ++r)
        z[r] = bf2f(*(const __hip_bfloat16*)(hsb + swz(r, tid*2)))
             + unpk(resp[r >> 1], r & 1) + fbuf[r][tid] + bov;
    }
    #pragma unroll
    for (int k = 0; k < 12; ++k) *(unsigned*)(uB + (k*256 + tid)*4) = 0u;
    ln24_norm(z, redbuf, n1g[l*256 + tid], n1b[l*256 + tid], tid);
    #pragma unroll
    for (int r = 0; r < NROW; ++r)
      *(__hip_bfloat16*)(hsb + swz(r, tid*2)) = f2bf(z[r]);
    {
      uint4 zz = {0u,0u,0u,0u};
      *(uint4*)(uA + 24*512 + tid*16) = zz;
      *(uint4*)(uA + 16384 + 24*512 + tid*16) = zz;
    }
    __syncthreads();

    {
      auto lAh = mkA(hsb);
      #pragma unroll 1
      for (int ch = 0; ch < 4; ++ch) {
        char* gb = uA + (ch & 1)*16384;
        {
          f32x4 C[4][2];
          gemm_ks<8>(W1f + (unsigned)(ch*128 + wid*8)*512u + lane*8, lAh, C);
          #pragma unroll
          for (int i = 0; i < 4; ++i) {
            float bbv = b1[l*1024 + ch*256 + (wid + i*4)*16 + l15];
            int col2 = ((wid + i*4)*16 + l15)*2;
            #pragma unroll
            for (int j = 0; j < 4; ++j) {
              *(__hip_bfloat16*)(gb + swz(l4*4 + j, col2)) = f2bf(gelu_f(C[i][0][j] + bbv));
              int r1 = 16 + l4*4 + j;
              if (r1 < NROW)
                *(__hip_bfloat16*)(gb + swz(r1, col2)) = f2bf(gelu_f(C[i][1][j] + bbv));
            }
          }
        }
        __syncthreads();
        {
          f32x4 C[4][2];
          gemm_ks<32>(W2f + (unsigned)(wid*32 + ch*8)*512u + lane*8, mkA(gb), C);
          #pragma unroll
          for (int i = 0; i < 4; ++i) {
            int col2 = ((wid + i*4)*16 + l15)*2;
            #pragma unroll
            for (int j = 0; j < 4; ++j) {
              {
                __hip_bfloat16* pp = (__hip_bfloat16*)(uB + (l4*4 + j)*512 + col2);
                *pp = f2bf(bf2f(*pp) + C[i][0][j]);
              }
              int r1 = 16 + l4*4 + j;
              if (r1 < NROW) {
                __hip_bfloat16* pp = (__hip_bfloat16*)(uB + r1*512 + col2);
                *pp = f2bf(bf2f(*pp) + C[i][1][j]);
              }
            }
          }
        }
      }
    }
    __syncthreads();

    {
      float b2v = b2[l*256 + tid];
      #pragma unroll
      for (int r = 0; r < NROW; ++r)
        z[r] = bf2f(*(const __hip_bfloat16*)(hsb + swz(r, tid*2)))
             + unpk(resp[r >> 1], r & 1)
             + bf2f(*(const __hip_bfloat16*)(uB + r*512 + tid*2)) + b2v;
    }
    ln24_norm(z, redbuf, n2g[l*256 + tid], n2b[l*256 + tid], tid);
    #pragma unroll
    for (int r = 0; r < NROW; ++r)
      *(__hip_bfloat16*)(hsb + swz(r, tid*2)) = f2bf(z[r]);
  }

  #pragma unroll
  for (int tt = 0; tt < TB; ++tt)
    out[(bt*TB + tt)*256 + tid] = z[tt*6];
}

// ---------------------------------------------------------------------------
// Pure-VALU fallback (round-2 proven).
__global__ __launch_bounds__(256, 2) void gb_fused_fallback(
    const float* __restrict__ x,
    const float* __restrict__ W_raw, const float* __restrict__ b_raw,
    const float* __restrict__ wl_emb, const float* __restrict__ pos_emb,
    const float* __restrict__ hop_emb,
    const float* __restrict__ ln_g, const float* __restrict__ ln_b,
    const float* __restrict__ Wqkv, const float* __restrict__ bqkv,
    const float* __restrict__ Wo,   const float* __restrict__ bo,
    const float* __restrict__ n1g,  const float* __restrict__ n1b,
    const float* __restrict__ W1,   const float* __restrict__ b1,
    const float* __restrict__ W2,   const float* __restrict__ b2,
    const float* __restrict__ n2g,  const float* __restrict__ n2b,
    const float* __restrict__ W_res, const float* __restrict__ b_res,
    float* __restrict__ out)
{
  __shared__ float hs[NROW][256];
  __shared__ __align__(16) char bufraw[NROW*768*2];
  __shared__ float attw[8][NROW][8];
  __shared__ float redbuf[192];

  __hip_bfloat16 (*qkvs)[768] = (__hip_bfloat16 (*)[768])bufraw;
  float (*fbuf)[256] = (float (*)[256])bufraw;
  float (*xbuf)[128] = (float (*)[128])bufraw;

  const int tid = threadIdx.x;
  const int bt  = blockIdx.x;

  for (int idx = tid; idx < TB*6*128; idx += 256) {
    int tt = idx / 768, rem = idx % 768;
    int s = rem >> 7, f = rem & 127;
    int t = bt*TB + tt, g = t >> 7, i = t & 127;
    int node;
    if (s < 2) node = i;
    else { int j = s - 2; node = (j < i) ? j : (j + 1); }
    xbuf[tt*6+s][f] = x[(g*128 + node)*128 + f];
  }
  __syncthreads();

  float z[NROW];
  {
    #pragma unroll
    for (int r = 0; r < NROW; ++r) z[r] = 0.f;
    #pragma unroll 4
    for (int f = 0; f < 128; ++f) {
      float w = W_raw[f*256 + tid];
      #pragma unroll
      for (int r = 0; r < NROW; ++r) z[r] += xbuf[r][f] * w;
    }
    float br  = b_raw[tid];
    float wl  = wl_emb[tid];
    float hp0 = hop_emb[5*256 + tid];
    float hp1 = hop_emb[511*256 + tid];
    float p[6];
    #pragma unroll
    for (int s = 0; s < 6; ++s) p[s] = pos_emb[s*256 + tid];
    #pragma unroll
    for (int r = 0; r < NROW; ++r) {
      int s = r % 6;
      z[r] += br + p[s] + wl + ((s < 2) ? hp0 : hp1);
    }
  }
  ln24_norm(z, redbuf, ln_g[tid], ln_b[tid], tid);
  #pragma unroll
  for (int r = 0; r < NROW; ++r) hs[r][tid] = z[r];

  float resv[NROW];
  #pragma unroll
  for (int r = 0; r < NROW; ++r) resv[r] = 0.f;
  if (bt < 64) {
    __syncthreads();
    for (int idx = tid; idx < TB*6*128; idx += 256) {
      int tt = idx / 768, rem = idx % 768;
      int s = rem >> 7, f = rem & 127;
      int t = bt*TB + tt;
      xbuf[tt*6+s][f] = x[(t*128 + s)*128 + f];
    }
    __syncthreads();
    #pragma unroll 4
    for (int f = 0; f < 128; ++f) {
      float w = W_res[f*256 + tid];
      #pragma unroll
      for (int r = 0; r < NROW; ++r) resv[r] += xbuf[r][f] * w;
    }
    float brr = b_res[tid];
    #pragma unroll
    for (int r = 0; r < NROW; ++r) resv[r] += brr;
  }

  for (int l = 0; l < 4; ++l) {
    const float* Wqkv_l = Wqkv + l*196608;
    const float* bqkv_l = bqkv + l*768;
    const float* Wo_l   = Wo   + l*65536;
    const float* bo_l   = bo   + l*256;
    const float* W1_l   = W1   + l*262144;
    const float* b1_l   = b1   + l*1024;
    const float* W2_l   = W2   + l*262144;
    const float* b2_l   = b2   + l*256;

    __syncthreads();

    for (int cg = 0; cg < 3; ++cg) {
      int col = cg*256 + tid;
      float acc[NROW];
      #pragma unroll
      for (int r = 0; r < NROW; ++r) acc[r] = 0.f;
      #pragma unroll 4
      for (int kk = 0; kk < 256; ++kk) {
        float w = Wqkv_l[kk*768 + col];
        #pragma unroll
        for (int r = 0; r < NROW; ++r) acc[r] += hs[r][kk] * w;
      }
      float bbv = bqkv_l[col];
      #pragma unroll
      for (int r = 0; r < NROW; ++r) qkvs[r][col] = f2bf(acc[r] + bbv);
    }
    __syncthreads();

    #pragma unroll 1
    for (int it = 0; it < 5; ++it) {
      int idx = it*256 + tid;
      if (idx < 1152) {
        int hh = idx / 144, rem = idx % 144;
        int r = rem / 6, sp = rem % 6;
        int tt6 = (r / 6) * 6;
        float sc = 0.f;
        #pragma unroll
        for (int c = 0; c < 32; ++c)
          sc += bf2f(qkvs[r][hh*32 + c]) * bf2f(qkvs[tt6 + sp][256 + hh*32 + c]);
        attw[hh][r][sp] = sc * 0.17677669529663687f;
      }
    }
    __syncthreads();

    if (tid < 192) {
      int hh = tid / 24, r = tid % 24;
      float mx = attw[hh][r][0];
      #pragma unroll
      for (int sp = 1; sp < 6; ++sp) mx = fmaxf(mx, attw[hh][r][sp]);
      float e[6], sum = 0.f;
      #pragma unroll
      for (int sp = 0; sp < 6; ++sp) { e[sp] = expf(attw[hh][r][sp] - mx); sum += e[sp]; }
      float inv = 1.f / sum;
      #pragma unroll
      for (int sp = 0; sp < 6; ++sp) attw[hh][r][sp] = e[sp] * inv;
    }
    __syncthreads();

    float oreg[NROW];
    {
      int hh = tid >> 5, c = tid & 31;
      #pragma unroll
      for (int r = 0; r < NROW; ++r) {
        int tt6 = (r / 6) * 6;
        float o = 0.f;
        #pragma unroll
        for (int sp = 0; sp < 6; ++sp)
          o += attw[hh][r][sp] * bf2f(qkvs[tt6 + sp][512 + hh*32 + c]);
        oreg[r] = o;
      }
    }
    __syncthreads();
    #pragma unroll
    for (int r = 0; r < NROW; ++r) fbuf[r][tid] = oreg[r];
    __syncthreads();

    {
      float bod = bo_l[tid];
      float zz[NROW];
      #pragma unroll
      for (int r = 0; r < NROW; ++r) zz[r] = bod;
      #pragma unroll 4
      for (int kk = 0; kk < 256; ++kk) {
        float w = Wo_l[kk*256 + tid];
        #pragma unroll
        for (int r = 0; r < NROW; ++r) zz[r] += fbuf[r][kk] * w;
      }
      #pragma unroll
      for (int r = 0; r < NROW; ++r) z[r] += zz[r] + resv[r];
    }
    ln24_norm(z, redbuf, n1g[l*256 + tid], n1b[l*256 + tid], tid);
    #pragma unroll
    for (int r = 0; r < NROW; ++r) hs[r][tid] = z[r];
    __syncthreads();

    float ffv[NROW];
    {
      float b2d = b2_l[tid];
      #pragma unroll
      for (int r = 0; r < NROW; ++r) ffv[r] = b2d;
    }
    for (int ch = 0; ch < 4; ++ch) {
      int j = ch*256 + tid;
      float gvv[NROW];
      float b1j = b1_l[j];
      #pragma unroll
      for (int r = 0; r < NROW; ++r) gvv[r] = b1j;
      #pragma unroll 4
      for (int kk = 0; kk < 256; ++kk) {
        float w = W1_l[kk*1024 + j];
        #pragma unroll
        for (int r = 0; r < NROW; ++r) gvv[r] += hs[r][kk] * w;
      }
      __syncthreads();
      #pragma unroll
      for (int r = 0; r < NROW; ++r) fbuf[r][tid] = gelu_f(gvv[r]);
      __syncthreads();
      #pragma unroll 4
      for (int kk = 0; kk < 256; ++kk) {
        float w = W2_l[(ch*256 + kk)*256 + tid];
        #pragma unroll
        for (int r = 0; r < NROW; ++r) ffv[r] += fbuf[r][kk] * w;
      }
    }
    #pragma unroll
    for (int r = 0; r < NROW; ++r) z[r] += ffv[r] + resv[r];
    ln24_norm(z, redbuf, n2g[l*256 + tid], n2b[l*256 + tid], tid);
    #pragma unroll
    for (int r = 0; r < NROW; ++r) hs[r][tid] = z[r];
  }

  __syncthreads();
  #pragma unroll
  for (int tt = 0; tt < TB; ++tt)
    out[(bt*TB + tt)*256 + tid] = hs[tt*6][tid];
}

// ===========================================================================
extern "C" void kernel_launch(void* const* d_in, const int* in_sizes, int n_in,
                              void* d_out, int out_size, void* d_ws, size_t ws_size,
                              hipStream_t stream) {
  (void)in_sizes; (void)n_in; (void)out_size;
  const float* x      = (const float*)d_in[0];
  const float* W_raw  = (const float*)d_in[1];
  const float* b_raw  = (const float*)d_in[2];
  const float* wl_emb = (const float*)d_in[3];
  const float* pos_emb= (const float*)d_in[4];
  const float* hop_emb= (const float*)d_in[5];
  const float* ln_g   = (const float*)d_in[6];
  const float* ln_b   = (const float*)d_in[7];
  const float* Wqkv   = (const float*)d_in[8];
  const float* bqkv   = (const float*)d_in[9];
  const float* Wo     = (const float*)d_in[10];
  const float* bo     = (const float*)d_in[11];
  const float* n1g    = (const float*)d_in[12];
  const float* n1b    = (const float*)d_in[13];
  const float* W1     = (const float*)d_in[14];
  const float* b1     = (const float*)d_in[15];
  const float* W2     = (const float*)d_in[16];
  const float* b2     = (const float*)d_in[17];
  const float* n2g    = (const float*)d_in[18];
  const float* n2b    = (const float*)d_in[19];
  const float* W_res  = (const float*)d_in[20];
  const float* b_res  = (const float*)d_in[21];

  int tc = 0;
  for (int cand = 32768; cand >= 4096; cand >>= 1) {
    size_t need = (size_t)ACTOFF + (size_t)cand * 15360u;
    if (ws_size >= need) { tc = cand; break; }
  }

  if (tc > 0) {
    char* wsb = (char*)d_ws;
    __hip_bfloat16* wf  = (__hip_bfloat16*)wsb;
    float*          res = (float*)(wsb + RESOFF);
    __hip_bfloat16* h0  = (__hip_bfloat16*)(wsb + ACTOFF);
    __hip_bfloat16* h1  = (__hip_bfloat16*)(wsb + ACTOFF + (size_t)tc*6*512);
    __hip_bfloat16* qkv = (__hip_bfloat16*)(wsb + ACTOFF + (size_t)tc*6*1024);
    float* outp = (float*)d_out;

    gb_prep_kernel<<<1536, 256, 0, stream>>>(Wqkv, Wo, W1, W2, wf);

    int nchunk = 32768 / tc;
    for (int c = 0; c < nchunk; ++c) {
      int t0 = c * tc;
      mk_embed<<<tc/4, 256, 0, stream>>>(x, W_raw, b_raw, wl_emb, pos_emb,
          hop_emb, ln_g, ln_b, W_res, b_res, h0, res, t0);
      for (int l = 0; l < 4; ++l) {
        mk_qkv<<<tc*6/32, 256, 0, stream>>>(
            h0, wf + OWQ + (unsigned)l*196608u, bqkv + l*768, qkv);
        mk_attn<<<tc/32, 256, 0, stream>>>(qkv);
        mk_wo_ln<<<tc*6/32, 512, 0, stream>>>(
            qkv, h0, res, wf + OWO + (unsigned)l*65536u, bo + l*256,
            n1g + l*256, n1b + l*256, h1, t0);
        mk_ffn<<<tc*6/32, 512, 0, stream>>>(
            h1, wf + OW1 + (unsigned)l*262144u, wf + OW2 + (unsigned)l*262144u,
            b1 + l*1024, b2 + l*256, n2g + l*256, n2b + l*256,
            res, h0, (l == 3) ? outp : (float*)nullptr, t0);
      }
    }
  } else if (ws_size >= (size_t)WS_ELEMS * 2) {
    __hip_bfloat16* wsb = (__hip_bfloat16*)d_ws;
    gb_prep_kernel<<<1536, 256, 0, stream>>>(Wqkv, Wo, W1, W2, wsb);
    gb_mfma_kernel<<<8192, 256, 0, stream>>>(
        x, W_raw, b_raw, wl_emb, pos_emb, hop_emb, ln_g, ln_b,
        bqkv, bo, n1g, n1b, b1, b2, n2g, n2b, W_res, b_res,
        wsb, (float*)d_out);
  } else {
    gb_fused_fallback<<<8192, 256, 0, stream>>>(
        x, W_raw, b_raw, wl_emb, pos_emb, hop_emb, ln_g, ln_b,
        Wqkv, bqkv, Wo, bo, n1g, n1b, W1, b1, W2, b2, n2g, n2b,
        W_res, b_res, (float*)d_out);
  }
}

// Round 21
// 3127.828 us; speedup vs baseline: 1.0447x; 1.0221x over previous
//
#include <hip/hip_runtime.h>
#include <hip/hip_bf16.h>

// GraphBertEncoder: T=32768 tokens, S=6, D=256, H=8 (hd=32), L=4.
// Round 21: r18 champion (3.18ms) + LDS diet for occupancy (the one untried
// lever: mk_ffn/mk_wo_ln are latency-bound at 44% occupancy, LDS-capped at
// 2 blocks/CU). mk_ffn: ff accumulator fp32->bf16 (r10-proven scheme, same
// absmax) + phase-overlay of {aT,gT}->fp32 LN buffer and ff->{part,stat}:
// 70144 -> 49152 B = 3 blocks/CU. mk_wo_ln: zb overlays aT (one extra
// barrier): 52.5K -> 37120 B = 4 blocks/CU. Everything else = r18.

#define TB 4
#define NROW 24

typedef float f32x4 __attribute__((ext_vector_type(4)));
typedef short bfv8  __attribute__((ext_vector_type(8)));   // 8 bf16 = 4 VGPR

__device__ __forceinline__ float bf2f(__hip_bfloat16 v) { return __bfloat162float(v); }
__device__ __forceinline__ __hip_bfloat16 f2bf(float v) { return __float2bfloat16(v); }
__device__ __forceinline__ float bfs2f(short s) { return __uint_as_float(((unsigned)(unsigned short)s) << 16); }
__device__ __forceinline__ int swz(int row, int cb) { return row*512 + (cb ^ ((row & 7) << 4)); }
__device__ __forceinline__ float gelu_f(float v) { return 0.5f*v*(1.f + erff(v*0.70710678118654752f)); }
__device__ __forceinline__ float unpk(unsigned p, int hi) {
  return __uint_as_float(hi ? (p & 0xffff0000u) : (p << 16));
}

// packed-weight offsets (bf16 elements)
#define OWQ 0u
#define OWO 786432u
#define OW1 1048576u
#define OW2 2097152u
#define WS_ELEMS 3145728u      // weights: 6291456 bytes
#define RESOFF    6291456u     // res fp32 [1536][256] = 1572864 B
#define ACTOFF    7864320u

// ---------------------------------------------------------------------------
__global__ __launch_bounds__(256) void gb_prep_kernel(
    const float* __restrict__ Wqkv, const float* __restrict__ Wo,
    const float* __restrict__ W1,   const float* __restrict__ W2,
    __hip_bfloat16* __restrict__ ws)
{
  int fg   = blockIdx.x * 4 + (threadIdx.x >> 6);
  int lane = threadIdx.x & 63;
  int layer = fg / 1536, r = fg % 1536;
  const float* src; int K, N, fl; unsigned dstbase;
  if (r < 384)       { src = Wqkv + layer*196608; K = 256;  N = 768;  fl = r;       dstbase = OWQ + layer*196608u; }
  else if (r < 512)  { src = Wo   + layer*65536;  K = 256;  N = 256;  fl = r - 384; dstbase = OWO + layer*65536u;  }
  else if (r < 1024) { src = W1   + layer*262144; K = 256;  N = 1024; fl = r - 512; dstbase = OW1 + layer*262144u; }
  else               { src = W2   + layer*262144; K = 1024; N = 256;  fl = r - 1024;dstbase = OW2 + layer*262144u; }
  int nk = K >> 5;
  int nt = fl / nk, ks = fl % nk;
  int n  = nt*16 + (lane & 15);
  int k0 = ks*32 + (lane >> 4)*8;
  __align__(16) __hip_bfloat16 tmp[8];
  #pragma unroll
  for (int j = 0; j < 8; ++j) tmp[j] = f2bf(src[(size_t)(k0 + j)*N + n]);
  *(uint4*)(ws + dstbase + (unsigned)fl*512u + lane*8) = *(const uint4*)tmp;
}

// ---------------------------------------------------------------------------
// K-split GEMM, 4 n-tiles/wave (4-wave blocks). Peak ~112 regs. (mk_qkv)
template<int NKTOT, class LoadA>
__device__ __forceinline__ void gemm_ks(const __hip_bfloat16* __restrict__ p,
                                        LoadA loadA, f32x4 (&C)[4][2])
{
  const unsigned ST = 4u*(unsigned)NKTOT*512u;
  bfv8 B[3][4];
  bfv8 a[2][4];
  #pragma unroll
  for (int i = 0; i < 4; ++i) {
    C[i][0] = (f32x4){0.f,0.f,0.f,0.f};
    C[i][1] = (f32x4){0.f,0.f,0.f,0.f};
  }
  #pragma unroll
  for (int k = 0; k < 4; ++k) B[0][k] = *(const bfv8*)(p + k*512);
  {
    const __hip_bfloat16* q = p + ST;
    #pragma unroll
    for (int k = 0; k < 4; ++k) B[1][k] = *(const bfv8*)(q + k*512);
  }
  loadA(0, a);
  #pragma unroll
  for (int s = 0; s < 8; ++s) {
    if (s + 2 < 8) {
      const __hip_bfloat16* q = p + (unsigned)((s+2) & 3)*ST + (unsigned)((s+2) >> 2)*2048u;
      #pragma unroll
      for (int k = 0; k < 4; ++k) B[(s+2)%3][k] = *(const bfv8*)(q + k*512);
    }
    if (s == 4) loadA(1, a);
    #pragma unroll
    for (int k = 0; k < 4; ++k) {
      C[s&3][0] = __builtin_amdgcn_mfma_f32_16x16x32_bf16(a[0][k], B[s%3][k], C[s&3][0], 0,0,0);
      C[s&3][1] = __builtin_amdgcn_mfma_f32_16x16x32_bf16(a[1][k], B[s%3][k], C[s&3][1], 0,0,0);
    }
  }
}

// K-quarter streaming GEMM, 2 n-tiles/wave (8-wave blocks). Demand ~48 regs:
// a[2][2]=16 (reloaded per K-quarter from LDS), B streamed 2 frags (8),
// C[2][2]=16. Spill-proof at the allocator's observed 52-VGPR choice.
template<int NKTOT, class LoadA>
__device__ __forceinline__ void gemm_ksq(const __hip_bfloat16* __restrict__ p,
                                         LoadA loadA, f32x4 (&C)[2][2])
{
  const unsigned ST = 8u*(unsigned)NKTOT*512u;
  bfv8 a[2][2];
  #pragma unroll
  for (int i = 0; i < 2; ++i) {
    C[i][0] = (f32x4){0.f,0.f,0.f,0.f};
    C[i][1] = (f32x4){0.f,0.f,0.f,0.f};
  }
  #pragma unroll
  for (int q = 0; q < 4; ++q) {
    loadA(q, a);
    #pragma unroll
    for (int i = 0; i < 2; ++i) {
      const __hip_bfloat16* b = p + (unsigned)i*ST + (unsigned)q*1024u;
      bfv8 B0 = *(const bfv8*)(b);
      bfv8 B1 = *(const bfv8*)(b + 512);
      C[i][0] = __builtin_amdgcn_mfma_f32_16x16x32_bf16(a[0][0], B0, C[i][0], 0,0,0);
      C[i][1] = __builtin_amdgcn_mfma_f32_16x16x32_bf16(a[1][0], B0, C[i][1], 0,0,0);
      C[i][0] = __builtin_amdgcn_mfma_f32_16x16x32_bf16(a[0][1], B1, C[i][0], 0,0,0);
      C[i][1] = __builtin_amdgcn_mfma_f32_16x16x32_bf16(a[1][1], B1, C[i][1], 0,0,0);
    }
  }
}

// ---------------------------------------------------------------------------
// one-pass LayerNorm helper (register version, used only by fallback kernels)
__device__ __forceinline__ void ln24_norm(float* z, float* redbuf, float g, float b, int tid) {
  const int lane = tid & 63, wid = tid >> 6;
  float s1[NROW], s2[NROW];
  #pragma unroll
  for (int r = 0; r < NROW; ++r) { float v = z[r]; s1[r] = v; s2[r] = v*v; }
  #pragma unroll
  for (int off = 32; off; off >>= 1) {
    #pragma unroll
    for (int r = 0; r < NROW; ++r) {
      s1[r] += __shfl_down(s1[r], off, 64);
      s2[r] += __shfl_down(s2[r], off, 64);
    }
  }
  if (lane == 0) {
    #pragma unroll
    for (int r = 0; r < NROW; ++r) { redbuf[wid*48 + r] = s1[r]; redbuf[wid*48 + 24 + r] = s2[r]; }
  }
  __syncthreads();
  #pragma unroll
  for (int r = 0; r < NROW; ++r) {
    float S1 = redbuf[r] + redbuf[48+r] + redbuf[96+r] + redbuf[144+r];
    float S2 = redbuf[24+r] + redbuf[72+r] + redbuf[120+r] + redbuf[168+r];
    float m  = S1 * (1.0f/256.0f);
    float var = S2 * (1.0f/256.0f) - m*m;
    float iv = rsqrtf(var + 1e-5f);
    z[r] = (z[r] - m) * iv * g + b;
  }
  __syncthreads();
}

// ===========================================================================
// ============ multi-kernel path ============================================
// ===========================================================================

// embed: block = 4 tokens (24 rows). LDS-resident z + LDS-partial LN ->
// ~40 live regs, spill-proof at any VGPR allocation.
__global__ __launch_bounds__(256) void mk_embed(
    const float* __restrict__ x,
    const float* __restrict__ W_raw, const float* __restrict__ b_raw,
    const float* __restrict__ wl_emb, const float* __restrict__ pos_emb,
    const float* __restrict__ hop_emb,
    const float* __restrict__ ln_g, const float* __restrict__ ln_b,
    const float* __restrict__ W_res, const float* __restrict__ b_res,
    __hip_bfloat16* __restrict__ h0, float* __restrict__ res, int t0)
{
  __shared__ float xbuf[24][128];     // 12 KB
  __shared__ float zb[24][256];       // 24 KB
  __shared__ float part[2][24][8];
  __shared__ float stat[24][2];
  const int tid = threadIdx.x;
  const int bt  = blockIdx.x;

  for (int idx = tid; idx < 24*128; idx += 256) {
    int tt = idx / 768, rem = idx % 768;
    int s = rem >> 7, f = rem & 127;
    int t = t0 + bt*4 + tt, g = t >> 7, i = t & 127;
    int node;
    if (s < 2) node = i;
    else { int j = s - 2; node = (j < i) ? j : (j + 1); }
    xbuf[tt*6+s][f] = x[(g*128 + node)*128 + f];
  }
  __syncthreads();

  {
    float z[NROW];
    #pragma unroll
    for (int r = 0; r < NROW; ++r) z[r] = 0.f;
    #pragma unroll 2
    for (int f4 = 0; f4 < 32; ++f4) {
      float w0 = W_raw[(f4*4+0)*256 + tid];
      float w1 = W_raw[(f4*4+1)*256 + tid];
      float w2 = W_raw[(f4*4+2)*256 + tid];
      float w3 = W_raw[(f4*4+3)*256 + tid];
      #pragma unroll
      for (int r = 0; r < NROW; ++r) {
        float4 xv = *(const float4*)(&xbuf[r][f4*4]);
        z[r] += xv.x*w0 + xv.y*w1 + xv.z*w2 + xv.w*w3;
      }
    }
    float br  = b_raw[tid];
    float wl  = wl_emb[tid];
    float hp0 = hop_emb[5*256 + tid];
    float hp1 = hop_emb[511*256 + tid];
    float p[6];
    #pragma unroll
    for (int s = 0; s < 6; ++s) p[s] = pos_emb[s*256 + tid];
    #pragma unroll
    for (int r = 0; r < NROW; ++r) {
      int s = r % 6;
      zb[r][tid] = z[r] + br + p[s] + wl + ((s < 2) ? hp0 : hp1);
    }
  }
  __syncthreads();

  if (tid < 192) {
    int row = tid >> 3, seg = tid & 7;
    float s1 = 0.f, s2 = 0.f;
    #pragma unroll
    for (int i = 0; i < 32; ++i) {
      int col = seg*32 + ((i + tid) & 31);
      float v = zb[row][col];
      s1 += v; s2 += v*v;
    }
    part[0][row][seg] = s1; part[1][row][seg] = s2;
  }
  __syncthreads();
  if (tid < 24) {
    float S1 = 0.f, S2 = 0.f;
    #pragma unroll
    for (int k = 0; k < 8; ++k) { S1 += part[0][tid][k]; S2 += part[1][tid][k]; }
    float m = S1 * (1.0f/256.0f);
    float var = S2 * (1.0f/256.0f) - m*m;
    stat[tid][0] = m; stat[tid][1] = rsqrtf(var + 1e-5f);
  }
  __syncthreads();
  {
    float g = ln_g[tid], b = ln_b[tid];
    #pragma unroll
    for (int r = 0; r < NROW; ++r) {
      float v = (zb[r][tid] - stat[r][0]) * stat[r][1] * g + b;
      h0[(size_t)(bt*24 + r)*256 + tid] = f2bf(v);
    }
  }

  if (t0 + bt*4 < 256) {
    __syncthreads();
    for (int idx = tid; idx < 24*128; idx += 256) {
      int tt = idx / 768, rem = idx % 768;
      int s = rem >> 7, f = rem & 127;
      int t = t0 + bt*4 + tt;
      xbuf[tt*6+s][f] = x[(t*128 + s)*128 + f];
    }
    __syncthreads();
    float resv[NROW];
    float brr = b_res[tid];
    #pragma unroll
    for (int r = 0; r < NROW; ++r) resv[r] = brr;
    #pragma unroll 2
    for (int f4 = 0; f4 < 32; ++f4) {
      float w0 = W_res[(f4*4+0)*256 + tid];
      float w1 = W_res[(f4*4+1)*256 + tid];
      float w2 = W_res[(f4*4+2)*256 + tid];
      float w3 = W_res[(f4*4+3)*256 + tid];
      #pragma unroll
      for (int r = 0; r < NROW; ++r) {
        float4 xv = *(const float4*)(&xbuf[r][f4*4]);
        resv[r] += xv.x*w0 + xv.y*w1 + xv.z*w2 + xv.w*w3;
      }
    }
    #pragma unroll
    for (int r = 0; r < NROW; ++r)
      res[(size_t)((t0 + bt*4)*6 + r)*256 + tid] = resv[r];
  }
}

// stage 32x256 bf16 rows into swz LDS -- 256-thread version
__device__ __forceinline__ void stageA(const __hip_bfloat16* __restrict__ src,
                                       int row0, int stride, char* aT, int tid) {
  #pragma unroll
  for (int k = 0; k < 4; ++k) {
    int cid = tid + k*256;
    int row = cid >> 5, cc = cid & 31;
    uint4 v = *(const uint4*)(src + (size_t)(row0 + row)*stride + cc*8);
    *(uint4*)(aT + swz(row, cc*16)) = v;
  }
}
// 512-thread version
__device__ __forceinline__ void stageA512(const __hip_bfloat16* __restrict__ src,
                                          int row0, int stride, char* aT, int tid) {
  #pragma unroll
  for (int k = 0; k < 2; ++k) {
    int cid = tid + k*512;
    int row = cid >> 5, cc = cid & 31;
    uint4 v = *(const uint4*)(src + (size_t)(row0 + row)*stride + cc*8);
    *(uint4*)(aT + swz(row, cc*16)) = v;
  }
}

// qkv GEMM: 256 threads, M=32, N=768.
__global__ __launch_bounds__(256) void mk_qkv(
    const __hip_bfloat16* __restrict__ h, const __hip_bfloat16* __restrict__ Wf,
    const float* __restrict__ bqkv_l, __hip_bfloat16* __restrict__ qkv)
{
  __shared__ __align__(16) char aT[16384];
  const int tid = threadIdx.x;
  const int lane = tid & 63, wid = tid >> 6;
  const int l15 = lane & 15, l4 = lane >> 4;
  const int row0 = blockIdx.x * 32;

  stageA(h, row0, 256, aT, tid);
  __syncthreads();

  auto lA = [&](int kh, bfv8 (&a)[2][4]) {
    #pragma unroll
    for (int k = 0; k < 4; ++k) {
      a[0][k] = *(const bfv8*)(aT + swz(l15,      (kh*4 + k)*64 + l4*16));
      a[1][k] = *(const bfv8*)(aT + swz(16 + l15, (kh*4 + k)*64 + l4*16));
    }
  };

  #pragma unroll 1
  for (int sub = 0; sub < 3; ++sub) {
    f32x4 C[4][2];
    gemm_ks<8>(Wf + (unsigned)(sub*16 + wid)*8u*512u + lane*8, lA, C);
    #pragma unroll
    for (int i = 0; i < 4; ++i) {
      int col = sub*256 + (wid + i*4)*16 + l15;
      float bb = bqkv_l[col];
      #pragma unroll
      for (int j = 0; j < 4; ++j) {
        qkv[(size_t)(row0 + l4*4 + j)*768 + col]      = f2bf(C[i][0][j] + bb);
        qkv[(size_t)(row0 + 16 + l4*4 + j)*768 + col] = f2bf(C[i][1][j] + bb);
      }
    }
  }
}

// attention: 256 threads, VALU; 32 tokens/block, thread = (token, head).
__global__ __launch_bounds__(256) void mk_attn(__hip_bfloat16* __restrict__ qkv)
{
  const int tid = threadIdx.x;
  const int tl = tid >> 3, hh = tid & 7;
  const size_t rowbase = (size_t)(blockIdx.x*32 + tl)*6;
  const int cb = hh*32;

  #pragma unroll 1
  for (int q = 0; q < 6; ++q) {
    const __hip_bfloat16* qr = qkv + (rowbase + q)*768 + cb;
    bfv8 qv[4];
    #pragma unroll
    for (int p4 = 0; p4 < 4; ++p4) qv[p4] = *(const bfv8*)(qr + p4*8);
    float a[6]; float mx = -1e30f;
    #pragma unroll
    for (int sp = 0; sp < 6; ++sp) {
      const __hip_bfloat16* kr = qkv + (rowbase + sp)*768 + 256 + cb;
      float s = 0.f;
      #pragma unroll
      for (int p4 = 0; p4 < 4; ++p4) {
        bfv8 kv = *(const bfv8*)(kr + p4*8);
        #pragma unroll
        for (int j = 0; j < 8; ++j) s += bfs2f(qv[p4][j]) * bfs2f(kv[j]);
      }
      a[sp] = s * 0.17677669529663687f;
      mx = fmaxf(mx, a[sp]);
    }
    float sum = 0.f;
    #pragma unroll
    for (int sp = 0; sp < 6; ++sp) { a[sp] = __expf(a[sp] - mx); sum += a[sp]; }
    float inv = 1.f / sum;
    #pragma unroll
    for (int sp = 0; sp < 6; ++sp) a[sp] *= inv;
    float oc[32];
    #pragma unroll
    for (int j = 0; j < 32; ++j) oc[j] = 0.f;
    #pragma unroll
    for (int sp = 0; sp < 6; ++sp) {
      const __hip_bfloat16* vr = qkv + (rowbase + sp)*768 + 512 + cb;
      float asp = a[sp];
      #pragma unroll
      for (int p4 = 0; p4 < 4; ++p4) {
        bfv8 vv = *(const bfv8*)(vr + p4*8);
        #pragma unroll
        for (int j = 0; j < 8; ++j) oc[p4*8 + j] += asp * bfs2f(vv[j]);
      }
    }
    __hip_bfloat16* orow = qkv + (rowbase + q)*768 + cb;
    #pragma unroll
    for (int p4 = 0; p4 < 4; ++p4) {
      __align__(16) __hip_bfloat16 ob[8];
      #pragma unroll
      for (int j = 0; j < 8; ++j) ob[j] = f2bf(oc[p4*8 + j]);
      *(uint4*)(orow + p4*8) = *(const uint4*)ob;
    }
  }
}

// Wo GEMM + residual + LN1: 512 threads, spill-proof gemm_ksq.
// LDS overlay: zb (fp32 [32][256], 32K) reuses aT's region (aT dead after the
// GEMM barrier). 37120 B total -> 4 blocks/CU (was 52.5 KB / 3 blocks).
__global__ __launch_bounds__(512) void mk_wo_ln(
    const __hip_bfloat16* __restrict__ qkv /* o at stride 768 */,
    const __hip_bfloat16* __restrict__ h,
    const float* __restrict__ res,
    const __hip_bfloat16* __restrict__ Wf, const float* __restrict__ bo_l,
    const float* __restrict__ gln, const float* __restrict__ bln,
    __hip_bfloat16* __restrict__ h1, int t0)
{
  __shared__ __align__(16) char smem[37120];
  char* aT = smem;                                        // [0, 16K)
  float (*zb)[256]      = (float (*)[256])smem;           // [0, 32K) after GEMM
  float (*part)[32][16] = (float (*)[32][16])(smem + 32768);
  float (*stat)[2]      = (float (*)[2])(smem + 32768 + 4096);
  const int tid = threadIdx.x;
  const int lane = tid & 63, wid = tid >> 6;      // wid 0..7
  const int l15 = lane & 15, l4 = lane >> 4;
  const int row0 = blockIdx.x * 32;

  stageA512(qkv, row0, 768, aT, tid);
  __syncthreads();

  auto lAq = [&](int q, bfv8 (&a)[2][2]) {
    #pragma unroll
    for (int k = 0; k < 2; ++k) {
      a[0][k] = *(const bfv8*)(aT + swz(l15,      (q*2 + k)*64 + l4*16));
      a[1][k] = *(const bfv8*)(aT + swz(16 + l15, (q*2 + k)*64 + l4*16));
    }
  };

  {
    f32x4 C[2][2];
    gemm_ksq<8>(Wf + (unsigned)wid*8u*512u + lane*8, lAq, C);
    __syncthreads();    // all aT reads done before zb overlays it
    #pragma unroll
    for (int i = 0; i < 2; ++i) {
      int col = (wid + i*8)*16 + l15;
      #pragma unroll
      for (int j = 0; j < 4; ++j) {
        zb[l4*4 + j][col]      = C[i][0][j];
        zb[16 + l4*4 + j][col] = C[i][1][j];
      }
    }
  }
  __syncthreads();

  #pragma unroll 4
  for (int it = 0; it < 16; ++it) {
    int idx = tid + it*512, row = idx >> 8, col = idx & 255;
    float v = zb[row][col] + bf2f(h[(size_t)(row0 + row)*256 + col]) + bo_l[col];
    int grow = t0*6 + row0 + row;
    if (grow < 1536) v += res[(size_t)grow*256 + col];
    zb[row][col] = v;
  }
  __syncthreads();

  {
    int row = tid >> 4, seg = tid & 15;
    float s1 = 0.f, s2 = 0.f;
    #pragma unroll
    for (int i = 0; i < 16; ++i) {
      int col = seg*16 + ((i + tid) & 15);
      float v = zb[row][col];
      s1 += v; s2 += v*v;
    }
    part[0][row][seg] = s1; part[1][row][seg] = s2;
  }
  __syncthreads();
  if (tid < 32) {
    float S1 = 0.f, S2 = 0.f;
    #pragma unroll
    for (int k = 0; k < 16; ++k) { S1 += part[0][tid][k]; S2 += part[1][tid][k]; }
    float m = S1 * (1.0f/256.0f);
    float var = S2 * (1.0f/256.0f) - m*m;
    stat[tid][0] = m; stat[tid][1] = rsqrtf(var + 1e-5f);
  }
  __syncthreads();
  #pragma unroll 4
  for (int it = 0; it < 16; ++it) {
    int idx = tid + it*512, row = idx >> 8, col = idx & 255;
    float v = (zb[row][col] - stat[row][0]) * stat[row][1] * gln[col] + bln[col];
    h1[(size_t)(row0 + row)*256 + col] = f2bf(v);
  }
}

// FFN fused + residual + LN2: 512 threads, spill-proof gemm_ksq.
// LDS overlay (49152 B -> 3 blocks/CU, was 70144 / 2 blocks):
//  [0,32K):  aT (16K) + gT (16K) during GEMMs; fp32 zf [32][256] after.
//  [32K,48K): ff bf16 accumulator [32][256] (r10-proven bf16 accumulation);
//             part (4K) + stat (256) overlay ff once ff is consumed.
__global__ __launch_bounds__(512) void mk_ffn(
    const __hip_bfloat16* __restrict__ h1,
    const __hip_bfloat16* __restrict__ W1f, const __hip_bfloat16* __restrict__ W2f,
    const float* __restrict__ b1_l, const float* __restrict__ b2_l,
    const float* __restrict__ gln, const float* __restrict__ bln,
    const float* __restrict__ res, __hip_bfloat16* __restrict__ hout,
    float* __restrict__ outp, int t0)
{
  __shared__ __align__(16) char smem[49152];
  char* aT = smem;                                            // [0, 16K)
  char* gT = smem + 16384;                                    // [16K, 32K)
  float (*zf)[256]          = (float (*)[256])smem;           // [0, 32K) after GEMMs
  __hip_bfloat16 (*ff)[256] = (__hip_bfloat16 (*)[256])(smem + 32768);  // [32K, 48K)
  float (*part)[32][16]     = (float (*)[32][16])(smem + 32768);        // after ff dead
  float (*stat)[2]          = (float (*)[2])(smem + 32768 + 4096);
  const int tid = threadIdx.x;
  const int lane = tid & 63, wid = tid >> 6;      // wid 0..7
  const int l15 = lane & 15, l4 = lane >> 4;
  const int row0 = blockIdx.x * 32;

  stageA512(h1, row0, 256, aT, tid);
  {  // zero ff (16 KB): 512 threads x 32 B
    uint4 zz = {0u,0u,0u,0u};
    *(uint4*)((char*)ff + tid*16) = zz;
    *(uint4*)((char*)ff + 8192 + tid*16) = zz;
  }
  __syncthreads();

  auto lAq = [&](int q, bfv8 (&a)[2][2]) {
    #pragma unroll
    for (int k = 0; k < 2; ++k) {
      a[0][k] = *(const bfv8*)(aT + swz(l15,      (q*2 + k)*64 + l4*16));
      a[1][k] = *(const bfv8*)(aT + swz(16 + l15, (q*2 + k)*64 + l4*16));
    }
  };
  auto lGq = [&](int q, bfv8 (&a)[2][2]) {
    #pragma unroll
    for (int k = 0; k < 2; ++k) {
      a[0][k] = *(const bfv8*)(gT + swz(l15,      (q*2 + k)*64 + l4*16));
      a[1][k] = *(const bfv8*)(gT + swz(16 + l15, (q*2 + k)*64 + l4*16));
    }
  };

  #pragma unroll 1
  for (int ch = 0; ch < 4; ++ch) {
    {
      f32x4 C[2][2];
      gemm_ksq<8>(W1f + (unsigned)(ch*16 + wid)*8u*512u + lane*8, lAq, C);
      #pragma unroll
      for (int i = 0; i < 2; ++i) {
        int colR = (wid + i*8)*16 + l15;
        float bb = b1_l[ch*256 + colR];
        int col2 = colR*2;
        #pragma unroll
        for (int j = 0; j < 4; ++j) {
          *(__hip_bfloat16*)(gT + swz(l4*4 + j, col2))      = f2bf(gelu_f(C[i][0][j] + bb));
          *(__hip_bfloat16*)(gT + swz(16 + l4*4 + j, col2)) = f2bf(gelu_f(C[i][1][j] + bb));
        }
      }
    }
    __syncthreads();   // g visible
    {
      f32x4 C[2][2];
      gemm_ksq<32>(W2f + (unsigned)(wid*32 + ch*8)*512u + lane*8, lGq, C);
      #pragma unroll
      for (int i = 0; i < 2; ++i) {
        int col = (wid + i*8)*16 + l15;
        #pragma unroll
        for (int j = 0; j < 4; ++j) {
          { __hip_bfloat16* pp = &ff[l4*4 + j][col];      *pp = f2bf(bf2f(*pp) + C[i][0][j]); }
          { __hip_bfloat16* pp = &ff[16 + l4*4 + j][col]; *pp = f2bf(bf2f(*pp) + C[i][1][j]); }
        }
      }
    }
    __syncthreads();   // g reads done (also: aT/gT dead after last iteration)
  }

  // residual + bias: ff (bf16) -> zf (fp32, overlays aT/gT which are now dead)
  #pragma unroll 4
  for (int it = 0; it < 16; ++it) {
    int idx = tid + it*512, row = idx >> 8, col = idx & 255;
    float v = bf2f(ff[row][col]) + bf2f(h1[(size_t)(row0 + row)*256 + col]) + b2_l[col];
    int grow = t0*6 + row0 + row;
    if (grow < 1536) v += res[(size_t)grow*256 + col];
    zf[row][col] = v;
  }
  __syncthreads();     // all ff reads done before part/stat overlay it
  {
    int row = tid >> 4, seg = tid & 15;
    float s1 = 0.f, s2 = 0.f;
    #pragma unroll
    for (int i = 0; i < 16; ++i) {
      int col = seg*16 + ((i + tid) & 15);
      float v = zf[row][col];
      s1 += v; s2 += v*v;
    }
    part[0][row][seg] = s1; part[1][row][seg] = s2;
  }
  __syncthreads();
  if (tid < 32) {
    float S1 = 0.f, S2 = 0.f;
    #pragma unroll
    for (int k = 0; k < 16; ++k) { S1 += part[0][tid][k]; S2 += part[1][tid][k]; }
    float m = S1 * (1.0f/256.0f);
    float var = S2 * (1.0f/256.0f) - m*m;
    stat[tid][0] = m; stat[tid][1] = rsqrtf(var + 1e-5f);
  }
  __syncthreads();
  #pragma unroll 4
  for (int it = 0; it < 16; ++it) {
    int idx = tid + it*512, row = idx >> 8, col = idx & 255;
    float v = (zf[row][col] - stat[row][0]) * stat[row][1] * gln[col] + bln[col];
    hout[(size_t)(row0 + row)*256 + col] = f2bf(v);
    if (outp && ((row0 + row) % 6 == 0)) {
      int gtok = t0 + (row0 + row) / 6;
      outp[(size_t)gtok*256 + col] = v;
    }
  }
}

// ===========================================================================
// ============ round-10 fused champion (fallback) ===========================
// ===========================================================================
__global__ __launch_bounds__(256, 2) void gb_mfma_kernel(
    const float* __restrict__ x,
    const float* __restrict__ W_raw, const float* __restrict__ b_raw,
    const float* __restrict__ wl_emb, const float* __restrict__ pos_emb,
    const float* __restrict__ hop_emb,
    const float* __restrict__ ln_g, const float* __restrict__ ln_b,
    const float* __restrict__ bqkv, const float* __restrict__ bo,
    const float* __restrict__ n1g,  const float* __restrict__ n1b,
    const float* __restrict__ b1,   const float* __restrict__ b2,
    const float* __restrict__ n2g,  const float* __restrict__ n2b,
    const float* __restrict__ W_res, const float* __restrict__ b_res,
    const __hip_bfloat16* __restrict__ wf,
    float* __restrict__ out)
{
  __shared__ __align__(16) char smem[75392];
  char* hsb = smem;
  char* uA  = smem + 16384;
  char* uB  = smem + 53632;
  float (*attw)[24][6] = (float (*)[24][6])(smem + 70016);
  float* redbuf = (float*)(smem + 74624);

  __hip_bfloat16 (*qkvs)[776] = (__hip_bfloat16 (*)[776])uA;
  float (*fbuf)[264] = (float (*)[264])uA;
  float (*xbuf)[128] = (float (*)[128])uA;

  const int tid  = threadIdx.x;
  const int bt   = blockIdx.x;
  const int lane = tid & 63, wid = tid >> 6;
  const int l15  = lane & 15, l4 = lane >> 4;

  auto mkA = [l15, l4](const char* buf) {
    return [buf, l15, l4](int kh, bfv8 (&a)[2][4]) {
      #pragma unroll
      for (int k = 0; k < 4; ++k) {
        a[0][k] = *(const bfv8*)(buf + swz(l15,      (kh*4 + k)*64 + l4*16));
        a[1][k] = *(const bfv8*)(buf + swz(16 + l15, (kh*4 + k)*64 + l4*16));
      }
    };
  };

  {
    uint4 zz = {0u,0u,0u,0u};
    *(uint4*)(hsb + 24*512 + tid*16) = zz;
    *(uint4*)(uB  + 24*512 + tid*16) = zz;
  }

  for (int idx = tid; idx < TB*6*128; idx += 256) {
    int tt = idx / 768, rem = idx % 768;
    int s = rem >> 7, f = rem & 127;
    int t = bt*TB + tt, g = t >> 7, i = t & 127;
    int node;
    if (s < 2) node = i;
    else { int j = s - 2; node = (j < i) ? j : (j + 1); }
    xbuf[tt*6+s][f] = x[(g*128 + node)*128 + f];
  }
  __syncthreads();

  {
    float z[NROW];
    #pragma unroll
    for (int r = 0; r < NROW; ++r) z[r] = 0.f;
    #pragma unroll 2
    for (int f4 = 0; f4 < 32; ++f4) {
      float w0 = W_raw[(f4*4+0)*256 + tid];
      float w1 = W_raw[(f4*4+1)*256 + tid];
      float w2 = W_raw[(f4*4+2)*256 + tid];
      float w3 = W_raw[(f4*4+3)*256 + tid];
      #pragma unroll
      for (int r = 0; r < NROW; ++r) {
        float4 xv = *(const float4*)(&xbuf[r][f4*4]);
        z[r] += xv.x*w0 + xv.y*w1 + xv.z*w2 + xv.w*w3;
      }
    }
    float br  = b_raw[tid];
    float wl  = wl_emb[tid];
    float hp0 = hop_emb[5*256 + tid];
    float hp1 = hop_emb[511*256 + tid];
    float p[6];
    #pragma unroll
    for (int s = 0; s < 6; ++s) p[s] = pos_emb[s*256 + tid];
    #pragma unroll
    for (int r = 0; r < NROW; ++r) {
      int s = r % 6;
      z[r] += br + p[s] + wl + ((s < 2) ? hp0 : hp1);
    }
    ln24_norm(z, redbuf, ln_g[tid], ln_b[tid], tid);
    #pragma unroll
    for (int r = 0; r < NROW; ++r)
      *(__hip_bfloat16*)(hsb + swz(r, tid*2)) = f2bf(z[r]);
  }

  unsigned resp[12];
  #pragma unroll
  for (int k = 0; k < 12; ++k) resp[k] = 0u;
  if (bt < 64) {
    __syncthreads();
    for (int idx = tid; idx < TB*6*128; idx += 256) {
      int tt = idx / 768, rem = idx % 768;
      int s = rem >> 7, f = rem & 127;
      int t = bt*TB + tt;
      xbuf[tt*6+s][f] = x[(t*128 + s)*128 + f];
    }
    __syncthreads();
    float resv[NROW];
    float brr = b_res[tid];
    #pragma unroll
    for (int r = 0; r < NROW; ++r) resv[r] = brr;
    #pragma unroll 2
    for (int f4 = 0; f4 < 32; ++f4) {
      float w0 = W_res[(f4*4+0)*256 + tid];
      float w1 = W_res[(f4*4+1)*256 + tid];
      float w2 = W_res[(f4*4+2)*256 + tid];
      float w3 = W_res[(f4*4+3)*256 + tid];
      #pragma unroll
      for (int r = 0; r < NROW; ++r) {
        float4 xv = *(const float4*)(&xbuf[r][f4*4]);
        resv[r] += xv.x*w0 + xv.y*w1 + xv.z*w2 + xv.w*w3;
      }
    }
    #pragma unroll
    for (int k = 0; k < 12; ++k) {
      unsigned lo = __float_as_uint(resv[2*k])   >> 16;
      unsigned hi = __float_as_uint(resv[2*k+1]) & 0xffff0000u;
      resp[k] = hi | lo;
    }
  }

  float z[NROW];

  #pragma unroll 1
  for (int l = 0; l < 4; ++l) {
    const __hip_bfloat16* WQf = wf + OWQ + (unsigned)l*196608u;
    const __hip_bfloat16* WOf = wf + OWO + (unsigned)l*65536u;
    const __hip_bfloat16* W1f = wf + OW1 + (unsigned)l*262144u;
    const __hip_bfloat16* W2f = wf + OW2 + (unsigned)l*262144u;

    __syncthreads();

    {
      auto lA = mkA(hsb);
      #pragma unroll 1
      for (int sub = 0; sub < 3; ++sub) {
        f32x4 C[4][2];
        gemm_ks<8>(WQf + (unsigned)(sub*16 + wid)*8u*512u + lane*8, lA, C);
        #pragma unroll
        for (int i = 0; i < 4; ++i) {
          int gcol = sub*256 + (wid + i*4)*16 + l15;
          float bbv = bqkv[l*768 + gcol];
          #pragma unroll
          for (int j = 0; j < 4; ++j) {
            qkvs[l4*4 + j][gcol] = f2bf(C[i][0][j] + bbv);
            int r1 = 16 + l4*4 + j;
            if (r1 < NROW) qkvs[r1][gcol] = f2bf(C[i][1][j] + bbv);
          }
        }
      }
    }
    __syncthreads();

    if (tid < 192) {
      int hh = tid / 24, r = tid % 24;
      int tt6 = (r / 6) * 6;
      bfv8 qv[4];
      #pragma unroll
      for (int p4 = 0; p4 < 4; ++p4) qv[p4] = *(const bfv8*)(&qkvs[r][hh*32 + p4*8]);
      float sc[6];
      #pragma unroll
      for (int sp = 0; sp < 6; ++sp) {
        float s = 0.f;
        #pragma unroll
        for (int p4 = 0; p4 < 4; ++p4) {
          bfv8 kv = *(const bfv8*)(&qkvs[tt6 + sp][256 + hh*32 + p4*8]);
          #pragma unroll
          for (int j = 0; j < 8; ++j) s += bfs2f(qv[p4][j]) * bfs2f(kv[j]);
        }
        sc[sp] = s * 0.17677669529663687f;
      }
      float mx = sc[0];
      #pragma unroll
      for (int sp = 1; sp < 6; ++sp) mx = fmaxf(mx, sc[sp]);
      float sum = 0.f;
      #pragma unroll
      for (int sp = 0; sp < 6; ++sp) { sc[sp] = __expf(sc[sp] - mx); sum += sc[sp]; }
      float inv = 1.f / sum;
      #pragma unroll
      for (int sp = 0; sp < 6; ++sp) attw[hh][r][sp] = sc[sp] * inv;
    }
    __syncthreads();

    {
      int hh = tid >> 5, c = tid & 31;
      int col2 = (hh*32 + c)*2;
      #pragma unroll
      for (int tt = 0; tt < 4; ++tt) {
        float vv[6];
        #pragma unroll
        for (int sp = 0; sp < 6; ++sp) vv[sp] = bf2f(qkvs[tt*6 + sp][512 + hh*32 + c]);
        #pragma unroll
        for (int q = 0; q < 6; ++q) {
          float o = 0.f;
          #pragma unroll
          for (int sp = 0; sp < 6; ++sp) o += attw[hh][tt*6 + q][sp] * vv[sp];
          *(__hip_bfloat16*)(uB + swz(tt*6 + q, col2)) = f2bf(o);
        }
      }
    }
    __syncthreads();

    {
      f32x4 C[4][2];
      gemm_ks<8>(WOf + (unsigned)wid*8u*512u + lane*8, mkA(uB), C);
      #pragma unroll
      for (int i = 0; i < 4; ++i) {
        int col = (wid + i*4)*16 + l15;
        #pragma unroll
        for (int j = 0; j < 4; ++j) {
          fbuf[l4*4 + j][col] = C[i][0][j];
          int r1 = 16 + l4*4 + j;
          if (r1 < NROW) fbuf[r1][col] = C[i][1][j];
        }
      }
    }
    __syncthreads();

    {
      float bov = bo[l*256 + tid];
      #pragma unroll
      for (int r = 0; r < NROW; ++r)
        z[r] = bf2f(*(const __hip_bfloat16*)(hsb + swz(r, tid*2)))
             + unpk(resp[r >> 1], r & 1) + fbuf[r][tid] + bov;
    }
    #pragma unroll
    for (int k = 0; k < 12; ++k) *(unsigned*)(uB + (k*256 + tid)*4) = 0u;
    ln24_norm(z, redbuf, n1g[l*256 + tid], n1b[l*256 + tid], tid);
    #pragma unroll
    for (int r = 0; r < NROW; ++r)
      *(__hip_bfloat16*)(hsb + swz(r, tid*2)) = f2bf(z[r]);
    {
      uint4 zz = {0u,0u,0u,0u};
      *(uint4*)(uA + 24*512 + tid*16) = zz;
      *(uint4*)(uA + 16384 + 24*512 + tid*16) = zz;
    }
    __syncthreads();

    {
      auto lAh = mkA(hsb);
      #pragma unroll 1
      for (int ch = 0; ch < 4; ++ch) {
        char* gb = uA + (ch & 1)*16384;
        {
          f32x4 C[4][2];
          gemm_ks<8>(W1f + (unsigned)(ch*128 + wid*8)*512u + lane*8, lAh, C);
          #pragma unroll
          for (int i = 0; i < 4; ++i) {
            float bbv = b1[l*1024 + ch*256 + (wid + i*4)*16 + l15];
            int col2 = ((wid + i*4)*16 + l15)*2;
            #pragma unroll
            for (int j = 0; j < 4; ++j) {
              *(__hip_bfloat16*)(gb + swz(l4*4 + j, col2)) = f2bf(gelu_f(C[i][0][j] + bbv));
              int r1 = 16 + l4*4 + j;
              if (r1 < NROW)
                *(__hip_bfloat16*)(gb + swz(r1, col2)) = f2bf(gelu_f(C[i][1][j] + bbv));
            }
          }
        }
        __syncthreads();
        {
          f32x4 C[4][2];
          gemm_ks<32>(W2f + (unsigned)(wid*32 + ch*8)*512u + lane*8, mkA(gb), C);
          #pragma unroll
          for (int i = 0; i < 4; ++i) {
            int col2 = ((wid + i*4)*16 + l15)*2;
            #pragma unroll
            for (int j = 0; j < 4; ++j) {
              {
                __hip_bfloat16* pp = (__hip_bfloat16*)(uB + (l4*4 + j)*512 + col2);
                *pp = f2bf(bf2f(*pp) + C[i][0][j]);
              }
              int r1 = 16 + l4*4 + j;
              if (r1 < NROW) {
                __hip_bfloat16* pp = (__hip_bfloat16*)(uB + r1*512 + col2);
                *pp = f2bf(bf2f(*pp) + C[i][1][j]);
              }
            }
          }
        }
      }
    }
    __syncthreads();

    {
      float b2v = b2[l*256 + tid];
      #pragma unroll
      for (int r = 0; r < NROW; ++r)
        z[r] = bf2f(*(const __hip_bfloat16*)(hsb + swz(r, tid*2)))
             + unpk(resp[r >> 1], r & 1)
             + bf2f(*(const __hip_bfloat16*)(uB + r*512 + tid*2)) + b2v;
    }
    ln24_norm(z, redbuf, n2g[l*256 + tid], n2b[l*256 + tid], tid);
    #pragma unroll
    for (int r = 0; r < NROW; ++r)
      *(__hip_bfloat16*)(hsb + swz(r, tid*2)) = f2bf(z[r]);
  }

  #pragma unroll
  for (int tt = 0; tt < TB; ++tt)
    out[(bt*TB + tt)*256 + tid] = z[tt*6];
}

// ---------------------------------------------------------------------------
// Pure-VALU fallback (round-2 proven).
__global__ __launch_bounds__(256, 2) void gb_fused_fallback(
    const float* __restrict__ x,
    const float* __restrict__ W_raw, const float* __restrict__ b_raw,
    const float* __restrict__ wl_emb, const float* __restrict__ pos_emb,
    const float* __restrict__ hop_emb,
    const float* __restrict__ ln_g, const float* __restrict__ ln_b,
    const float* __restrict__ Wqkv, const float* __restrict__ bqkv,
    const float* __restrict__ Wo,   const float* __restrict__ bo,
    const float* __restrict__ n1g,  const float* __restrict__ n1b,
    const float* __restrict__ W1,   const float* __restrict__ b1,
    const float* __restrict__ W2,   const float* __restrict__ b2,
    const float* __restrict__ n2g,  const float* __restrict__ n2b,
    const float* __restrict__ W_res, const float* __restrict__ b_res,
    float* __restrict__ out)
{
  __shared__ float hs[NROW][256];
  __shared__ __align__(16) char bufraw[NROW*768*2];
  __shared__ float attw[8][NROW][8];
  __shared__ float redbuf[192];

  __hip_bfloat16 (*qkvs)[768] = (__hip_bfloat16 (*)[768])bufraw;
  float (*fbuf)[256] = (float (*)[256])bufraw;
  float (*xbuf)[128] = (float (*)[128])bufraw;

  const int tid = threadIdx.x;
  const int bt  = blockIdx.x;

  for (int idx = tid; idx < TB*6*128; idx += 256) {
    int tt = idx / 768, rem = idx % 768;
    int s = rem >> 7, f = rem & 127;
    int t = bt*TB + tt, g = t >> 7, i = t & 127;
    int node;
    if (s < 2) node = i;
    else { int j = s - 2; node = (j < i) ? j : (j + 1); }
    xbuf[tt*6+s][f] = x[(g*128 + node)*128 + f];
  }
  __syncthreads();

  float z[NROW];
  {
    #pragma unroll
    for (int r = 0; r < NROW; ++r) z[r] = 0.f;
    #pragma unroll 4
    for (int f = 0; f < 128; ++f) {
      float w = W_raw[f*256 + tid];
      #pragma unroll
      for (int r = 0; r < NROW; ++r) z[r] += xbuf[r][f] * w;
    }
    float br  = b_raw[tid];
    float wl  = wl_emb[tid];
    float hp0 = hop_emb[5*256 + tid];
    float hp1 = hop_emb[511*256 + tid];
    float p[6];
    #pragma unroll
    for (int s = 0; s < 6; ++s) p[s] = pos_emb[s*256 + tid];
    #pragma unroll
    for (int r = 0; r < NROW; ++r) {
      int s = r % 6;
      z[r] += br + p[s] + wl + ((s < 2) ? hp0 : hp1);
    }
  }
  ln24_norm(z, redbuf, ln_g[tid], ln_b[tid], tid);
  #pragma unroll
  for (int r = 0; r < NROW; ++r) hs[r][tid] = z[r];

  float resv[NROW];
  #pragma unroll
  for (int r = 0; r < NROW; ++r) resv[r] = 0.f;
  if (bt < 64) {
    __syncthreads();
    for (int idx = tid; idx < TB*6*128; idx += 256) {
      int tt = idx / 768, rem = idx % 768;
      int s = rem >> 7, f = rem & 127;
      int t = bt*TB + tt;
      xbuf[tt*6+s][f] = x[(t*128 + s)*128 + f];
    }
    __syncthreads();
    #pragma unroll 4
    for (int f = 0; f < 128; ++f) {
      float w = W_res[f*256 + tid];
      #pragma unroll
      for (int r = 0; r < NROW; ++r) resv[r] += xbuf[r][f] * w;
    }
    float brr = b_res[tid];
    #pragma unroll
    for (int r = 0; r < NROW; ++r) resv[r] += brr;
  }

  for (int l = 0; l < 4; ++l) {
    const float* Wqkv_l = Wqkv + l*196608;
    const float* bqkv_l = bqkv + l*768;
    const float* Wo_l   = Wo   + l*65536;
    const float* bo_l   = bo   + l*256;
    const float* W1_l   = W1   + l*262144;
    const float* b1_l   = b1   + l*1024;
    const float* W2_l   = W2   + l*262144;
    const float* b2_l   = b2   + l*256;

    __syncthreads();

    for (int cg = 0; cg < 3; ++cg) {
      int col = cg*256 + tid;
      float acc[NROW];
      #pragma unroll
      for (int r = 0; r < NROW; ++r) acc[r] = 0.f;
      #pragma unroll 4
      for (int kk = 0; kk < 256; ++kk) {
        float w = Wqkv_l[kk*768 + col];
        #pragma unroll
        for (int r = 0; r < NROW; ++r) acc[r] += hs[r][kk] * w;
      }
      float bbv = bqkv_l[col];
      #pragma unroll
      for (int r = 0; r < NROW; ++r) qkvs[r][col] = f2bf(acc[r] + bbv);
    }
    __syncthreads();

    #pragma unroll 1
    for (int it = 0; it < 5; ++it) {
      int idx = it*256 + tid;
      if (idx < 1152) {
        int hh = idx / 144, rem = idx % 144;
        int r = rem / 6, sp = rem % 6;
        int tt6 = (r / 6) * 6;
        float sc = 0.f;
        #pragma unroll
        for (int c = 0; c < 32; ++c)
          sc += bf2f(qkvs[r][hh*32 + c]) * bf2f(qkvs[tt6 + sp][256 + hh*32 + c]);
        attw[hh][r][sp] = sc * 0.17677669529663687f;
      }
    }
    __syncthreads();

    if (tid < 192) {
      int hh = tid / 24, r = tid % 24;
      float mx = attw[hh][r][0];
      #pragma unroll
      for (int sp = 1; sp < 6; ++sp) mx = fmaxf(mx, attw[hh][r][sp]);
      float e[6], sum = 0.f;
      #pragma unroll
      for (int sp = 0; sp < 6; ++sp) { e[sp] = expf(attw[hh][r][sp] - mx); sum += e[sp]; }
      float inv = 1.f / sum;
      #pragma unroll
      for (int sp = 0; sp < 6; ++sp) attw[hh][r][sp] = e[sp] * inv;
    }
    __syncthreads();

    float oreg[NROW];
    {
      int hh = tid >> 5, c = tid & 31;
      #pragma unroll
      for (int r = 0; r < NROW; ++r) {
        int tt6 = (r / 6) * 6;
        float o = 0.f;
        #pragma unroll
        for (int sp = 0; sp < 6; ++sp)
          o += attw[hh][r][sp] * bf2f(qkvs[tt6 + sp][512 + hh*32 + c]);
        oreg[r] = o;
      }
    }
    __syncthreads();
    #pragma unroll
    for (int r = 0; r < NROW; ++r) fbuf[r][tid] = oreg[r];
    __syncthreads();

    {
      float bod = bo_l[tid];
      float zz[NROW];
      #pragma unroll
      for (int r = 0; r < NROW; ++r) zz[r] = bod;
      #pragma unroll 4
      for (int kk = 0; kk < 256; ++kk) {
        float w = Wo_l[kk*256 + tid];
        #pragma unroll
        for (int r = 0; r < NROW; ++r) zz[r] += fbuf[r][kk] * w;
      }
      #pragma unroll
      for (int r = 0; r < NROW; ++r) z[r] += zz[r] + resv[r];
    }
    ln24_norm(z, redbuf, n1g[l*256 + tid], n1b[l*256 + tid], tid);
    #pragma unroll
    for (int r = 0; r < NROW; ++r) hs[r][tid] = z[r];
    __syncthreads();

    float ffv[NROW];
    {
      float b2d = b2_l[tid];
      #pragma unroll
      for (int r = 0; r < NROW; ++r) ffv[r] = b2d;
    }
    for (int ch = 0; ch < 4; ++ch) {
      int j = ch*256 + tid;
      float gvv[NROW];
      float b1j = b1_l[j];
      #pragma unroll
      for (int r = 0; r < NROW; ++r) gvv[r] = b1j;
      #pragma unroll 4
      for (int kk = 0; kk < 256; ++kk) {
        float w = W1_l[kk*1024 + j];
        #pragma unroll
        for (int r = 0; r < NROW; ++r) gvv[r] += hs[r][kk] * w;
      }
      __syncthreads();
      #pragma unroll
      for (int r = 0; r < NROW; ++r) fbuf[r][tid] = gelu_f(gvv[r]);
      __syncthreads();
      #pragma unroll 4
      for (int kk = 0; kk < 256; ++kk) {
        float w = W2_l[(ch*256 + kk)*256 + tid];
        #pragma unroll
        for (int r = 0; r < NROW; ++r) ffv[r] += fbuf[r][kk] * w;
      }
    }
    #pragma unroll
    for (int r = 0; r < NROW; ++r) z[r] += ffv[r] + resv[r];
    ln24_norm(z, redbuf, n2g[l*256 + tid], n2b[l*256 + tid], tid);
    #pragma unroll
    for (int r = 0; r < NROW; ++r) hs[r][tid] = z[r];
  }

  __syncthreads();
  #pragma unroll
  for (int tt = 0; tt < TB; ++tt)
    out[(bt*TB + tt)*256 + tid] = hs[tt*6][tid];
}

// ===========================================================================
extern "C" void kernel_launch(void* const* d_in, const int* in_sizes, int n_in,
                              void* d_out, int out_size, void* d_ws, size_t ws_size,
                              hipStream_t stream) {
  (void)in_sizes; (void)n_in; (void)out_size;
  const float* x      = (const float*)d_in[0];
  const float* W_raw  = (const float*)d_in[1];
  const float* b_raw  = (const float*)d_in[2];
  const float* wl_emb = (const float*)d_in[3];
  const float* pos_emb= (const float*)d_in[4];
  const float* hop_emb= (const float*)d_in[5];
  const float* ln_g   = (const float*)d_in[6];
  const float* ln_b   = (const float*)d_in[7];
  const float* Wqkv   = (const float*)d_in[8];
  const float* bqkv   = (const float*)d_in[9];
  const float* Wo     = (const float*)d_in[10];
  const float* bo     = (const float*)d_in[11];
  const float* n1g    = (const float*)d_in[12];
  const float* n1b    = (const float*)d_in[13];
  const float* W1     = (const float*)d_in[14];
  const float* b1     = (const float*)d_in[15];
  const float* W2     = (const float*)d_in[16];
  const float* b2     = (const float*)d_in[17];
  const float* n2g    = (const float*)d_in[18];
  const float* n2b    = (const float*)d_in[19];
  const float* W_res  = (const float*)d_in[20];
  const float* b_res  = (const float*)d_in[21];

  int tc = 0;
  for (int cand = 32768; cand >= 4096; cand >>= 1) {
    size_t need = (size_t)ACTOFF + (size_t)cand * 15360u;
    if (ws_size >= need) { tc = cand; break; }
  }

  if (tc > 0) {
    char* wsb = (char*)d_ws;
    __hip_bfloat16* wf  = (__hip_bfloat16*)wsb;
    float*          res = (float*)(wsb + RESOFF);
    __hip_bfloat16* h0  = (__hip_bfloat16*)(wsb + ACTOFF);
    __hip_bfloat16* h1  = (__hip_bfloat16*)(wsb + ACTOFF + (size_t)tc*6*512);
    __hip_bfloat16* qkv = (__hip_bfloat16*)(wsb + ACTOFF + (size_t)tc*6*1024);
    float* outp = (float*)d_out;

    gb_prep_kernel<<<1536, 256, 0, stream>>>(Wqkv, Wo, W1, W2, wf);

    int nchunk = 32768 / tc;
    for (int c = 0; c < nchunk; ++c) {
      int t0 = c * tc;
      mk_embed<<<tc/4, 256, 0, stream>>>(x, W_raw, b_raw, wl_emb, pos_emb,
          hop_emb, ln_g, ln_b, W_res, b_res, h0, res, t0);
      for (int l = 0; l < 4; ++l) {
        mk_qkv<<<tc*6/32, 256, 0, stream>>>(
            h0, wf + OWQ + (unsigned)l*196608u, bqkv + l*768, qkv);
        mk_attn<<<tc/32, 256, 0, stream>>>(qkv);
        mk_wo_ln<<<tc*6/32, 512, 0, stream>>>(
            qkv, h0, res, wf + OWO + (unsigned)l*65536u, bo + l*256,
            n1g + l*256, n1b + l*256, h1, t0);
        mk_ffn<<<tc*6/32, 512, 0, stream>>>(
            h1, wf + OW1 + (unsigned)l*262144u, wf + OW2 + (unsigned)l*262144u,
            b1 + l*1024, b2 + l*256, n2g + l*256, n2b + l*256,
            res, h0, (l == 3) ? outp : (float*)nullptr, t0);
      }
    }
  } else if (ws_size >= (size_t)WS_ELEMS * 2) {
    __hip_bfloat16* wsb = (__hip_bfloat16*)d_ws;
    gb_prep_kernel<<<1536, 256, 0, stream>>>(Wqkv, Wo, W1, W2, wsb);
    gb_mfma_kernel<<<8192, 256, 0, stream>>>(
        x, W_raw, b_raw, wl_emb, pos_emb, hop_emb, ln_g, ln_b,
        bqkv, bo, n1g, n1b, b1, b2, n2g, n2b, W_res, b_res,
        wsb, (float*)d_out);
  } else {
    gb_fused_fallback<<<8192, 256, 0, stream>>>(
        x, W_raw, b_raw, wl_emb, pos_emb, hop_emb, ln_g, ln_b,
        Wqkv, bqkv, Wo, bo, n1g, n1b, W1, b1, W2, b2, n2g, n2b,
        W_res, b_res, (float*)d_out);
  }
}

// Round 22
// 3002.883 us; speedup vs baseline: 1.0882x; 1.0416x over previous
//
#include <hip/hip_runtime.h>
#include <hip/hip_bf16.h>

// GraphBertEncoder: T=32768 tokens, S=6, D=256, H=8 (hd=32), L=4.
// Round 22: r21 champion (3.128ms) + mk_ffn issue-count cut: ff accumulator
// moves from LDS (bf16 RMW, ~450 ops/thread) into persistent registers
// Cff[2][2] (W2's output mapping is identical across all 4 ch chunks).
// Residual+bias fused into the Cff->zf write. LDS 49152->37120 (4 blocks/CU).
// Peak reg demand ~64 = the allocator's observed 8-wave/SIMD budget for
// 512-thread kernels (r21: chose 48 at demand 48). Numerics = r18 fp32 order.

#define TB 4
#define NROW 24

typedef float f32x4 __attribute__((ext_vector_type(4)));
typedef short bfv8  __attribute__((ext_vector_type(8)));   // 8 bf16 = 4 VGPR

__device__ __forceinline__ float bf2f(__hip_bfloat16 v) { return __bfloat162float(v); }
__device__ __forceinline__ __hip_bfloat16 f2bf(float v) { return __float2bfloat16(v); }
__device__ __forceinline__ float bfs2f(short s) { return __uint_as_float(((unsigned)(unsigned short)s) << 16); }
__device__ __forceinline__ int swz(int row, int cb) { return row*512 + (cb ^ ((row & 7) << 4)); }
__device__ __forceinline__ float gelu_f(float v) { return 0.5f*v*(1.f + erff(v*0.70710678118654752f)); }
__device__ __forceinline__ float unpk(unsigned p, int hi) {
  return __uint_as_float(hi ? (p & 0xffff0000u) : (p << 16));
}

// packed-weight offsets (bf16 elements)
#define OWQ 0u
#define OWO 786432u
#define OW1 1048576u
#define OW2 2097152u
#define WS_ELEMS 3145728u      // weights: 6291456 bytes
#define RESOFF    6291456u     // res fp32 [1536][256] = 1572864 B
#define ACTOFF    7864320u

// ---------------------------------------------------------------------------
__global__ __launch_bounds__(256) void gb_prep_kernel(
    const float* __restrict__ Wqkv, const float* __restrict__ Wo,
    const float* __restrict__ W1,   const float* __restrict__ W2,
    __hip_bfloat16* __restrict__ ws)
{
  int fg   = blockIdx.x * 4 + (threadIdx.x >> 6);
  int lane = threadIdx.x & 63;
  int layer = fg / 1536, r = fg % 1536;
  const float* src; int K, N, fl; unsigned dstbase;
  if (r < 384)       { src = Wqkv + layer*196608; K = 256;  N = 768;  fl = r;       dstbase = OWQ + layer*196608u; }
  else if (r < 512)  { src = Wo   + layer*65536;  K = 256;  N = 256;  fl = r - 384; dstbase = OWO + layer*65536u;  }
  else if (r < 1024) { src = W1   + layer*262144; K = 256;  N = 1024; fl = r - 512; dstbase = OW1 + layer*262144u; }
  else               { src = W2   + layer*262144; K = 1024; N = 256;  fl = r - 1024;dstbase = OW2 + layer*262144u; }
  int nk = K >> 5;
  int nt = fl / nk, ks = fl % nk;
  int n  = nt*16 + (lane & 15);
  int k0 = ks*32 + (lane >> 4)*8;
  __align__(16) __hip_bfloat16 tmp[8];
  #pragma unroll
  for (int j = 0; j < 8; ++j) tmp[j] = f2bf(src[(size_t)(k0 + j)*N + n]);
  *(uint4*)(ws + dstbase + (unsigned)fl*512u + lane*8) = *(const uint4*)tmp;
}

// ---------------------------------------------------------------------------
// K-split GEMM, 4 n-tiles/wave (4-wave blocks). Peak ~112 regs. (mk_qkv)
template<int NKTOT, class LoadA>
__device__ __forceinline__ void gemm_ks(const __hip_bfloat16* __restrict__ p,
                                        LoadA loadA, f32x4 (&C)[4][2])
{
  const unsigned ST = 4u*(unsigned)NKTOT*512u;
  bfv8 B[3][4];
  bfv8 a[2][4];
  #pragma unroll
  for (int i = 0; i < 4; ++i) {
    C[i][0] = (f32x4){0.f,0.f,0.f,0.f};
    C[i][1] = (f32x4){0.f,0.f,0.f,0.f};
  }
  #pragma unroll
  for (int k = 0; k < 4; ++k) B[0][k] = *(const bfv8*)(p + k*512);
  {
    const __hip_bfloat16* q = p + ST;
    #pragma unroll
    for (int k = 0; k < 4; ++k) B[1][k] = *(const bfv8*)(q + k*512);
  }
  loadA(0, a);
  #pragma unroll
  for (int s = 0; s < 8; ++s) {
    if (s + 2 < 8) {
      const __hip_bfloat16* q = p + (unsigned)((s+2) & 3)*ST + (unsigned)((s+2) >> 2)*2048u;
      #pragma unroll
      for (int k = 0; k < 4; ++k) B[(s+2)%3][k] = *(const bfv8*)(q + k*512);
    }
    if (s == 4) loadA(1, a);
    #pragma unroll
    for (int k = 0; k < 4; ++k) {
      C[s&3][0] = __builtin_amdgcn_mfma_f32_16x16x32_bf16(a[0][k], B[s%3][k], C[s&3][0], 0,0,0);
      C[s&3][1] = __builtin_amdgcn_mfma_f32_16x16x32_bf16(a[1][k], B[s%3][k], C[s&3][1], 0,0,0);
    }
  }
}

// K-quarter streaming GEMM, 2 n-tiles/wave (8-wave blocks). Demand ~48 regs.
template<int NKTOT, class LoadA>
__device__ __forceinline__ void gemm_ksq(const __hip_bfloat16* __restrict__ p,
                                         LoadA loadA, f32x4 (&C)[2][2])
{
  const unsigned ST = 8u*(unsigned)NKTOT*512u;
  bfv8 a[2][2];
  #pragma unroll
  for (int i = 0; i < 2; ++i) {
    C[i][0] = (f32x4){0.f,0.f,0.f,0.f};
    C[i][1] = (f32x4){0.f,0.f,0.f,0.f};
  }
  #pragma unroll
  for (int q = 0; q < 4; ++q) {
    loadA(q, a);
    #pragma unroll
    for (int i = 0; i < 2; ++i) {
      const __hip_bfloat16* b = p + (unsigned)i*ST + (unsigned)q*1024u;
      bfv8 B0 = *(const bfv8*)(b);
      bfv8 B1 = *(const bfv8*)(b + 512);
      C[i][0] = __builtin_amdgcn_mfma_f32_16x16x32_bf16(a[0][0], B0, C[i][0], 0,0,0);
      C[i][1] = __builtin_amdgcn_mfma_f32_16x16x32_bf16(a[1][0], B0, C[i][1], 0,0,0);
      C[i][0] = __builtin_amdgcn_mfma_f32_16x16x32_bf16(a[0][1], B1, C[i][0], 0,0,0);
      C[i][1] = __builtin_amdgcn_mfma_f32_16x16x32_bf16(a[1][1], B1, C[i][1], 0,0,0);
    }
  }
}

// Accumulating variant: same loop, no zero-init (C carries across calls).
template<int NKTOT, class LoadA>
__device__ __forceinline__ void gemm_ksq_acc(const __hip_bfloat16* __restrict__ p,
                                             LoadA loadA, f32x4 (&C)[2][2])
{
  const unsigned ST = 8u*(unsigned)NKTOT*512u;
  bfv8 a[2][2];
  #pragma unroll
  for (int q = 0; q < 4; ++q) {
    loadA(q, a);
    #pragma unroll
    for (int i = 0; i < 2; ++i) {
      const __hip_bfloat16* b = p + (unsigned)i*ST + (unsigned)q*1024u;
      bfv8 B0 = *(const bfv8*)(b);
      bfv8 B1 = *(const bfv8*)(b + 512);
      C[i][0] = __builtin_amdgcn_mfma_f32_16x16x32_bf16(a[0][0], B0, C[i][0], 0,0,0);
      C[i][1] = __builtin_amdgcn_mfma_f32_16x16x32_bf16(a[1][0], B0, C[i][1], 0,0,0);
      C[i][0] = __builtin_amdgcn_mfma_f32_16x16x32_bf16(a[0][1], B1, C[i][0], 0,0,0);
      C[i][1] = __builtin_amdgcn_mfma_f32_16x16x32_bf16(a[1][1], B1, C[i][1], 0,0,0);
    }
  }
}

// ---------------------------------------------------------------------------
// one-pass LayerNorm helper (register version, used only by fallback kernels)
__device__ __forceinline__ void ln24_norm(float* z, float* redbuf, float g, float b, int tid) {
  const int lane = tid & 63, wid = tid >> 6;
  float s1[NROW], s2[NROW];
  #pragma unroll
  for (int r = 0; r < NROW; ++r) { float v = z[r]; s1[r] = v; s2[r] = v*v; }
  #pragma unroll
  for (int off = 32; off; off >>= 1) {
    #pragma unroll
    for (int r = 0; r < NROW; ++r) {
      s1[r] += __shfl_down(s1[r], off, 64);
      s2[r] += __shfl_down(s2[r], off, 64);
    }
  }
  if (lane == 0) {
    #pragma unroll
    for (int r = 0; r < NROW; ++r) { redbuf[wid*48 + r] = s1[r]; redbuf[wid*48 + 24 + r] = s2[r]; }
  }
  __syncthreads();
  #pragma unroll
  for (int r = 0; r < NROW; ++r) {
    float S1 = redbuf[r] + redbuf[48+r] + redbuf[96+r] + redbuf[144+r];
    float S2 = redbuf[24+r] + redbuf[72+r] + redbuf[120+r] + redbuf[168+r];
    float m  = S1 * (1.0f/256.0f);
    float var = S2 * (1.0f/256.0f) - m*m;
    float iv = rsqrtf(var + 1e-5f);
    z[r] = (z[r] - m) * iv * g + b;
  }
  __syncthreads();
}

// ===========================================================================
// ============ multi-kernel path ============================================
// ===========================================================================

// embed: block = 4 tokens (24 rows). LDS-resident z + LDS-partial LN.
__global__ __launch_bounds__(256) void mk_embed(
    const float* __restrict__ x,
    const float* __restrict__ W_raw, const float* __restrict__ b_raw,
    const float* __restrict__ wl_emb, const float* __restrict__ pos_emb,
    const float* __restrict__ hop_emb,
    const float* __restrict__ ln_g, const float* __restrict__ ln_b,
    const float* __restrict__ W_res, const float* __restrict__ b_res,
    __hip_bfloat16* __restrict__ h0, float* __restrict__ res, int t0)
{
  __shared__ float xbuf[24][128];     // 12 KB
  __shared__ float zb[24][256];       // 24 KB
  __shared__ float part[2][24][8];
  __shared__ float stat[24][2];
  const int tid = threadIdx.x;
  const int bt  = blockIdx.x;

  for (int idx = tid; idx < 24*128; idx += 256) {
    int tt = idx / 768, rem = idx % 768;
    int s = rem >> 7, f = rem & 127;
    int t = t0 + bt*4 + tt, g = t >> 7, i = t & 127;
    int node;
    if (s < 2) node = i;
    else { int j = s - 2; node = (j < i) ? j : (j + 1); }
    xbuf[tt*6+s][f] = x[(g*128 + node)*128 + f];
  }
  __syncthreads();

  {
    float z[NROW];
    #pragma unroll
    for (int r = 0; r < NROW; ++r) z[r] = 0.f;
    #pragma unroll 2
    for (int f4 = 0; f4 < 32; ++f4) {
      float w0 = W_raw[(f4*4+0)*256 + tid];
      float w1 = W_raw[(f4*4+1)*256 + tid];
      float w2 = W_raw[(f4*4+2)*256 + tid];
      float w3 = W_raw[(f4*4+3)*256 + tid];
      #pragma unroll
      for (int r = 0; r < NROW; ++r) {
        float4 xv = *(const float4*)(&xbuf[r][f4*4]);
        z[r] += xv.x*w0 + xv.y*w1 + xv.z*w2 + xv.w*w3;
      }
    }
    float br  = b_raw[tid];
    float wl  = wl_emb[tid];
    float hp0 = hop_emb[5*256 + tid];
    float hp1 = hop_emb[511*256 + tid];
    float p[6];
    #pragma unroll
    for (int s = 0; s < 6; ++s) p[s] = pos_emb[s*256 + tid];
    #pragma unroll
    for (int r = 0; r < NROW; ++r) {
      int s = r % 6;
      zb[r][tid] = z[r] + br + p[s] + wl + ((s < 2) ? hp0 : hp1);
    }
  }
  __syncthreads();

  if (tid < 192) {
    int row = tid >> 3, seg = tid & 7;
    float s1 = 0.f, s2 = 0.f;
    #pragma unroll
    for (int i = 0; i < 32; ++i) {
      int col = seg*32 + ((i + tid) & 31);
      float v = zb[row][col];
      s1 += v; s2 += v*v;
    }
    part[0][row][seg] = s1; part[1][row][seg] = s2;
  }
  __syncthreads();
  if (tid < 24) {
    float S1 = 0.f, S2 = 0.f;
    #pragma unroll
    for (int k = 0; k < 8; ++k) { S1 += part[0][tid][k]; S2 += part[1][tid][k]; }
    float m = S1 * (1.0f/256.0f);
    float var = S2 * (1.0f/256.0f) - m*m;
    stat[tid][0] = m; stat[tid][1] = rsqrtf(var + 1e-5f);
  }
  __syncthreads();
  {
    float g = ln_g[tid], b = ln_b[tid];
    #pragma unroll
    for (int r = 0; r < NROW; ++r) {
      float v = (zb[r][tid] - stat[r][0]) * stat[r][1] * g + b;
      h0[(size_t)(bt*24 + r)*256 + tid] = f2bf(v);
    }
  }

  if (t0 + bt*4 < 256) {
    __syncthreads();
    for (int idx = tid; idx < 24*128; idx += 256) {
      int tt = idx / 768, rem = idx % 768;
      int s = rem >> 7, f = rem & 127;
      int t = t0 + bt*4 + tt;
      xbuf[tt*6+s][f] = x[(t*128 + s)*128 + f];
    }
    __syncthreads();
    float resv[NROW];
    float brr = b_res[tid];
    #pragma unroll
    for (int r = 0; r < NROW; ++r) resv[r] = brr;
    #pragma unroll 2
    for (int f4 = 0; f4 < 32; ++f4) {
      float w0 = W_res[(f4*4+0)*256 + tid];
      float w1 = W_res[(f4*4+1)*256 + tid];
      float w2 = W_res[(f4*4+2)*256 + tid];
      float w3 = W_res[(f4*4+3)*256 + tid];
      #pragma unroll
      for (int r = 0; r < NROW; ++r) {
        float4 xv = *(const float4*)(&xbuf[r][f4*4]);
        resv[r] += xv.x*w0 + xv.y*w1 + xv.z*w2 + xv.w*w3;
      }
    }
    #pragma unroll
    for (int r = 0; r < NROW; ++r)
      res[(size_t)((t0 + bt*4)*6 + r)*256 + tid] = resv[r];
  }
}

// stage 32x256 bf16 rows into swz LDS -- 256-thread version
__device__ __forceinline__ void stageA(const __hip_bfloat16* __restrict__ src,
                                       int row0, int stride, char* aT, int tid) {
  #pragma unroll
  for (int k = 0; k < 4; ++k) {
    int cid = tid + k*256;
    int row = cid >> 5, cc = cid & 31;
    uint4 v = *(const uint4*)(src + (size_t)(row0 + row)*stride + cc*8);
    *(uint4*)(aT + swz(row, cc*16)) = v;
  }
}
// 512-thread version
__device__ __forceinline__ void stageA512(const __hip_bfloat16* __restrict__ src,
                                          int row0, int stride, char* aT, int tid) {
  #pragma unroll
  for (int k = 0; k < 2; ++k) {
    int cid = tid + k*512;
    int row = cid >> 5, cc = cid & 31;
    uint4 v = *(const uint4*)(src + (size_t)(row0 + row)*stride + cc*8);
    *(uint4*)(aT + swz(row, cc*16)) = v;
  }
}

// qkv GEMM: 256 threads, M=32, N=768.
__global__ __launch_bounds__(256) void mk_qkv(
    const __hip_bfloat16* __restrict__ h, const __hip_bfloat16* __restrict__ Wf,
    const float* __restrict__ bqkv_l, __hip_bfloat16* __restrict__ qkv)
{
  __shared__ __align__(16) char aT[16384];
  const int tid = threadIdx.x;
  const int lane = tid & 63, wid = tid >> 6;
  const int l15 = lane & 15, l4 = lane >> 4;
  const int row0 = blockIdx.x * 32;

  stageA(h, row0, 256, aT, tid);
  __syncthreads();

  auto lA = [&](int kh, bfv8 (&a)[2][4]) {
    #pragma unroll
    for (int k = 0; k < 4; ++k) {
      a[0][k] = *(const bfv8*)(aT + swz(l15,      (kh*4 + k)*64 + l4*16));
      a[1][k] = *(const bfv8*)(aT + swz(16 + l15, (kh*4 + k)*64 + l4*16));
    }
  };

  #pragma unroll 1
  for (int sub = 0; sub < 3; ++sub) {
    f32x4 C[4][2];
    gemm_ks<8>(Wf + (unsigned)(sub*16 + wid)*8u*512u + lane*8, lA, C);
    #pragma unroll
    for (int i = 0; i < 4; ++i) {
      int col = sub*256 + (wid + i*4)*16 + l15;
      float bb = bqkv_l[col];
      #pragma unroll
      for (int j = 0; j < 4; ++j) {
        qkv[(size_t)(row0 + l4*4 + j)*768 + col]      = f2bf(C[i][0][j] + bb);
        qkv[(size_t)(row0 + 16 + l4*4 + j)*768 + col] = f2bf(C[i][1][j] + bb);
      }
    }
  }
}

// attention: 256 threads, VALU; 32 tokens/block, thread = (token, head).
__global__ __launch_bounds__(256) void mk_attn(__hip_bfloat16* __restrict__ qkv)
{
  const int tid = threadIdx.x;
  const int tl = tid >> 3, hh = tid & 7;
  const size_t rowbase = (size_t)(blockIdx.x*32 + tl)*6;
  const int cb = hh*32;

  #pragma unroll 1
  for (int q = 0; q < 6; ++q) {
    const __hip_bfloat16* qr = qkv + (rowbase + q)*768 + cb;
    bfv8 qv[4];
    #pragma unroll
    for (int p4 = 0; p4 < 4; ++p4) qv[p4] = *(const bfv8*)(qr + p4*8);
    float a[6]; float mx = -1e30f;
    #pragma unroll
    for (int sp = 0; sp < 6; ++sp) {
      const __hip_bfloat16* kr = qkv + (rowbase + sp)*768 + 256 + cb;
      float s = 0.f;
      #pragma unroll
      for (int p4 = 0; p4 < 4; ++p4) {
        bfv8 kv = *(const bfv8*)(kr + p4*8);
        #pragma unroll
        for (int j = 0; j < 8; ++j) s += bfs2f(qv[p4][j]) * bfs2f(kv[j]);
      }
      a[sp] = s * 0.17677669529663687f;
      mx = fmaxf(mx, a[sp]);
    }
    float sum = 0.f;
    #pragma unroll
    for (int sp = 0; sp < 6; ++sp) { a[sp] = __expf(a[sp] - mx); sum += a[sp]; }
    float inv = 1.f / sum;
    #pragma unroll
    for (int sp = 0; sp < 6; ++sp) a[sp] *= inv;
    float oc[32];
    #pragma unroll
    for (int j = 0; j < 32; ++j) oc[j] = 0.f;
    #pragma unroll
    for (int sp = 0; sp < 6; ++sp) {
      const __hip_bfloat16* vr = qkv + (rowbase + sp)*768 + 512 + cb;
      float asp = a[sp];
      #pragma unroll
      for (int p4 = 0; p4 < 4; ++p4) {
        bfv8 vv = *(const bfv8*)(vr + p4*8);
        #pragma unroll
        for (int j = 0; j < 8; ++j) oc[p4*8 + j] += asp * bfs2f(vv[j]);
      }
    }
    __hip_bfloat16* orow = qkv + (rowbase + q)*768 + cb;
    #pragma unroll
    for (int p4 = 0; p4 < 4; ++p4) {
      __align__(16) __hip_bfloat16 ob[8];
      #pragma unroll
      for (int j = 0; j < 8; ++j) ob[j] = f2bf(oc[p4*8 + j]);
      *(uint4*)(orow + p4*8) = *(const uint4*)ob;
    }
  }
}

// Wo GEMM + residual + LN1: 512 threads, spill-proof gemm_ksq.
// LDS overlay: zb (fp32 [32][256], 32K) reuses aT's region. 37120 B.
__global__ __launch_bounds__(512) void mk_wo_ln(
    const __hip_bfloat16* __restrict__ qkv /* o at stride 768 */,
    const __hip_bfloat16* __restrict__ h,
    const float* __restrict__ res,
    const __hip_bfloat16* __restrict__ Wf, const float* __restrict__ bo_l,
    const float* __restrict__ gln, const float* __restrict__ bln,
    __hip_bfloat16* __restrict__ h1, int t0)
{
  __shared__ __align__(16) char smem[37120];
  char* aT = smem;                                        // [0, 16K)
  float (*zb)[256]      = (float (*)[256])smem;           // [0, 32K) after GEMM
  float (*part)[32][16] = (float (*)[32][16])(smem + 32768);
  float (*stat)[2]      = (float (*)[2])(smem + 32768 + 4096);
  const int tid = threadIdx.x;
  const int lane = tid & 63, wid = tid >> 6;      // wid 0..7
  const int l15 = lane & 15, l4 = lane >> 4;
  const int row0 = blockIdx.x * 32;

  stageA512(qkv, row0, 768, aT, tid);
  __syncthreads();

  auto lAq = [&](int q, bfv8 (&a)[2][2]) {
    #pragma unroll
    for (int k = 0; k < 2; ++k) {
      a[0][k] = *(const bfv8*)(aT + swz(l15,      (q*2 + k)*64 + l4*16));
      a[1][k] = *(const bfv8*)(aT + swz(16 + l15, (q*2 + k)*64 + l4*16));
    }
  };

  {
    f32x4 C[2][2];
    gemm_ksq<8>(Wf + (unsigned)wid*8u*512u + lane*8, lAq, C);
    __syncthreads();    // all aT reads done before zb overlays it
    #pragma unroll
    for (int i = 0; i < 2; ++i) {
      int col = (wid + i*8)*16 + l15;
      #pragma unroll
      for (int j = 0; j < 4; ++j) {
        zb[l4*4 + j][col]      = C[i][0][j];
        zb[16 + l4*4 + j][col] = C[i][1][j];
      }
    }
  }
  __syncthreads();

  #pragma unroll 4
  for (int it = 0; it < 16; ++it) {
    int idx = tid + it*512, row = idx >> 8, col = idx & 255;
    float v = zb[row][col] + bf2f(h[(size_t)(row0 + row)*256 + col]) + bo_l[col];
    int grow = t0*6 + row0 + row;
    if (grow < 1536) v += res[(size_t)grow*256 + col];
    zb[row][col] = v;
  }
  __syncthreads();

  {
    int row = tid >> 4, seg = tid & 15;
    float s1 = 0.f, s2 = 0.f;
    #pragma unroll
    for (int i = 0; i < 16; ++i) {
      int col = seg*16 + ((i + tid) & 15);
      float v = zb[row][col];
      s1 += v; s2 += v*v;
    }
    part[0][row][seg] = s1; part[1][row][seg] = s2;
  }
  __syncthreads();
  if (tid < 32) {
    float S1 = 0.f, S2 = 0.f;
    #pragma unroll
    for (int k = 0; k < 16; ++k) { S1 += part[0][tid][k]; S2 += part[1][tid][k]; }
    float m = S1 * (1.0f/256.0f);
    float var = S2 * (1.0f/256.0f) - m*m;
    stat[tid][0] = m; stat[tid][1] = rsqrtf(var + 1e-5f);
  }
  __syncthreads();
  #pragma unroll 4
  for (int it = 0; it < 16; ++it) {
    int idx = tid + it*512, row = idx >> 8, col = idx & 255;
    float v = (zb[row][col] - stat[row][0]) * stat[row][1] * gln[col] + bln[col];
    h1[(size_t)(row0 + row)*256 + col] = f2bf(v);
  }
}

// FFN fused + residual + LN2: 512 threads. ff accumulator in REGISTERS
// (Cff[2][2], persistent across the 4 ch chunks -- W2's output mapping is
// ch-invariant). Residual+bias fused into the Cff->zf write. LDS 37120 B:
// aT+gT [0,32K) during GEMMs -> zf fp32 [32][256] after; part/stat at 32K.
__global__ __launch_bounds__(512) void mk_ffn(
    const __hip_bfloat16* __restrict__ h1,
    const __hip_bfloat16* __restrict__ W1f, const __hip_bfloat16* __restrict__ W2f,
    const float* __restrict__ b1_l, const float* __restrict__ b2_l,
    const float* __restrict__ gln, const float* __restrict__ bln,
    const float* __restrict__ res, __hip_bfloat16* __restrict__ hout,
    float* __restrict__ outp, int t0)
{
  __shared__ __align__(16) char smem[37120];
  char* aT = smem;                                            // [0, 16K)
  char* gT = smem + 16384;                                    // [16K, 32K)
  float (*zf)[256]      = (float (*)[256])smem;               // [0, 32K) after GEMMs
  float (*part)[32][16] = (float (*)[32][16])(smem + 32768);
  float (*stat)[2]      = (float (*)[2])(smem + 32768 + 4096);
  const int tid = threadIdx.x;
  const int lane = tid & 63, wid = tid >> 6;      // wid 0..7
  const int l15 = lane & 15, l4 = lane >> 4;
  const int row0 = blockIdx.x * 32;

  stageA512(h1, row0, 256, aT, tid);
  __syncthreads();

  auto lAq = [&](int q, bfv8 (&a)[2][2]) {
    #pragma unroll
    for (int k = 0; k < 2; ++k) {
      a[0][k] = *(const bfv8*)(aT + swz(l15,      (q*2 + k)*64 + l4*16));
      a[1][k] = *(const bfv8*)(aT + swz(16 + l15, (q*2 + k)*64 + l4*16));
    }
  };
  auto lGq = [&](int q, bfv8 (&a)[2][2]) {
    #pragma unroll
    for (int k = 0; k < 2; ++k) {
      a[0][k] = *(const bfv8*)(gT + swz(l15,      (q*2 + k)*64 + l4*16));
      a[1][k] = *(const bfv8*)(gT + swz(16 + l15, (q*2 + k)*64 + l4*16));
    }
  };

  f32x4 Cff[2][2];
  #pragma unroll
  for (int i = 0; i < 2; ++i) {
    Cff[i][0] = (f32x4){0.f,0.f,0.f,0.f};
    Cff[i][1] = (f32x4){0.f,0.f,0.f,0.f};
  }

  #pragma unroll 1
  for (int ch = 0; ch < 4; ++ch) {
    {
      f32x4 C[2][2];
      gemm_ksq<8>(W1f + (unsigned)(ch*16 + wid)*8u*512u + lane*8, lAq, C);
      #pragma unroll
      for (int i = 0; i < 2; ++i) {
        int colR = (wid + i*8)*16 + l15;
        float bb = b1_l[ch*256 + colR];
        int col2 = colR*2;
        #pragma unroll
        for (int j = 0; j < 4; ++j) {
          *(__hip_bfloat16*)(gT + swz(l4*4 + j, col2))      = f2bf(gelu_f(C[i][0][j] + bb));
          *(__hip_bfloat16*)(gT + swz(16 + l4*4 + j, col2)) = f2bf(gelu_f(C[i][1][j] + bb));
        }
      }
    }
    __syncthreads();   // g visible
    gemm_ksq_acc<32>(W2f + (unsigned)(wid*32 + ch*8)*512u + lane*8, lGq, Cff);
    __syncthreads();   // g reads done; after ch=3 this also guards zf overlay
  }

  // Cff + residual + bias -> zf (fp32, overlays aT/gT which are now dead)
  #pragma unroll
  for (int i = 0; i < 2; ++i) {
    int col = (wid + i*8)*16 + l15;
    float b2v = b2_l[col];
    #pragma unroll
    for (int j = 0; j < 4; ++j) {
      int r0 = l4*4 + j, r1 = 16 + l4*4 + j;
      float v0 = Cff[i][0][j] + bf2f(h1[(size_t)(row0 + r0)*256 + col]) + b2v;
      float v1 = Cff[i][1][j] + bf2f(h1[(size_t)(row0 + r1)*256 + col]) + b2v;
      int g0 = t0*6 + row0 + r0, g1 = t0*6 + row0 + r1;
      if (g0 < 1536) v0 += res[(size_t)g0*256 + col];
      if (g1 < 1536) v1 += res[(size_t)g1*256 + col];
      zf[r0][col] = v0;
      zf[r1][col] = v1;
    }
  }
  __syncthreads();
  {
    int row = tid >> 4, seg = tid & 15;
    float s1 = 0.f, s2 = 0.f;
    #pragma unroll
    for (int i = 0; i < 16; ++i) {
      int col = seg*16 + ((i + tid) & 15);
      float v = zf[row][col];
      s1 += v; s2 += v*v;
    }
    part[0][row][seg] = s1; part[1][row][seg] = s2;
  }
  __syncthreads();
  if (tid < 32) {
    float S1 = 0.f, S2 = 0.f;
    #pragma unroll
    for (int k = 0; k < 16; ++k) { S1 += part[0][tid][k]; S2 += part[1][tid][k]; }
    float m = S1 * (1.0f/256.0f);
    float var = S2 * (1.0f/256.0f) - m*m;
    stat[tid][0] = m; stat[tid][1] = rsqrtf(var + 1e-5f);
  }
  __syncthreads();
  #pragma unroll 4
  for (int it = 0; it < 16; ++it) {
    int idx = tid + it*512, row = idx >> 8, col = idx & 255;
    float v = (zf[row][col] - stat[row][0]) * stat[row][1] * gln[col] + bln[col];
    hout[(size_t)(row0 + row)*256 + col] = f2bf(v);
    if (outp && ((row0 + row) % 6 == 0)) {
      int gtok = t0 + (row0 + row) / 6;
      outp[(size_t)gtok*256 + col] = v;
    }
  }
}

// ===========================================================================
// ============ round-10 fused champion (fallback) ===========================
// ===========================================================================
__global__ __launch_bounds__(256, 2) void gb_mfma_kernel(
    const float* __restrict__ x,
    const float* __restrict__ W_raw, const float* __restrict__ b_raw,
    const float* __restrict__ wl_emb, const float* __restrict__ pos_emb,
    const float* __restrict__ hop_emb,
    const float* __restrict__ ln_g, const float* __restrict__ ln_b,
    const float* __restrict__ bqkv, const float* __restrict__ bo,
    const float* __restrict__ n1g,  const float* __restrict__ n1b,
    const float* __restrict__ b1,   const float* __restrict__ b2,
    const float* __restrict__ n2g,  const float* __restrict__ n2b,
    const float* __restrict__ W_res, const float* __restrict__ b_res,
    const __hip_bfloat16* __restrict__ wf,
    float* __restrict__ out)
{
  __shared__ __align__(16) char smem[75392];
  char* hsb = smem;
  char* uA  = smem + 16384;
  char* uB  = smem + 53632;
  float (*attw)[24][6] = (float (*)[24][6])(smem + 70016);
  float* redbuf = (float*)(smem + 74624);

  __hip_bfloat16 (*qkvs)[776] = (__hip_bfloat16 (*)[776])uA;
  float (*fbuf)[264] = (float (*)[264])uA;
  float (*xbuf)[128] = (float (*)[128])uA;

  const int tid  = threadIdx.x;
  const int bt   = blockIdx.x;
  const int lane = tid & 63, wid = tid >> 6;
  const int l15  = lane & 15, l4 = lane >> 4;

  auto mkA = [l15, l4](const char* buf) {
    return [buf, l15, l4](int kh, bfv8 (&a)[2][4]) {
      #pragma unroll
      for (int k = 0; k < 4; ++k) {
        a[0][k] = *(const bfv8*)(buf + swz(l15,      (kh*4 + k)*64 + l4*16));
        a[1][k] = *(const bfv8*)(buf + swz(16 + l15, (kh*4 + k)*64 + l4*16));
      }
    };
  };

  {
    uint4 zz = {0u,0u,0u,0u};
    *(uint4*)(hsb + 24*512 + tid*16) = zz;
    *(uint4*)(uB  + 24*512 + tid*16) = zz;
  }

  for (int idx = tid; idx < TB*6*128; idx += 256) {
    int tt = idx / 768, rem = idx % 768;
    int s = rem >> 7, f = rem & 127;
    int t = bt*TB + tt, g = t >> 7, i = t & 127;
    int node;
    if (s < 2) node = i;
    else { int j = s - 2; node = (j < i) ? j : (j + 1); }
    xbuf[tt*6+s][f] = x[(g*128 + node)*128 + f];
  }
  __syncthreads();

  {
    float z[NROW];
    #pragma unroll
    for (int r = 0; r < NROW; ++r) z[r] = 0.f;
    #pragma unroll 2
    for (int f4 = 0; f4 < 32; ++f4) {
      float w0 = W_raw[(f4*4+0)*256 + tid];
      float w1 = W_raw[(f4*4+1)*256 + tid];
      float w2 = W_raw[(f4*4+2)*256 + tid];
      float w3 = W_raw[(f4*4+3)*256 + tid];
      #pragma unroll
      for (int r = 0; r < NROW; ++r) {
        float4 xv = *(const float4*)(&xbuf[r][f4*4]);
        z[r] += xv.x*w0 + xv.y*w1 + xv.z*w2 + xv.w*w3;
      }
    }
    float br  = b_raw[tid];
    float wl  = wl_emb[tid];
    float hp0 = hop_emb[5*256 + tid];
    float hp1 = hop_emb[511*256 + tid];
    float p[6];
    #pragma unroll
    for (int s = 0; s < 6; ++s) p[s] = pos_emb[s*256 + tid];
    #pragma unroll
    for (int r = 0; r < NROW; ++r) {
      int s = r % 6;
      z[r] += br + p[s] + wl + ((s < 2) ? hp0 : hp1);
    }
    ln24_norm(z, redbuf, ln_g[tid], ln_b[tid], tid);
    #pragma unroll
    for (int r = 0; r < NROW; ++r)
      *(__hip_bfloat16*)(hsb + swz(r, tid*2)) = f2bf(z[r]);
  }

  unsigned resp[12];
  #pragma unroll
  for (int k = 0; k < 12; ++k) resp[k] = 0u;
  if (bt < 64) {
    __syncthreads();
    for (int idx = tid; idx < TB*6*128; idx += 256) {
      int tt = idx / 768, rem = idx % 768;
      int s = rem >> 7, f = rem & 127;
      int t = bt*TB + tt;
      xbuf[tt*6+s][f] = x[(t*128 + s)*128 + f];
    }
    __syncthreads();
    float resv[NROW];
    float brr = b_res[tid];
    #pragma unroll
    for (int r = 0; r < NROW; ++r) resv[r] = brr;
    #pragma unroll 2
    for (int f4 = 0; f4 < 32; ++f4) {
      float w0 = W_res[(f4*4+0)*256 + tid];
      float w1 = W_res[(f4*4+1)*256 + tid];
      float w2 = W_res[(f4*4+2)*256 + tid];
      float w3 = W_res[(f4*4+3)*256 + tid];
      #pragma unroll
      for (int r = 0; r < NROW; ++r) {
        float4 xv = *(const float4*)(&xbuf[r][f4*4]);
        resv[r] += xv.x*w0 + xv.y*w1 + xv.z*w2 + xv.w*w3;
      }
    }
    #pragma unroll
    for (int k = 0; k < 12; ++k) {
      unsigned lo = __float_as_uint(resv[2*k])   >> 16;
      unsigned hi = __float_as_uint(resv[2*k+1]) & 0xffff0000u;
      resp[k] = hi | lo;
    }
  }

  float z[NROW];

  #pragma unroll 1
  for (int l = 0; l < 4; ++l) {
    const __hip_bfloat16* WQf = wf + OWQ + (unsigned)l*196608u;
    const __hip_bfloat16* WOf = wf + OWO + (unsigned)l*65536u;
    const __hip_bfloat16* W1f = wf + OW1 + (unsigned)l*262144u;
    const __hip_bfloat16* W2f = wf + OW2 + (unsigned)l*262144u;

    __syncthreads();

    {
      auto lA = mkA(hsb);
      #pragma unroll 1
      for (int sub = 0; sub < 3; ++sub) {
        f32x4 C[4][2];
        gemm_ks<8>(WQf + (unsigned)(sub*16 + wid)*8u*512u + lane*8, lA, C);
        #pragma unroll
        for (int i = 0; i < 4; ++i) {
          int gcol = sub*256 + (wid + i*4)*16 + l15;
          float bbv = bqkv[l*768 + gcol];
          #pragma unroll
          for (int j = 0; j < 4; ++j) {
            qkvs[l4*4 + j][gcol] = f2bf(C[i][0][j] + bbv);
            int r1 = 16 + l4*4 + j;
            if (r1 < NROW) qkvs[r1][gcol] = f2bf(C[i][1][j] + bbv);
          }
        }
      }
    }
    __syncthreads();

    if (tid < 192) {
      int hh = tid / 24, r = tid % 24;
      int tt6 = (r / 6) * 6;
      bfv8 qv[4];
      #pragma unroll
      for (int p4 = 0; p4 < 4; ++p4) qv[p4] = *(const bfv8*)(&qkvs[r][hh*32 + p4*8]);
      float sc[6];
      #pragma unroll
      for (int sp = 0; sp < 6; ++sp) {
        float s = 0.f;
        #pragma unroll
        for (int p4 = 0; p4 < 4; ++p4) {
          bfv8 kv = *(const bfv8*)(&qkvs[tt6 + sp][256 + hh*32 + p4*8]);
          #pragma unroll
          for (int j = 0; j < 8; ++j) s += bfs2f(qv[p4][j]) * bfs2f(kv[j]);
        }
        sc[sp] = s * 0.17677669529663687f;
      }
      float mx = sc[0];
      #pragma unroll
      for (int sp = 1; sp < 6; ++sp) mx = fmaxf(mx, sc[sp]);
      float sum = 0.f;
      #pragma unroll
      for (int sp = 0; sp < 6; ++sp) { sc[sp] = __expf(sc[sp] - mx); sum += sc[sp]; }
      float inv = 1.f / sum;
      #pragma unroll
      for (int sp = 0; sp < 6; ++sp) attw[hh][r][sp] = sc[sp] * inv;
    }
    __syncthreads();

    {
      int hh = tid >> 5, c = tid & 31;
      int col2 = (hh*32 + c)*2;
      #pragma unroll
      for (int tt = 0; tt < 4; ++tt) {
        float vv[6];
        #pragma unroll
        for (int sp = 0; sp < 6; ++sp) vv[sp] = bf2f(qkvs[tt*6 + sp][512 + hh*32 + c]);
        #pragma unroll
        for (int q = 0; q < 6; ++q) {
          float o = 0.f;
          #pragma unroll
          for (int sp = 0; sp < 6; ++sp) o += attw[hh][tt*6 + q][sp] * vv[sp];
          *(__hip_bfloat16*)(uB + swz(tt*6 + q, col2)) = f2bf(o);
        }
      }
    }
    __syncthreads();

    {
      f32x4 C[4][2];
      gemm_ks<8>(WOf + (unsigned)wid*8u*512u + lane*8, mkA(uB), C);
      #pragma unroll
      for (int i = 0; i < 4; ++i) {
        int col = (wid + i*4)*16 + l15;
        #pragma unroll
        for (int j = 0; j < 4; ++j) {
          fbuf[l4*4 + j][col] = C[i][0][j];
          int r1 = 16 + l4*4 + j;
          if (r1 < NROW) fbuf[r1][col] = C[i][1][j];
        }
      }
    }
    __syncthreads();

    {
      float bov = bo[l*256 + tid];
      #pragma unroll
      for (int r = 0; r < NROW; ++r)
        z[r] = bf2f(*(const __hip_bfloat16*)(hsb + swz(r, tid*2)))
             + unpk(resp[r >> 1], r & 1) + fbuf[r][tid] + bov;
    }
    #pragma unroll
    for (int k = 0; k < 12; ++k) *(unsigned*)(uB + (k*256 + tid)*4) = 0u;
    ln24_norm(z, redbuf, n1g[l*256 + tid], n1b[l*256 + tid], tid);
    #pragma unroll
    for (int r = 0; r < NROW; ++r)
      *(__hip_bfloat16*)(hsb + swz(r, tid*2)) = f2bf(z[r]);
    {
      uint4 zz = {0u,0u,0u,0u};
      *(uint4*)(uA + 24*512 + tid*16) = zz;
      *(uint4*)(uA + 16384 + 24*512 + tid*16) = zz;
    }
    __syncthreads();

    {
      auto lAh = mkA(hsb);
      #pragma unroll 1
      for (int ch = 0; ch < 4; ++ch) {
        char* gb = uA + (ch & 1)*16384;
        {
          f32x4 C[4][2];
          gemm_ks<8>(W1f + (unsigned)(ch*128 + wid*8)*512u + lane*8, lAh, C);
          #pragma unroll
          for (int i = 0; i < 4; ++i) {
            float bbv = b1[l*1024 + ch*256 + (wid + i*4)*16 + l15];
            int col2 = ((wid + i*4)*16 + l15)*2;
            #pragma unroll
            for (int j = 0; j < 4; ++j) {
              *(__hip_bfloat16*)(gb + swz(l4*4 + j, col2)) = f2bf(gelu_f(C[i][0][j] + bbv));
              int r1 = 16 + l4*4 + j;
              if (r1 < NROW)
                *(__hip_bfloat16*)(gb + swz(r1, col2)) = f2bf(gelu_f(C[i][1][j] + bbv));
            }
          }
        }
        __syncthreads();
        {
          f32x4 C[4][2];
          gemm_ks<32>(W2f + (unsigned)(wid*32 + ch*8)*512u + lane*8, mkA(gb), C);
          #pragma unroll
          for (int i = 0; i < 4; ++i) {
            int col2 = ((wid + i*4)*16 + l15)*2;
            #pragma unroll
            for (int j = 0; j < 4; ++j) {
              {
                __hip_bfloat16* pp = (__hip_bfloat16*)(uB + (l4*4 + j)*512 + col2);
                *pp = f2bf(bf2f(*pp) + C[i][0][j]);
              }
              int r1 = 16 + l4*4 + j;
              if (r1 < NROW) {
                __hip_bfloat16* pp = (__hip_bfloat16*)(uB + r1*512 + col2);
                *pp = f2bf(bf2f(*pp) + C[i][1][j]);
              }
            }
          }
        }
      }
    }
    __syncthreads();

    {
      float b2v = b2[l*256 + tid];
      #pragma unroll
      for (int r = 0; r < NROW; ++r)
        z[r] = bf2f(*(const __hip_bfloat16*)(hsb + swz(r, tid*2)))
             + unpk(resp[r >> 1], r & 1)
             + bf2f(*(const __hip_bfloat16*)(uB + r*512 + tid*2)) + b2v;
    }
    ln24_norm(z, redbuf, n2g[l*256 + tid], n2b[l*256 + tid], tid);
    #pragma unroll
    for (int r = 0; r < NROW; ++r)
      *(__hip_bfloat16*)(hsb + swz(r, tid*2)) = f2bf(z[r]);
  }

  #pragma unroll
  for (int tt = 0; tt < TB; ++tt)
    out[(bt*TB + tt)*256 + tid] = z[tt*6];
}

// ---------------------------------------------------------------------------
// Pure-VALU fallback (round-2 proven).
__global__ __launch_bounds__(256, 2) void gb_fused_fallback(
    const float* __restrict__ x,
    const float* __restrict__ W_raw, const float* __restrict__ b_raw,
    const float* __restrict__ wl_emb, const float* __restrict__ pos_emb,
    const float* __restrict__ hop_emb,
    const float* __restrict__ ln_g, const float* __restrict__ ln_b,
    const float* __restrict__ Wqkv, const float* __restrict__ bqkv,
    const float* __restrict__ Wo,   const float* __restrict__ bo,
    const float* __restrict__ n1g,  const float* __restrict__ n1b,
    const float* __restrict__ W1,   const float* __restrict__ b1,
    const float* __restrict__ W2,   const float* __restrict__ b2,
    const float* __restrict__ n2g,  const float* __restrict__ n2b,
    const float* __restrict__ W_res, const float* __restrict__ b_res,
    float* __restrict__ out)
{
  __shared__ float hs[NROW][256];
  __shared__ __align__(16) char bufraw[NROW*768*2];
  __shared__ float attw[8][NROW][8];
  __shared__ float redbuf[192];

  __hip_bfloat16 (*qkvs)[768] = (__hip_bfloat16 (*)[768])bufraw;
  float (*fbuf)[256] = (float (*)[256])bufraw;
  float (*xbuf)[128] = (float (*)[128])bufraw;

  const int tid = threadIdx.x;
  const int bt  = blockIdx.x;

  for (int idx = tid; idx < TB*6*128; idx += 256) {
    int tt = idx / 768, rem = idx % 768;
    int s = rem >> 7, f = rem & 127;
    int t = bt*TB + tt, g = t >> 7, i = t & 127;
    int node;
    if (s < 2) node = i;
    else { int j = s - 2; node = (j < i) ? j : (j + 1); }
    xbuf[tt*6+s][f] = x[(g*128 + node)*128 + f];
  }
  __syncthreads();

  float z[NROW];
  {
    #pragma unroll
    for (int r = 0; r < NROW; ++r) z[r] = 0.f;
    #pragma unroll 4
    for (int f = 0; f < 128; ++f) {
      float w = W_raw[f*256 + tid];
      #pragma unroll
      for (int r = 0; r < NROW; ++r) z[r] += xbuf[r][f] * w;
    }
    float br  = b_raw[tid];
    float wl  = wl_emb[tid];
    float hp0 = hop_emb[5*256 + tid];
    float hp1 = hop_emb[511*256 + tid];
    float p[6];
    #pragma unroll
    for (int s = 0; s < 6; ++s) p[s] = pos_emb[s*256 + tid];
    #pragma unroll
    for (int r = 0; r < NROW; ++r) {
      int s = r % 6;
      z[r] += br + p[s] + wl + ((s < 2) ? hp0 : hp1);
    }
  }
  ln24_norm(z, redbuf, ln_g[tid], ln_b[tid], tid);
  #pragma unroll
  for (int r = 0; r < NROW; ++r) hs[r][tid] = z[r];

  float resv[NROW];
  #pragma unroll
  for (int r = 0; r < NROW; ++r) resv[r] = 0.f;
  if (bt < 64) {
    __syncthreads();
    for (int idx = tid; idx < TB*6*128; idx += 256) {
      int tt = idx / 768, rem = idx % 768;
      int s = rem >> 7, f = rem & 127;
      int t = bt*TB + tt;
      xbuf[tt*6+s][f] = x[(t*128 + s)*128 + f];
    }
    __syncthreads();
    #pragma unroll 4
    for (int f = 0; f < 128; ++f) {
      float w = W_res[f*256 + tid];
      #pragma unroll
      for (int r = 0; r < NROW; ++r) resv[r] += xbuf[r][f] * w;
    }
    float brr = b_res[tid];
    #pragma unroll
    for (int r = 0; r < NROW; ++r) resv[r] += brr;
  }

  for (int l = 0; l < 4; ++l) {
    const float* Wqkv_l = Wqkv + l*196608;
    const float* bqkv_l = bqkv + l*768;
    const float* Wo_l   = Wo   + l*65536;
    const float* bo_l   = bo   + l*256;
    const float* W1_l   = W1   + l*262144;
    const float* b1_l   = b1   + l*1024;
    const float* W2_l   = W2   + l*262144;
    const float* b2_l   = b2   + l*256;

    __syncthreads();

    for (int cg = 0; cg < 3; ++cg) {
      int col = cg*256 + tid;
      float acc[NROW];
      #pragma unroll
      for (int r = 0; r < NROW; ++r) acc[r] = 0.f;
      #pragma unroll 4
      for (int kk = 0; kk < 256; ++kk) {
        float w = Wqkv_l[kk*768 + col];
        #pragma unroll
        for (int r = 0; r < NROW; ++r) acc[r] += hs[r][kk] * w;
      }
      float bbv = bqkv_l[col];
      #pragma unroll
      for (int r = 0; r < NROW; ++r) qkvs[r][col] = f2bf(acc[r] + bbv);
    }
    __syncthreads();

    #pragma unroll 1
    for (int it = 0; it < 5; ++it) {
      int idx = it*256 + tid;
      if (idx < 1152) {
        int hh = idx / 144, rem = idx % 144;
        int r = rem / 6, sp = rem % 6;
        int tt6 = (r / 6) * 6;
        float sc = 0.f;
        #pragma unroll
        for (int c = 0; c < 32; ++c)
          sc += bf2f(qkvs[r][hh*32 + c]) * bf2f(qkvs[tt6 + sp][256 + hh*32 + c]);
        attw[hh][r][sp] = sc * 0.17677669529663687f;
      }
    }
    __syncthreads();

    if (tid < 192) {
      int hh = tid / 24, r = tid % 24;
      float mx = attw[hh][r][0];
      #pragma unroll
      for (int sp = 1; sp < 6; ++sp) mx = fmaxf(mx, attw[hh][r][sp]);
      float e[6], sum = 0.f;
      #pragma unroll
      for (int sp = 0; sp < 6; ++sp) { e[sp] = expf(attw[hh][r][sp] - mx); sum += e[sp]; }
      float inv = 1.f / sum;
      #pragma unroll
      for (int sp = 0; sp < 6; ++sp) attw[hh][r][sp] = e[sp] * inv;
    }
    __syncthreads();

    float oreg[NROW];
    {
      int hh = tid >> 5, c = tid & 31;
      #pragma unroll
      for (int r = 0; r < NROW; ++r) {
        int tt6 = (r / 6) * 6;
        float o = 0.f;
        #pragma unroll
        for (int sp = 0; sp < 6; ++sp)
          o += attw[hh][r][sp] * bf2f(qkvs[tt6 + sp][512 + hh*32 + c]);
        oreg[r] = o;
      }
    }
    __syncthreads();
    #pragma unroll
    for (int r = 0; r < NROW; ++r) fbuf[r][tid] = oreg[r];
    __syncthreads();

    {
      float bod = bo_l[tid];
      float zz[NROW];
      #pragma unroll
      for (int r = 0; r < NROW; ++r) zz[r] = bod;
      #pragma unroll 4
      for (int kk = 0; kk < 256; ++kk) {
        float w = Wo_l[kk*256 + tid];
        #pragma unroll
        for (int r = 0; r < NROW; ++r) zz[r] += fbuf[r][kk] * w;
      }
      #pragma unroll
      for (int r = 0; r < NROW; ++r) z[r] += zz[r] + resv[r];
    }
    ln24_norm(z, redbuf, n1g[l*256 + tid], n1b[l*256 + tid], tid);
    #pragma unroll
    for (int r = 0; r < NROW; ++r) hs[r][tid] = z[r];
    __syncthreads();

    float ffv[NROW];
    {
      float b2d = b2_l[tid];
      #pragma unroll
      for (int r = 0; r < NROW; ++r) ffv[r] = b2d;
    }
    for (int ch = 0; ch < 4; ++ch) {
      int j = ch*256 + tid;
      float gvv[NROW];
      float b1j = b1_l[j];
      #pragma unroll
      for (int r = 0; r < NROW; ++r) gvv[r] = b1j;
      #pragma unroll 4
      for (int kk = 0; kk < 256; ++kk) {
        float w = W1_l[kk*1024 + j];
        #pragma unroll
        for (int r = 0; r < NROW; ++r) gvv[r] += hs[r][kk] * w;
      }
      __syncthreads();
      #pragma unroll
      for (int r = 0; r < NROW; ++r) fbuf[r][tid] = gelu_f(gvv[r]);
      __syncthreads();
      #pragma unroll 4
      for (int kk = 0; kk < 256; ++kk) {
        float w = W2_l[(ch*256 + kk)*256 + tid];
        #pragma unroll
        for (int r = 0; r < NROW; ++r) ffv[r] += fbuf[r][kk] * w;
      }
    }
    #pragma unroll
    for (int r = 0; r < NROW; ++r) z[r] += ffv[r] + resv[r];
    ln24_norm(z, redbuf, n2g[l*256 + tid], n2b[l*256 + tid], tid);
    #pragma unroll
    for (int r = 0; r < NROW; ++r) hs[r][tid] = z[r];
  }

  __syncthreads();
  #pragma unroll
  for (int tt = 0; tt < TB; ++tt)
    out[(bt*TB + tt)*256 + tid] = hs[tt*6][tid];
}

// ===========================================================================
extern "C" void kernel_launch(void* const* d_in, const int* in_sizes, int n_in,
                              void* d_out, int out_size, void* d_ws, size_t ws_size,
                              hipStream_t stream) {
  (void)in_sizes; (void)n_in; (void)out_size;
  const float* x      = (const float*)d_in[0];
  const float* W_raw  = (const float*)d_in[1];
  const float* b_raw  = (const float*)d_in[2];
  const float* wl_emb = (const float*)d_in[3];
  const float* pos_emb= (const float*)d_in[4];
  const float* hop_emb= (const float*)d_in[5];
  const float* ln_g   = (const float*)d_in[6];
  const float* ln_b   = (const float*)d_in[7];
  const float* Wqkv   = (const float*)d_in[8];
  const float* bqkv   = (const float*)d_in[9];
  const float* Wo     = (const float*)d_in[10];
  const float* bo     = (const float*)d_in[11];
  const float* n1g    = (const float*)d_in[12];
  const float* n1b    = (const float*)d_in[13];
  const float* W1     = (const float*)d_in[14];
  const float* b1     = (const float*)d_in[15];
  const float* W2     = (const float*)d_in[16];
  const float* b2     = (const float*)d_in[17];
  const float* n2g    = (const float*)d_in[18];
  const float* n2b    = (const float*)d_in[19];
  const float* W_res  = (const float*)d_in[20];
  const float* b_res  = (const float*)d_in[21];

  int tc = 0;
  for (int cand = 32768; cand >= 4096; cand >>= 1) {
    size_t need = (size_t)ACTOFF + (size_t)cand * 15360u;
    if (ws_size >= need) { tc = cand; break; }
  }

  if (tc > 0) {
    char* wsb = (char*)d_ws;
    __hip_bfloat16* wf  = (__hip_bfloat16*)wsb;
    float*          res = (float*)(wsb + RESOFF);
    __hip_bfloat16* h0  = (__hip_bfloat16*)(wsb + ACTOFF);
    __hip_bfloat16* h1  = (__hip_bfloat16*)(wsb + ACTOFF + (size_t)tc*6*512);
    __hip_bfloat16* qkv = (__hip_bfloat16*)(wsb + ACTOFF + (size_t)tc*6*1024);
    float* outp = (float*)d_out;

    gb_prep_kernel<<<1536, 256, 0, stream>>>(Wqkv, Wo, W1, W2, wf);

    int nchunk = 32768 / tc;
    for (int c = 0; c < nchunk; ++c) {
      int t0 = c * tc;
      mk_embed<<<tc/4, 256, 0, stream>>>(x, W_raw, b_raw, wl_emb, pos_emb,
          hop_emb, ln_g, ln_b, W_res, b_res, h0, res, t0);
      for (int l = 0; l < 4; ++l) {
        mk_qkv<<<tc*6/32, 256, 0, stream>>>(
            h0, wf + OWQ + (unsigned)l*196608u, bqkv + l*768, qkv);
        mk_attn<<<tc/32, 256, 0, stream>>>(qkv);
        mk_wo_ln<<<tc*6/32, 512, 0, stream>>>(
            qkv, h0, res, wf + OWO + (unsigned)l*65536u, bo + l*256,
            n1g + l*256, n1b + l*256, h1, t0);
        mk_ffn<<<tc*6/32, 512, 0, stream>>>(
            h1, wf + OW1 + (unsigned)l*262144u, wf + OW2 + (unsigned)l*262144u,
            b1 + l*1024, b2 + l*256, n2g + l*256, n2b + l*256,
            res, h0, (l == 3) ? outp : (float*)nullptr, t0);
      }
    }
  } else if (ws_size >= (size_t)WS_ELEMS * 2) {
    __hip_bfloat16* wsb = (__hip_bfloat16*)d_ws;
    gb_prep_kernel<<<1536, 256, 0, stream>>>(Wqkv, Wo, W1, W2, wsb);
    gb_mfma_kernel<<<8192, 256, 0, stream>>>(
        x, W_raw, b_raw, wl_emb, pos_emb, hop_emb, ln_g, ln_b,
        bqkv, bo, n1g, n1b, b1, b2, n2g, n2b, W_res, b_res,
        wsb, (float*)d_out);
  } else {
    gb_fused_fallback<<<8192, 256, 0, stream>>>(
        x, W_raw, b_raw, wl_emb, pos_emb, hop_emb, ln_g, ln_b,
        Wqkv, bqkv, Wo, bo, n1g, n1b, W1, b1, W2, b2, n2g, n2b,
        W_res, b_res, (float*)d_out);
  }
}

// Round 23
// 2787.570 us; speedup vs baseline: 1.1722x; 1.0772x over previous
//
#include <hip/hip_runtime.h>
#include <hip/hip_bf16.h>

// GraphBertEncoder: T=32768 tokens, S=6, D=256, H=8 (hd=32), L=4.
// Round 23: r22 champion (3.003ms) + embed de-duplication. The old mk_embed
// computed x[g,node]@W_raw per (token,s) row = 6x redundant FLOPs (the
// gathered rows are just the 128 graph rows). Split: mk_xw computes
// y = x@W_raw once over source rows (same per-row FMA order -> identical
// numerics), parked in h1's dead region; mk_embed2 gathers y + embeddings +
// LN (code identical to old mk_embed minus the GEMM). Everything else = r22.

#define TB 4
#define NROW 24

typedef float f32x4 __attribute__((ext_vector_type(4)));
typedef short bfv8  __attribute__((ext_vector_type(8)));   // 8 bf16 = 4 VGPR

__device__ __forceinline__ float bf2f(__hip_bfloat16 v) { return __bfloat162float(v); }
__device__ __forceinline__ __hip_bfloat16 f2bf(float v) { return __float2bfloat16(v); }
__device__ __forceinline__ float bfs2f(short s) { return __uint_as_float(((unsigned)(unsigned short)s) << 16); }
__device__ __forceinline__ int swz(int row, int cb) { return row*512 + (cb ^ ((row & 7) << 4)); }
__device__ __forceinline__ float gelu_f(float v) { return 0.5f*v*(1.f + erff(v*0.70710678118654752f)); }
__device__ __forceinline__ float unpk(unsigned p, int hi) {
  return __uint_as_float(hi ? (p & 0xffff0000u) : (p << 16));
}

// packed-weight offsets (bf16 elements)
#define OWQ 0u
#define OWO 786432u
#define OW1 1048576u
#define OW2 2097152u
#define WS_ELEMS 3145728u      // weights: 6291456 bytes
#define RESOFF    6291456u     // res fp32 [1536][256] = 1572864 B
#define ACTOFF    7864320u

// ---------------------------------------------------------------------------
__global__ __launch_bounds__(256) void gb_prep_kernel(
    const float* __restrict__ Wqkv, const float* __restrict__ Wo,
    const float* __restrict__ W1,   const float* __restrict__ W2,
    __hip_bfloat16* __restrict__ ws)
{
  int fg   = blockIdx.x * 4 + (threadIdx.x >> 6);
  int lane = threadIdx.x & 63;
  int layer = fg / 1536, r = fg % 1536;
  const float* src; int K, N, fl; unsigned dstbase;
  if (r < 384)       { src = Wqkv + layer*196608; K = 256;  N = 768;  fl = r;       dstbase = OWQ + layer*196608u; }
  else if (r < 512)  { src = Wo   + layer*65536;  K = 256;  N = 256;  fl = r - 384; dstbase = OWO + layer*65536u;  }
  else if (r < 1024) { src = W1   + layer*262144; K = 256;  N = 1024; fl = r - 512; dstbase = OW1 + layer*262144u; }
  else               { src = W2   + layer*262144; K = 1024; N = 256;  fl = r - 1024;dstbase = OW2 + layer*262144u; }
  int nk = K >> 5;
  int nt = fl / nk, ks = fl % nk;
  int n  = nt*16 + (lane & 15);
  int k0 = ks*32 + (lane >> 4)*8;
  __align__(16) __hip_bfloat16 tmp[8];
  #pragma unroll
  for (int j = 0; j < 8; ++j) tmp[j] = f2bf(src[(size_t)(k0 + j)*N + n]);
  *(uint4*)(ws + dstbase + (unsigned)fl*512u + lane*8) = *(const uint4*)tmp;
}

// ---------------------------------------------------------------------------
// K-split GEMM, 4 n-tiles/wave (4-wave blocks). Peak ~112 regs. (mk_qkv)
template<int NKTOT, class LoadA>
__device__ __forceinline__ void gemm_ks(const __hip_bfloat16* __restrict__ p,
                                        LoadA loadA, f32x4 (&C)[4][2])
{
  const unsigned ST = 4u*(unsigned)NKTOT*512u;
  bfv8 B[3][4];
  bfv8 a[2][4];
  #pragma unroll
  for (int i = 0; i < 4; ++i) {
    C[i][0] = (f32x4){0.f,0.f,0.f,0.f};
    C[i][1] = (f32x4){0.f,0.f,0.f,0.f};
  }
  #pragma unroll
  for (int k = 0; k < 4; ++k) B[0][k] = *(const bfv8*)(p + k*512);
  {
    const __hip_bfloat16* q = p + ST;
    #pragma unroll
    for (int k = 0; k < 4; ++k) B[1][k] = *(const bfv8*)(q + k*512);
  }
  loadA(0, a);
  #pragma unroll
  for (int s = 0; s < 8; ++s) {
    if (s + 2 < 8) {
      const __hip_bfloat16* q = p + (unsigned)((s+2) & 3)*ST + (unsigned)((s+2) >> 2)*2048u;
      #pragma unroll
      for (int k = 0; k < 4; ++k) B[(s+2)%3][k] = *(const bfv8*)(q + k*512);
    }
    if (s == 4) loadA(1, a);
    #pragma unroll
    for (int k = 0; k < 4; ++k) {
      C[s&3][0] = __builtin_amdgcn_mfma_f32_16x16x32_bf16(a[0][k], B[s%3][k], C[s&3][0], 0,0,0);
      C[s&3][1] = __builtin_amdgcn_mfma_f32_16x16x32_bf16(a[1][k], B[s%3][k], C[s&3][1], 0,0,0);
    }
  }
}

// K-quarter streaming GEMM, 2 n-tiles/wave (8-wave blocks). Demand ~48 regs.
template<int NKTOT, class LoadA>
__device__ __forceinline__ void gemm_ksq(const __hip_bfloat16* __restrict__ p,
                                         LoadA loadA, f32x4 (&C)[2][2])
{
  const unsigned ST = 8u*(unsigned)NKTOT*512u;
  bfv8 a[2][2];
  #pragma unroll
  for (int i = 0; i < 2; ++i) {
    C[i][0] = (f32x4){0.f,0.f,0.f,0.f};
    C[i][1] = (f32x4){0.f,0.f,0.f,0.f};
  }
  #pragma unroll
  for (int q = 0; q < 4; ++q) {
    loadA(q, a);
    #pragma unroll
    for (int i = 0; i < 2; ++i) {
      const __hip_bfloat16* b = p + (unsigned)i*ST + (unsigned)q*1024u;
      bfv8 B0 = *(const bfv8*)(b);
      bfv8 B1 = *(const bfv8*)(b + 512);
      C[i][0] = __builtin_amdgcn_mfma_f32_16x16x32_bf16(a[0][0], B0, C[i][0], 0,0,0);
      C[i][1] = __builtin_amdgcn_mfma_f32_16x16x32_bf16(a[1][0], B0, C[i][1], 0,0,0);
      C[i][0] = __builtin_amdgcn_mfma_f32_16x16x32_bf16(a[0][1], B1, C[i][0], 0,0,0);
      C[i][1] = __builtin_amdgcn_mfma_f32_16x16x32_bf16(a[1][1], B1, C[i][1], 0,0,0);
    }
  }
}

// Accumulating variant: same loop, no zero-init (C carries across calls).
template<int NKTOT, class LoadA>
__device__ __forceinline__ void gemm_ksq_acc(const __hip_bfloat16* __restrict__ p,
                                             LoadA loadA, f32x4 (&C)[2][2])
{
  const unsigned ST = 8u*(unsigned)NKTOT*512u;
  bfv8 a[2][2];
  #pragma unroll
  for (int q = 0; q < 4; ++q) {
    loadA(q, a);
    #pragma unroll
    for (int i = 0; i < 2; ++i) {
      const __hip_bfloat16* b = p + (unsigned)i*ST + (unsigned)q*1024u;
      bfv8 B0 = *(const bfv8*)(b);
      bfv8 B1 = *(const bfv8*)(b + 512);
      C[i][0] = __builtin_amdgcn_mfma_f32_16x16x32_bf16(a[0][0], B0, C[i][0], 0,0,0);
      C[i][1] = __builtin_amdgcn_mfma_f32_16x16x32_bf16(a[1][0], B0, C[i][1], 0,0,0);
      C[i][0] = __builtin_amdgcn_mfma_f32_16x16x32_bf16(a[0][1], B1, C[i][0], 0,0,0);
      C[i][1] = __builtin_amdgcn_mfma_f32_16x16x32_bf16(a[1][1], B1, C[i][1], 0,0,0);
    }
  }
}

// ---------------------------------------------------------------------------
// one-pass LayerNorm helper (register version, used only by fallback kernels)
__device__ __forceinline__ void ln24_norm(float* z, float* redbuf, float g, float b, int tid) {
  const int lane = tid & 63, wid = tid >> 6;
  float s1[NROW], s2[NROW];
  #pragma unroll
  for (int r = 0; r < NROW; ++r) { float v = z[r]; s1[r] = v; s2[r] = v*v; }
  #pragma unroll
  for (int off = 32; off; off >>= 1) {
    #pragma unroll
    for (int r = 0; r < NROW; ++r) {
      s1[r] += __shfl_down(s1[r], off, 64);
      s2[r] += __shfl_down(s2[r], off, 64);
    }
  }
  if (lane == 0) {
    #pragma unroll
    for (int r = 0; r < NROW; ++r) { redbuf[wid*48 + r] = s1[r]; redbuf[wid*48 + 24 + r] = s2[r]; }
  }
  __syncthreads();
  #pragma unroll
  for (int r = 0; r < NROW; ++r) {
    float S1 = redbuf[r] + redbuf[48+r] + redbuf[96+r] + redbuf[144+r];
    float S2 = redbuf[24+r] + redbuf[72+r] + redbuf[120+r] + redbuf[168+r];
    float m  = S1 * (1.0f/256.0f);
    float var = S2 * (1.0f/256.0f) - m*m;
    float iv = rsqrtf(var + 1e-5f);
    z[r] = (z[r] - m) * iv * g + b;
  }
  __syncthreads();
}

// ===========================================================================
// ============ multi-kernel path ============================================
// ===========================================================================

// xw: y = x @ W_raw over SOURCE rows [t0, t0+tc) -- 6x fewer FLOPs than the
// old per-(token,s) embed GEMM. Same sequential-f FMA order -> identical
// numerics. 16 rows/block, 256 threads (thread = output col). ~35 regs.
__global__ __launch_bounds__(256) void mk_xw(
    const float* __restrict__ x, const float* __restrict__ W_raw,
    float* __restrict__ y, int t0)
{
  __shared__ float xbuf[16][128];     // 8 KB
  const int tid = threadIdx.x;
  const int row0 = t0 + blockIdx.x * 16;

  #pragma unroll
  for (int k = 0; k < 8; ++k) {
    int idx = tid + k*256;
    xbuf[idx >> 7][idx & 127] = x[(size_t)(row0 + (idx >> 7))*128 + (idx & 127)];
  }
  __syncthreads();

  float z[16];
  #pragma unroll
  for (int r = 0; r < 16; ++r) z[r] = 0.f;
  #pragma unroll 2
  for (int f4 = 0; f4 < 32; ++f4) {
    float w0 = W_raw[(f4*4+0)*256 + tid];
    float w1 = W_raw[(f4*4+1)*256 + tid];
    float w2 = W_raw[(f4*4+2)*256 + tid];
    float w3 = W_raw[(f4*4+3)*256 + tid];
    #pragma unroll
    for (int r = 0; r < 16; ++r) {
      float4 xv = *(const float4*)(&xbuf[r][f4*4]);
      z[r] += xv.x*w0 + xv.y*w1 + xv.z*w2 + xv.w*w3;
    }
  }
  #pragma unroll
  for (int r = 0; r < 16; ++r)
    y[(size_t)(blockIdx.x*16 + r)*256 + tid] = z[r];
}

// embed2: gather y rows per (token,s), add embeddings, LN, write h0.
// res path unchanged (x @ W_res for first 256 tokens).
__global__ __launch_bounds__(256) void mk_embed2(
    const float* __restrict__ x, const float* __restrict__ y,
    const float* __restrict__ b_raw,
    const float* __restrict__ wl_emb, const float* __restrict__ pos_emb,
    const float* __restrict__ hop_emb,
    const float* __restrict__ ln_g, const float* __restrict__ ln_b,
    const float* __restrict__ W_res, const float* __restrict__ b_res,
    __hip_bfloat16* __restrict__ h0, float* __restrict__ res, int t0)
{
  __shared__ float xbuf[24][128];     // 12 KB (res path only)
  __shared__ float zb[24][256];       // 24 KB
  __shared__ float part[2][24][8];
  __shared__ float stat[24][2];
  const int tid = threadIdx.x;
  const int bt  = blockIdx.x;

  {
    float br  = b_raw[tid];
    float wl  = wl_emb[tid];
    float hp0 = hop_emb[5*256 + tid];
    float hp1 = hop_emb[511*256 + tid];
    float p[6];
    #pragma unroll
    for (int s = 0; s < 6; ++s) p[s] = pos_emb[s*256 + tid];
    #pragma unroll
    for (int r = 0; r < NROW; ++r) {
      int t = t0 + bt*4 + (r / 6), s = r % 6;
      int g = t >> 7, i = t & 127;
      int node;
      if (s < 2) node = i;
      else { int j = s - 2; node = (j < i) ? j : (j + 1); }
      float yv = y[(size_t)(g*128 + node - t0)*256 + tid];
      zb[r][tid] = yv + br + p[s] + wl + ((s < 2) ? hp0 : hp1);
    }
  }
  __syncthreads();

  if (tid < 192) {
    int row = tid >> 3, seg = tid & 7;
    float s1 = 0.f, s2 = 0.f;
    #pragma unroll
    for (int i = 0; i < 32; ++i) {
      int col = seg*32 + ((i + tid) & 31);
      float v = zb[row][col];
      s1 += v; s2 += v*v;
    }
    part[0][row][seg] = s1; part[1][row][seg] = s2;
  }
  __syncthreads();
  if (tid < 24) {
    float S1 = 0.f, S2 = 0.f;
    #pragma unroll
    for (int k = 0; k < 8; ++k) { S1 += part[0][tid][k]; S2 += part[1][tid][k]; }
    float m = S1 * (1.0f/256.0f);
    float var = S2 * (1.0f/256.0f) - m*m;
    stat[tid][0] = m; stat[tid][1] = rsqrtf(var + 1e-5f);
  }
  __syncthreads();
  {
    float g = ln_g[tid], b = ln_b[tid];
    #pragma unroll
    for (int r = 0; r < NROW; ++r) {
      float v = (zb[r][tid] - stat[r][0]) * stat[r][1] * g + b;
      h0[(size_t)(bt*24 + r)*256 + tid] = f2bf(v);
    }
  }

  if (t0 + bt*4 < 256) {
    __syncthreads();
    for (int idx = tid; idx < 24*128; idx += 256) {
      int tt = idx / 768, rem = idx % 768;
      int s = rem >> 7, f = rem & 127;
      int t = t0 + bt*4 + tt;
      xbuf[tt*6+s][f] = x[(t*128 + s)*128 + f];
    }
    __syncthreads();
    float resv[NROW];
    float brr = b_res[tid];
    #pragma unroll
    for (int r = 0; r < NROW; ++r) resv[r] = brr;
    #pragma unroll 2
    for (int f4 = 0; f4 < 32; ++f4) {
      float w0 = W_res[(f4*4+0)*256 + tid];
      float w1 = W_res[(f4*4+1)*256 + tid];
      float w2 = W_res[(f4*4+2)*256 + tid];
      float w3 = W_res[(f4*4+3)*256 + tid];
      #pragma unroll
      for (int r = 0; r < NROW; ++r) {
        float4 xv = *(const float4*)(&xbuf[r][f4*4]);
        resv[r] += xv.x*w0 + xv.y*w1 + xv.z*w2 + xv.w*w3;
      }
    }
    #pragma unroll
    for (int r = 0; r < NROW; ++r)
      res[(size_t)((t0 + bt*4)*6 + r)*256 + tid] = resv[r];
  }
}

// stage 32x256 bf16 rows into swz LDS -- 256-thread version
__device__ __forceinline__ void stageA(const __hip_bfloat16* __restrict__ src,
                                       int row0, int stride, char* aT, int tid) {
  #pragma unroll
  for (int k = 0; k < 4; ++k) {
    int cid = tid + k*256;
    int row = cid >> 5, cc = cid & 31;
    uint4 v = *(const uint4*)(src + (size_t)(row0 + row)*stride + cc*8);
    *(uint4*)(aT + swz(row, cc*16)) = v;
  }
}
// 512-thread version
__device__ __forceinline__ void stageA512(const __hip_bfloat16* __restrict__ src,
                                          int row0, int stride, char* aT, int tid) {
  #pragma unroll
  for (int k = 0; k < 2; ++k) {
    int cid = tid + k*512;
    int row = cid >> 5, cc = cid & 31;
    uint4 v = *(const uint4*)(src + (size_t)(row0 + row)*stride + cc*8);
    *(uint4*)(aT + swz(row, cc*16)) = v;
  }
}

// qkv GEMM: 256 threads, M=32, N=768.
__global__ __launch_bounds__(256) void mk_qkv(
    const __hip_bfloat16* __restrict__ h, const __hip_bfloat16* __restrict__ Wf,
    const float* __restrict__ bqkv_l, __hip_bfloat16* __restrict__ qkv)
{
  __shared__ __align__(16) char aT[16384];
  const int tid = threadIdx.x;
  const int lane = tid & 63, wid = tid >> 6;
  const int l15 = lane & 15, l4 = lane >> 4;
  const int row0 = blockIdx.x * 32;

  stageA(h, row0, 256, aT, tid);
  __syncthreads();

  auto lA = [&](int kh, bfv8 (&a)[2][4]) {
    #pragma unroll
    for (int k = 0; k < 4; ++k) {
      a[0][k] = *(const bfv8*)(aT + swz(l15,      (kh*4 + k)*64 + l4*16));
      a[1][k] = *(const bfv8*)(aT + swz(16 + l15, (kh*4 + k)*64 + l4*16));
    }
  };

  #pragma unroll 1
  for (int sub = 0; sub < 3; ++sub) {
    f32x4 C[4][2];
    gemm_ks<8>(Wf + (unsigned)(sub*16 + wid)*8u*512u + lane*8, lA, C);
    #pragma unroll
    for (int i = 0; i < 4; ++i) {
      int col = sub*256 + (wid + i*4)*16 + l15;
      float bb = bqkv_l[col];
      #pragma unroll
      for (int j = 0; j < 4; ++j) {
        qkv[(size_t)(row0 + l4*4 + j)*768 + col]      = f2bf(C[i][0][j] + bb);
        qkv[(size_t)(row0 + 16 + l4*4 + j)*768 + col] = f2bf(C[i][1][j] + bb);
      }
    }
  }
}

// attention: 256 threads, VALU; 32 tokens/block, thread = (token, head).
__global__ __launch_bounds__(256) void mk_attn(__hip_bfloat16* __restrict__ qkv)
{
  const int tid = threadIdx.x;
  const int tl = tid >> 3, hh = tid & 7;
  const size_t rowbase = (size_t)(blockIdx.x*32 + tl)*6;
  const int cb = hh*32;

  #pragma unroll 1
  for (int q = 0; q < 6; ++q) {
    const __hip_bfloat16* qr = qkv + (rowbase + q)*768 + cb;
    bfv8 qv[4];
    #pragma unroll
    for (int p4 = 0; p4 < 4; ++p4) qv[p4] = *(const bfv8*)(qr + p4*8);
    float a[6]; float mx = -1e30f;
    #pragma unroll
    for (int sp = 0; sp < 6; ++sp) {
      const __hip_bfloat16* kr = qkv + (rowbase + sp)*768 + 256 + cb;
      float s = 0.f;
      #pragma unroll
      for (int p4 = 0; p4 < 4; ++p4) {
        bfv8 kv = *(const bfv8*)(kr + p4*8);
        #pragma unroll
        for (int j = 0; j < 8; ++j) s += bfs2f(qv[p4][j]) * bfs2f(kv[j]);
      }
      a[sp] = s * 0.17677669529663687f;
      mx = fmaxf(mx, a[sp]);
    }
    float sum = 0.f;
    #pragma unroll
    for (int sp = 0; sp < 6; ++sp) { a[sp] = __expf(a[sp] - mx); sum += a[sp]; }
    float inv = 1.f / sum;
    #pragma unroll
    for (int sp = 0; sp < 6; ++sp) a[sp] *= inv;
    float oc[32];
    #pragma unroll
    for (int j = 0; j < 32; ++j) oc[j] = 0.f;
    #pragma unroll
    for (int sp = 0; sp < 6; ++sp) {
      const __hip_bfloat16* vr = qkv + (rowbase + sp)*768 + 512 + cb;
      float asp = a[sp];
      #pragma unroll
      for (int p4 = 0; p4 < 4; ++p4) {
        bfv8 vv = *(const bfv8*)(vr + p4*8);
        #pragma unroll
        for (int j = 0; j < 8; ++j) oc[p4*8 + j] += asp * bfs2f(vv[j]);
      }
    }
    __hip_bfloat16* orow = qkv + (rowbase + q)*768 + cb;
    #pragma unroll
    for (int p4 = 0; p4 < 4; ++p4) {
      __align__(16) __hip_bfloat16 ob[8];
      #pragma unroll
      for (int j = 0; j < 8; ++j) ob[j] = f2bf(oc[p4*8 + j]);
      *(uint4*)(orow + p4*8) = *(const uint4*)ob;
    }
  }
}

// Wo GEMM + residual + LN1: 512 threads, spill-proof gemm_ksq.
// LDS overlay: zb (fp32 [32][256], 32K) reuses aT's region. 37120 B.
__global__ __launch_bounds__(512) void mk_wo_ln(
    const __hip_bfloat16* __restrict__ qkv /* o at stride 768 */,
    const __hip_bfloat16* __restrict__ h,
    const float* __restrict__ res,
    const __hip_bfloat16* __restrict__ Wf, const float* __restrict__ bo_l,
    const float* __restrict__ gln, const float* __restrict__ bln,
    __hip_bfloat16* __restrict__ h1, int t0)
{
  __shared__ __align__(16) char smem[37120];
  char* aT = smem;                                        // [0, 16K)
  float (*zb)[256]      = (float (*)[256])smem;           // [0, 32K) after GEMM
  float (*part)[32][16] = (float (*)[32][16])(smem + 32768);
  float (*stat)[2]      = (float (*)[2])(smem + 32768 + 4096);
  const int tid = threadIdx.x;
  const int lane = tid & 63, wid = tid >> 6;      // wid 0..7
  const int l15 = lane & 15, l4 = lane >> 4;
  const int row0 = blockIdx.x * 32;

  stageA512(qkv, row0, 768, aT, tid);
  __syncthreads();

  auto lAq = [&](int q, bfv8 (&a)[2][2]) {
    #pragma unroll
    for (int k = 0; k < 2; ++k) {
      a[0][k] = *(const bfv8*)(aT + swz(l15,      (q*2 + k)*64 + l4*16));
      a[1][k] = *(const bfv8*)(aT + swz(16 + l15, (q*2 + k)*64 + l4*16));
    }
  };

  {
    f32x4 C[2][2];
    gemm_ksq<8>(Wf + (unsigned)wid*8u*512u + lane*8, lAq, C);
    __syncthreads();    // all aT reads done before zb overlays it
    #pragma unroll
    for (int i = 0; i < 2; ++i) {
      int col = (wid + i*8)*16 + l15;
      #pragma unroll
      for (int j = 0; j < 4; ++j) {
        zb[l4*4 + j][col]      = C[i][0][j];
        zb[16 + l4*4 + j][col] = C[i][1][j];
      }
    }
  }
  __syncthreads();

  #pragma unroll 4
  for (int it = 0; it < 16; ++it) {
    int idx = tid + it*512, row = idx >> 8, col = idx & 255;
    float v = zb[row][col] + bf2f(h[(size_t)(row0 + row)*256 + col]) + bo_l[col];
    int grow = t0*6 + row0 + row;
    if (grow < 1536) v += res[(size_t)grow*256 + col];
    zb[row][col] = v;
  }
  __syncthreads();

  {
    int row = tid >> 4, seg = tid & 15;
    float s1 = 0.f, s2 = 0.f;
    #pragma unroll
    for (int i = 0; i < 16; ++i) {
      int col = seg*16 + ((i + tid) & 15);
      float v = zb[row][col];
      s1 += v; s2 += v*v;
    }
    part[0][row][seg] = s1; part[1][row][seg] = s2;
  }
  __syncthreads();
  if (tid < 32) {
    float S1 = 0.f, S2 = 0.f;
    #pragma unroll
    for (int k = 0; k < 16; ++k) { S1 += part[0][tid][k]; S2 += part[1][tid][k]; }
    float m = S1 * (1.0f/256.0f);
    float var = S2 * (1.0f/256.0f) - m*m;
    stat[tid][0] = m; stat[tid][1] = rsqrtf(var + 1e-5f);
  }
  __syncthreads();
  #pragma unroll 4
  for (int it = 0; it < 16; ++it) {
    int idx = tid + it*512, row = idx >> 8, col = idx & 255;
    float v = (zb[row][col] - stat[row][0]) * stat[row][1] * gln[col] + bln[col];
    h1[(size_t)(row0 + row)*256 + col] = f2bf(v);
  }
}

// FFN fused + residual + LN2: 512 threads. ff accumulator in REGISTERS
// (Cff[2][2], persistent across the 4 ch chunks). 37120 B LDS.
__global__ __launch_bounds__(512) void mk_ffn(
    const __hip_bfloat16* __restrict__ h1,
    const __hip_bfloat16* __restrict__ W1f, const __hip_bfloat16* __restrict__ W2f,
    const float* __restrict__ b1_l, const float* __restrict__ b2_l,
    const float* __restrict__ gln, const float* __restrict__ bln,
    const float* __restrict__ res, __hip_bfloat16* __restrict__ hout,
    float* __restrict__ outp, int t0)
{
  __shared__ __align__(16) char smem[37120];
  char* aT = smem;                                            // [0, 16K)
  char* gT = smem + 16384;                                    // [16K, 32K)
  float (*zf)[256]      = (float (*)[256])smem;               // [0, 32K) after GEMMs
  float (*part)[32][16] = (float (*)[32][16])(smem + 32768);
  float (*stat)[2]      = (float (*)[2])(smem + 32768 + 4096);
  const int tid = threadIdx.x;
  const int lane = tid & 63, wid = tid >> 6;      // wid 0..7
  const int l15 = lane & 15, l4 = lane >> 4;
  const int row0 = blockIdx.x * 32;

  stageA512(h1, row0, 256, aT, tid);
  __syncthreads();

  auto lAq = [&](int q, bfv8 (&a)[2][2]) {
    #pragma unroll
    for (int k = 0; k < 2; ++k) {
      a[0][k] = *(const bfv8*)(aT + swz(l15,      (q*2 + k)*64 + l4*16));
      a[1][k] = *(const bfv8*)(aT + swz(16 + l15, (q*2 + k)*64 + l4*16));
    }
  };
  auto lGq = [&](int q, bfv8 (&a)[2][2]) {
    #pragma unroll
    for (int k = 0; k < 2; ++k) {
      a[0][k] = *(const bfv8*)(gT + swz(l15,      (q*2 + k)*64 + l4*16));
      a[1][k] = *(const bfv8*)(gT + swz(16 + l15, (q*2 + k)*64 + l4*16));
    }
  };

  f32x4 Cff[2][2];
  #pragma unroll
  for (int i = 0; i < 2; ++i) {
    Cff[i][0] = (f32x4){0.f,0.f,0.f,0.f};
    Cff[i][1] = (f32x4){0.f,0.f,0.f,0.f};
  }

  #pragma unroll 1
  for (int ch = 0; ch < 4; ++ch) {
    {
      f32x4 C[2][2];
      gemm_ksq<8>(W1f + (unsigned)(ch*16 + wid)*8u*512u + lane*8, lAq, C);
      #pragma unroll
      for (int i = 0; i < 2; ++i) {
        int colR = (wid + i*8)*16 + l15;
        float bb = b1_l[ch*256 + colR];
        int col2 = colR*2;
        #pragma unroll
        for (int j = 0; j < 4; ++j) {
          *(__hip_bfloat16*)(gT + swz(l4*4 + j, col2))      = f2bf(gelu_f(C[i][0][j] + bb));
          *(__hip_bfloat16*)(gT + swz(16 + l4*4 + j, col2)) = f2bf(gelu_f(C[i][1][j] + bb));
        }
      }
    }
    __syncthreads();   // g visible
    gemm_ksq_acc<32>(W2f + (unsigned)(wid*32 + ch*8)*512u + lane*8, lGq, Cff);
    __syncthreads();   // g reads done; after ch=3 this also guards zf overlay
  }

  // Cff + residual + bias -> zf (fp32, overlays aT/gT which are now dead)
  #pragma unroll
  for (int i = 0; i < 2; ++i) {
    int col = (wid + i*8)*16 + l15;
    float b2v = b2_l[col];
    #pragma unroll
    for (int j = 0; j < 4; ++j) {
      int r0 = l4*4 + j, r1 = 16 + l4*4 + j;
      float v0 = Cff[i][0][j] + bf2f(h1[(size_t)(row0 + r0)*256 + col]) + b2v;
      float v1 = Cff[i][1][j] + bf2f(h1[(size_t)(row0 + r1)*256 + col]) + b2v;
      int g0 = t0*6 + row0 + r0, g1 = t0*6 + row0 + r1;
      if (g0 < 1536) v0 += res[(size_t)g0*256 + col];
      if (g1 < 1536) v1 += res[(size_t)g1*256 + col];
      zf[r0][col] = v0;
      zf[r1][col] = v1;
    }
  }
  __syncthreads();
  {
    int row = tid >> 4, seg = tid & 15;
    float s1 = 0.f, s2 = 0.f;
    #pragma unroll
    for (int i = 0; i < 16; ++i) {
      int col = seg*16 + ((i + tid) & 15);
      float v = zf[row][col];
      s1 += v; s2 += v*v;
    }
    part[0][row][seg] = s1; part[1][row][seg] = s2;
  }
  __syncthreads();
  if (tid < 32) {
    float S1 = 0.f, S2 = 0.f;
    #pragma unroll
    for (int k = 0; k < 16; ++k) { S1 += part[0][tid][k]; S2 += part[1][tid][k]; }
    float m = S1 * (1.0f/256.0f);
    float var = S2 * (1.0f/256.0f) - m*m;
    stat[tid][0] = m; stat[tid][1] = rsqrtf(var + 1e-5f);
  }
  __syncthreads();
  #pragma unroll 4
  for (int it = 0; it < 16; ++it) {
    int idx = tid + it*512, row = idx >> 8, col = idx & 255;
    float v = (zf[row][col] - stat[row][0]) * stat[row][1] * gln[col] + bln[col];
    hout[(size_t)(row0 + row)*256 + col] = f2bf(v);
    if (outp && ((row0 + row) % 6 == 0)) {
      int gtok = t0 + (row0 + row) / 6;
      outp[(size_t)gtok*256 + col] = v;
    }
  }
}

// ===========================================================================
// ============ round-10 fused champion (fallback) ===========================
// ===========================================================================
__global__ __launch_bounds__(256, 2) void gb_mfma_kernel(
    const float* __restrict__ x,
    const float* __restrict__ W_raw, const float* __restrict__ b_raw,
    const float* __restrict__ wl_emb, const float* __restrict__ pos_emb,
    const float* __restrict__ hop_emb,
    const float* __restrict__ ln_g, const float* __restrict__ ln_b,
    const float* __restrict__ bqkv, const float* __restrict__ bo,
    const float* __restrict__ n1g,  const float* __restrict__ n1b,
    const float* __restrict__ b1,   const float* __restrict__ b2,
    const float* __restrict__ n2g,  const float* __restrict__ n2b,
    const float* __restrict__ W_res, const float* __restrict__ b_res,
    const __hip_bfloat16* __restrict__ wf,
    float* __restrict__ out)
{
  __shared__ __align__(16) char smem[75392];
  char* hsb = smem;
  char* uA  = smem + 16384;
  char* uB  = smem + 53632;
  float (*attw)[24][6] = (float (*)[24][6])(smem + 70016);
  float* redbuf = (float*)(smem + 74624);

  __hip_bfloat16 (*qkvs)[776] = (__hip_bfloat16 (*)[776])uA;
  float (*fbuf)[264] = (float (*)[264])uA;
  float (*xbuf)[128] = (float (*)[128])uA;

  const int tid  = threadIdx.x;
  const int bt   = blockIdx.x;
  const int lane = tid & 63, wid = tid >> 6;
  const int l15  = lane & 15, l4 = lane >> 4;

  auto mkA = [l15, l4](const char* buf) {
    return [buf, l15, l4](int kh, bfv8 (&a)[2][4]) {
      #pragma unroll
      for (int k = 0; k < 4; ++k) {
        a[0][k] = *(const bfv8*)(buf + swz(l15,      (kh*4 + k)*64 + l4*16));
        a[1][k] = *(const bfv8*)(buf + swz(16 + l15, (kh*4 + k)*64 + l4*16));
      }
    };
  };

  {
    uint4 zz = {0u,0u,0u,0u};
    *(uint4*)(hsb + 24*512 + tid*16) = zz;
    *(uint4*)(uB  + 24*512 + tid*16) = zz;
  }

  for (int idx = tid; idx < TB*6*128; idx += 256) {
    int tt = idx / 768, rem = idx % 768;
    int s = rem >> 7, f = rem & 127;
    int t = bt*TB + tt, g = t >> 7, i = t & 127;
    int node;
    if (s < 2) node = i;
    else { int j = s - 2; node = (j < i) ? j : (j + 1); }
    xbuf[tt*6+s][f] = x[(g*128 + node)*128 + f];
  }
  __syncthreads();

  {
    float z[NROW];
    #pragma unroll
    for (int r = 0; r < NROW; ++r) z[r] = 0.f;
    #pragma unroll 2
    for (int f4 = 0; f4 < 32; ++f4) {
      float w0 = W_raw[(f4*4+0)*256 + tid];
      float w1 = W_raw[(f4*4+1)*256 + tid];
      float w2 = W_raw[(f4*4+2)*256 + tid];
      float w3 = W_raw[(f4*4+3)*256 + tid];
      #pragma unroll
      for (int r = 0; r < NROW; ++r) {
        float4 xv = *(const float4*)(&xbuf[r][f4*4]);
        z[r] += xv.x*w0 + xv.y*w1 + xv.z*w2 + xv.w*w3;
      }
    }
    float br  = b_raw[tid];
    float wl  = wl_emb[tid];
    float hp0 = hop_emb[5*256 + tid];
    float hp1 = hop_emb[511*256 + tid];
    float p[6];
    #pragma unroll
    for (int s = 0; s < 6; ++s) p[s] = pos_emb[s*256 + tid];
    #pragma unroll
    for (int r = 0; r < NROW; ++r) {
      int s = r % 6;
      z[r] += br + p[s] + wl + ((s < 2) ? hp0 : hp1);
    }
    ln24_norm(z, redbuf, ln_g[tid], ln_b[tid], tid);
    #pragma unroll
    for (int r = 0; r < NROW; ++r)
      *(__hip_bfloat16*)(hsb + swz(r, tid*2)) = f2bf(z[r]);
  }

  unsigned resp[12];
  #pragma unroll
  for (int k = 0; k < 12; ++k) resp[k] = 0u;
  if (bt < 64) {
    __syncthreads();
    for (int idx = tid; idx < TB*6*128; idx += 256) {
      int tt = idx / 768, rem = idx % 768;
      int s = rem >> 7, f = rem & 127;
      int t = bt*TB + tt;
      xbuf[tt*6+s][f] = x[(t*128 + s)*128 + f];
    }
    __syncthreads();
    float resv[NROW];
    float brr = b_res[tid];
    #pragma unroll
    for (int r = 0; r < NROW; ++r) resv[r] = brr;
    #pragma unroll 2
    for (int f4 = 0; f4 < 32; ++f4) {
      float w0 = W_res[(f4*4+0)*256 + tid];
      float w1 = W_res[(f4*4+1)*256 + tid];
      float w2 = W_res[(f4*4+2)*256 + tid];
      float w3 = W_res[(f4*4+3)*256 + tid];
      #pragma unroll
      for (int r = 0; r < NROW; ++r) {
        float4 xv = *(const float4*)(&xbuf[r][f4*4]);
        resv[r] += xv.x*w0 + xv.y*w1 + xv.z*w2 + xv.w*w3;
      }
    }
    #pragma unroll
    for (int k = 0; k < 12; ++k) {
      unsigned lo = __float_as_uint(resv[2*k])   >> 16;
      unsigned hi = __float_as_uint(resv[2*k+1]) & 0xffff0000u;
      resp[k] = hi | lo;
    }
  }

  float z[NROW];

  #pragma unroll 1
  for (int l = 0; l < 4; ++l) {
    const __hip_bfloat16* WQf = wf + OWQ + (unsigned)l*196608u;
    const __hip_bfloat16* WOf = wf + OWO + (unsigned)l*65536u;
    const __hip_bfloat16* W1f = wf + OW1 + (unsigned)l*262144u;
    const __hip_bfloat16* W2f = wf + OW2 + (unsigned)l*262144u;

    __syncthreads();

    {
      auto lA = mkA(hsb);
      #pragma unroll 1
      for (int sub = 0; sub < 3; ++sub) {
        f32x4 C[4][2];
        gemm_ks<8>(WQf + (unsigned)(sub*16 + wid)*8u*512u + lane*8, lA, C);
        #pragma unroll
        for (int i = 0; i < 4; ++i) {
          int gcol = sub*256 + (wid + i*4)*16 + l15;
          float bbv = bqkv[l*768 + gcol];
          #pragma unroll
          for (int j = 0; j < 4; ++j) {
            qkvs[l4*4 + j][gcol] = f2bf(C[i][0][j] + bbv);
            int r1 = 16 + l4*4 + j;
            if (r1 < NROW) qkvs[r1][gcol] = f2bf(C[i][1][j] + bbv);
          }
        }
      }
    }
    __syncthreads();

    if (tid < 192) {
      int hh = tid / 24, r = tid % 24;
      int tt6 = (r / 6) * 6;
      bfv8 qv[4];
      #pragma unroll
      for (int p4 = 0; p4 < 4; ++p4) qv[p4] = *(const bfv8*)(&qkvs[r][hh*32 + p4*8]);
      float sc[6];
      #pragma unroll
      for (int sp = 0; sp < 6; ++sp) {
        float s = 0.f;
        #pragma unroll
        for (int p4 = 0; p4 < 4; ++p4) {
          bfv8 kv = *(const bfv8*)(&qkvs[tt6 + sp][256 + hh*32 + p4*8]);
          #pragma unroll
          for (int j = 0; j < 8; ++j) s += bfs2f(qv[p4][j]) * bfs2f(kv[j]);
        }
        sc[sp] = s * 0.17677669529663687f;
      }
      float mx = sc[0];
      #pragma unroll
      for (int sp = 1; sp < 6; ++sp) mx = fmaxf(mx, sc[sp]);
      float sum = 0.f;
      #pragma unroll
      for (int sp = 0; sp < 6; ++sp) { sc[sp] = __expf(sc[sp] - mx); sum += sc[sp]; }
      float inv = 1.f / sum;
      #pragma unroll
      for (int sp = 0; sp < 6; ++sp) attw[hh][r][sp] = sc[sp] * inv;
    }
    __syncthreads();

    {
      int hh = tid >> 5, c = tid & 31;
      int col2 = (hh*32 + c)*2;
      #pragma unroll
      for (int tt = 0; tt < 4; ++tt) {
        float vv[6];
        #pragma unroll
        for (int sp = 0; sp < 6; ++sp) vv[sp] = bf2f(qkvs[tt*6 + sp][512 + hh*32 + c]);
        #pragma unroll
        for (int q = 0; q < 6; ++q) {
          float o = 0.f;
          #pragma unroll
          for (int sp = 0; sp < 6; ++sp) o += attw[hh][tt*6 + q][sp] * vv[sp];
          *(__hip_bfloat16*)(uB + swz(tt*6 + q, col2)) = f2bf(o);
        }
      }
    }
    __syncthreads();

    {
      f32x4 C[4][2];
      gemm_ks<8>(WOf + (unsigned)wid*8u*512u + lane*8, mkA(uB), C);
      #pragma unroll
      for (int i = 0; i < 4; ++i) {
        int col = (wid + i*4)*16 + l15;
        #pragma unroll
        for (int j = 0; j < 4; ++j) {
          fbuf[l4*4 + j][col] = C[i][0][j];
          int r1 = 16 + l4*4 + j;
          if (r1 < NROW) fbuf[r1][col] = C[i][1][j];
        }
      }
    }
    __syncthreads();

    {
      float bov = bo[l*256 + tid];
      #pragma unroll
      for (int r = 0; r < NROW; ++r)
        z[r] = bf2f(*(const __hip_bfloat16*)(hsb + swz(r, tid*2)))
             + unpk(resp[r >> 1], r & 1) + fbuf[r][tid] + bov;
    }
    #pragma unroll
    for (int k = 0; k < 12; ++k) *(unsigned*)(uB + (k*256 + tid)*4) = 0u;
    ln24_norm(z, redbuf, n1g[l*256 + tid], n1b[l*256 + tid], tid);
    #pragma unroll
    for (int r = 0; r < NROW; ++r)
      *(__hip_bfloat16*)(hsb + swz(r, tid*2)) = f2bf(z[r]);
    {
      uint4 zz = {0u,0u,0u,0u};
      *(uint4*)(uA + 24*512 + tid*16) = zz;
      *(uint4*)(uA + 16384 + 24*512 + tid*16) = zz;
    }
    __syncthreads();

    {
      auto lAh = mkA(hsb);
      #pragma unroll 1
      for (int ch = 0; ch < 4; ++ch) {
        char* gb = uA + (ch & 1)*16384;
        {
          f32x4 C[4][2];
          gemm_ks<8>(W1f + (unsigned)(ch*128 + wid*8)*512u + lane*8, lAh, C);
          #pragma unroll
          for (int i = 0; i < 4; ++i) {
            float bbv = b1[l*1024 + ch*256 + (wid + i*4)*16 + l15];
            int col2 = ((wid + i*4)*16 + l15)*2;
            #pragma unroll
            for (int j = 0; j < 4; ++j) {
              *(__hip_bfloat16*)(gb + swz(l4*4 + j, col2)) = f2bf(gelu_f(C[i][0][j] + bbv));
              int r1 = 16 + l4*4 + j;
              if (r1 < NROW)
                *(__hip_bfloat16*)(gb + swz(r1, col2)) = f2bf(gelu_f(C[i][1][j] + bbv));
            }
          }
        }
        __syncthreads();
        {
          f32x4 C[4][2];
          gemm_ks<32>(W2f + (unsigned)(wid*32 + ch*8)*512u + lane*8, mkA(gb), C);
          #pragma unroll
          for (int i = 0; i < 4; ++i) {
            int col2 = ((wid + i*4)*16 + l15)*2;
            #pragma unroll
            for (int j = 0; j < 4; ++j) {
              {
                __hip_bfloat16* pp = (__hip_bfloat16*)(uB + (l4*4 + j)*512 + col2);
                *pp = f2bf(bf2f(*pp) + C[i][0][j]);
              }
              int r1 = 16 + l4*4 + j;
              if (r1 < NROW) {
                __hip_bfloat16* pp = (__hip_bfloat16*)(uB + r1*512 + col2);
                *pp = f2bf(bf2f(*pp) + C[i][1][j]);
              }
            }
          }
        }
      }
    }
    __syncthreads();

    {
      float b2v = b2[l*256 + tid];
      #pragma unroll
      for (int r = 0; r < NROW; ++r)
        z[r] = bf2f(*(const __hip_bfloat16*)(hsb + swz(r, tid*2)))
             + unpk(resp[r >> 1], r & 1)
             + bf2f(*(const __hip_bfloat16*)(uB + r*512 + tid*2)) + b2v;
    }
    ln24_norm(z, redbuf, n2g[l*256 + tid], n2b[l*256 + tid], tid);
    #pragma unroll
    for (int r = 0; r < NROW; ++r)
      *(__hip_bfloat16*)(hsb + swz(r, tid*2)) = f2bf(z[r]);
  }

  #pragma unroll
  for (int tt = 0; tt < TB; ++tt)
    out[(bt*TB + tt)*256 + tid] = z[tt*6];
}

// ---------------------------------------------------------------------------
// Pure-VALU fallback (round-2 proven).
__global__ __launch_bounds__(256, 2) void gb_fused_fallback(
    const float* __restrict__ x,
    const float* __restrict__ W_raw, const float* __restrict__ b_raw,
    const float* __restrict__ wl_emb, const float* __restrict__ pos_emb,
    const float* __restrict__ hop_emb,
    const float* __restrict__ ln_g, const float* __restrict__ ln_b,
    const float* __restrict__ Wqkv, const float* __restrict__ bqkv,
    const float* __restrict__ Wo,   const float* __restrict__ bo,
    const float* __restrict__ n1g,  const float* __restrict__ n1b,
    const float* __restrict__ W1,   const float* __restrict__ b1,
    const float* __restrict__ W2,   const float* __restrict__ b2,
    const float* __restrict__ n2g,  const float* __restrict__ n2b,
    const float* __restrict__ W_res, const float* __restrict__ b_res,
    float* __restrict__ out)
{
  __shared__ float hs[NROW][256];
  __shared__ __align__(16) char bufraw[NROW*768*2];
  __shared__ float attw[8][NROW][8];
  __shared__ float redbuf[192];

  __hip_bfloat16 (*qkvs)[768] = (__hip_bfloat16 (*)[768])bufraw;
  float (*fbuf)[256] = (float (*)[256])bufraw;
  float (*xbuf)[128] = (float (*)[128])bufraw;

  const int tid = threadIdx.x;
  const int bt  = blockIdx.x;

  for (int idx = tid; idx < TB*6*128; idx += 256) {
    int tt = idx / 768, rem = idx % 768;
    int s = rem >> 7, f = rem & 127;
    int t = bt*TB + tt, g = t >> 7, i = t & 127;
    int node;
    if (s < 2) node = i;
    else { int j = s - 2; node = (j < i) ? j : (j + 1); }
    xbuf[tt*6+s][f] = x[(g*128 + node)*128 + f];
  }
  __syncthreads();

  float z[NROW];
  {
    #pragma unroll
    for (int r = 0; r < NROW; ++r) z[r] = 0.f;
    #pragma unroll 4
    for (int f = 0; f < 128; ++f) {
      float w = W_raw[f*256 + tid];
      #pragma unroll
      for (int r = 0; r < NROW; ++r) z[r] += xbuf[r][f] * w;
    }
    float br  = b_raw[tid];
    float wl  = wl_emb[tid];
    float hp0 = hop_emb[5*256 + tid];
    float hp1 = hop_emb[511*256 + tid];
    float p[6];
    #pragma unroll
    for (int s = 0; s < 6; ++s) p[s] = pos_emb[s*256 + tid];
    #pragma unroll
    for (int r = 0; r < NROW; ++r) {
      int s = r % 6;
      z[r] += br + p[s] + wl + ((s < 2) ? hp0 : hp1);
    }
  }
  ln24_norm(z, redbuf, ln_g[tid], ln_b[tid], tid);
  #pragma unroll
  for (int r = 0; r < NROW; ++r) hs[r][tid] = z[r];

  float resv[NROW];
  #pragma unroll
  for (int r = 0; r < NROW; ++r) resv[r] = 0.f;
  if (bt < 64) {
    __syncthreads();
    for (int idx = tid; idx < TB*6*128; idx += 256) {
      int tt = idx / 768, rem = idx % 768;
      int s = rem >> 7, f = rem & 127;
      int t = bt*TB + tt;
      xbuf[tt*6+s][f] = x[(t*128 + s)*128 + f];
    }
    __syncthreads();
    #pragma unroll 4
    for (int f = 0; f < 128; ++f) {
      float w = W_res[f*256 + tid];
      #pragma unroll
      for (int r = 0; r < NROW; ++r) resv[r] += xbuf[r][f] * w;
    }
    float brr = b_res[tid];
    #pragma unroll
    for (int r = 0; r < NROW; ++r) resv[r] += brr;
  }

  for (int l = 0; l < 4; ++l) {
    const float* Wqkv_l = Wqkv + l*196608;
    const float* bqkv_l = bqkv + l*768;
    const float* Wo_l   = Wo   + l*65536;
    const float* bo_l   = bo   + l*256;
    const float* W1_l   = W1   + l*262144;
    const float* b1_l   = b1   + l*1024;
    const float* W2_l   = W2   + l*262144;
    const float* b2_l   = b2   + l*256;

    __syncthreads();

    for (int cg = 0; cg < 3; ++cg) {
      int col = cg*256 + tid;
      float acc[NROW];
      #pragma unroll
      for (int r = 0; r < NROW; ++r) acc[r] = 0.f;
      #pragma unroll 4
      for (int kk = 0; kk < 256; ++kk) {
        float w = Wqkv_l[kk*768 + col];
        #pragma unroll
        for (int r = 0; r < NROW; ++r) acc[r] += hs[r][kk] * w;
      }
      float bbv = bqkv_l[col];
      #pragma unroll
      for (int r = 0; r < NROW; ++r) qkvs[r][col] = f2bf(acc[r] + bbv);
    }
    __syncthreads();

    #pragma unroll 1
    for (int it = 0; it < 5; ++it) {
      int idx = it*256 + tid;
      if (idx < 1152) {
        int hh = idx / 144, rem = idx % 144;
        int r = rem / 6, sp = rem % 6;
        int tt6 = (r / 6) * 6;
        float sc = 0.f;
        #pragma unroll
        for (int c = 0; c < 32; ++c)
          sc += bf2f(qkvs[r][hh*32 + c]) * bf2f(qkvs[tt6 + sp][256 + hh*32 + c]);
        attw[hh][r][sp] = sc * 0.17677669529663687f;
      }
    }
    __syncthreads();

    if (tid < 192) {
      int hh = tid / 24, r = tid % 24;
      float mx = attw[hh][r][0];
      #pragma unroll
      for (int sp = 1; sp < 6; ++sp) mx = fmaxf(mx, attw[hh][r][sp]);
      float e[6], sum = 0.f;
      #pragma unroll
      for (int sp = 0; sp < 6; ++sp) { e[sp] = expf(attw[hh][r][sp] - mx); sum += e[sp]; }
      float inv = 1.f / sum;
      #pragma unroll
      for (int sp = 0; sp < 6; ++sp) attw[hh][r][sp] = e[sp] * inv;
    }
    __syncthreads();

    float oreg[NROW];
    {
      int hh = tid >> 5, c = tid & 31;
      #pragma unroll
      for (int r = 0; r < NROW; ++r) {
        int tt6 = (r / 6) * 6;
        float o = 0.f;
        #pragma unroll
        for (int sp = 0; sp < 6; ++sp)
          o += attw[hh][r][sp] * bf2f(qkvs[tt6 + sp][512 + hh*32 + c]);
        oreg[r] = o;
      }
    }
    __syncthreads();
    #pragma unroll
    for (int r = 0; r < NROW; ++r) fbuf[r][tid] = oreg[r];
    __syncthreads();

    {
      float bod = bo_l[tid];
      float zz[NROW];
      #pragma unroll
      for (int r = 0; r < NROW; ++r) zz[r] = bod;
      #pragma unroll 4
      for (int kk = 0; kk < 256; ++kk) {
        float w = Wo_l[kk*256 + tid];
        #pragma unroll
        for (int r = 0; r < NROW; ++r) zz[r] += fbuf[r][kk] * w;
      }
      #pragma unroll
      for (int r = 0; r < NROW; ++r) z[r] += zz[r] + resv[r];
    }
    ln24_norm(z, redbuf, n1g[l*256 + tid], n1b[l*256 + tid], tid);
    #pragma unroll
    for (int r = 0; r < NROW; ++r) hs[r][tid] = z[r];
    __syncthreads();

    float ffv[NROW];
    {
      float b2d = b2_l[tid];
      #pragma unroll
      for (int r = 0; r < NROW; ++r) ffv[r] = b2d;
    }
    for (int ch = 0; ch < 4; ++ch) {
      int j = ch*256 + tid;
      float gvv[NROW];
      float b1j = b1_l[j];
      #pragma unroll
      for (int r = 0; r < NROW; ++r) gvv[r] = b1j;
      #pragma unroll 4
      for (int kk = 0; kk < 256; ++kk) {
        float w = W1_l[kk*1024 + j];
        #pragma unroll
        for (int r = 0; r < NROW; ++r) gvv[r] += hs[r][kk] * w;
      }
      __syncthreads();
      #pragma unroll
      for (int r = 0; r < NROW; ++r) fbuf[r][tid] = gelu_f(gvv[r]);
      __syncthreads();
      #pragma unroll 4
      for (int kk = 0; kk < 256; ++kk) {
        float w = W2_l[(ch*256 + kk)*256 + tid];
        #pragma unroll
        for (int r = 0; r < NROW; ++r) ffv[r] += fbuf[r][kk] * w;
      }
    }
    #pragma unroll
    for (int r = 0; r < NROW; ++r) z[r] += ffv[r] + resv[r];
    ln24_norm(z, redbuf, n2g[l*256 + tid], n2b[l*256 + tid], tid);
    #pragma unroll
    for (int r = 0; r < NROW; ++r) hs[r][tid] = z[r];
  }

  __syncthreads();
  #pragma unroll
  for (int tt = 0; tt < TB; ++tt)
    out[(bt*TB + tt)*256 + tid] = hs[tt*6][tid];
}

// ===========================================================================
extern "C" void kernel_launch(void* const* d_in, const int* in_sizes, int n_in,
                              void* d_out, int out_size, void* d_ws, size_t ws_size,
                              hipStream_t stream) {
  (void)in_sizes; (void)n_in; (void)out_size;
  const float* x      = (const float*)d_in[0];
  const float* W_raw  = (const float*)d_in[1];
  const float* b_raw  = (const float*)d_in[2];
  const float* wl_emb = (const float*)d_in[3];
  const float* pos_emb= (const float*)d_in[4];
  const float* hop_emb= (const float*)d_in[5];
  const float* ln_g   = (const float*)d_in[6];
  const float* ln_b   = (const float*)d_in[7];
  const float* Wqkv   = (const float*)d_in[8];
  const float* bqkv   = (const float*)d_in[9];
  const float* Wo     = (const float*)d_in[10];
  const float* bo     = (const float*)d_in[11];
  const float* n1g    = (const float*)d_in[12];
  const float* n1b    = (const float*)d_in[13];
  const float* W1     = (const float*)d_in[14];
  const float* b1     = (const float*)d_in[15];
  const float* W2     = (const float*)d_in[16];
  const float* b2     = (const float*)d_in[17];
  const float* n2g    = (const float*)d_in[18];
  const float* n2b    = (const float*)d_in[19];
  const float* W_res  = (const float*)d_in[20];
  const float* b_res  = (const float*)d_in[21];

  int tc = 0;
  for (int cand = 32768; cand >= 4096; cand >>= 1) {
    size_t need = (size_t)ACTOFF + (size_t)cand * 15360u;
    if (ws_size >= need) { tc = cand; break; }
  }

  if (tc > 0) {
    char* wsb = (char*)d_ws;
    __hip_bfloat16* wf  = (__hip_bfloat16*)wsb;
    float*          res = (float*)(wsb + RESOFF);
    __hip_bfloat16* h0  = (__hip_bfloat16*)(wsb + ACTOFF);
    __hip_bfloat16* h1  = (__hip_bfloat16*)(wsb + ACTOFF + (size_t)tc*6*512);
    __hip_bfloat16* qkv = (__hip_bfloat16*)(wsb + ACTOFF + (size_t)tc*6*1024);
    float* y = (float*)h1;   // y = x@W_raw (tc*1024 B) in h1's region; dead
                             // before mk_wo_ln writes h1 in layer 0.
    float* outp = (float*)d_out;

    gb_prep_kernel<<<1536, 256, 0, stream>>>(Wqkv, Wo, W1, W2, wf);

    int nchunk = 32768 / tc;
    for (int c = 0; c < nchunk; ++c) {
      int t0 = c * tc;
      mk_xw<<<tc/16, 256, 0, stream>>>(x, W_raw, y, t0);
      mk_embed2<<<tc/4, 256, 0, stream>>>(x, y, b_raw, wl_emb, pos_emb,
          hop_emb, ln_g, ln_b, W_res, b_res, h0, res, t0);
      for (int l = 0; l < 4; ++l) {
        mk_qkv<<<tc*6/32, 256, 0, stream>>>(
            h0, wf + OWQ + (unsigned)l*196608u, bqkv + l*768, qkv);
        mk_attn<<<tc/32, 256, 0, stream>>>(qkv);
        mk_wo_ln<<<tc*6/32, 512, 0, stream>>>(
            qkv, h0, res, wf + OWO + (unsigned)l*65536u, bo + l*256,
            n1g + l*256, n1b + l*256, h1, t0);
        mk_ffn<<<tc*6/32, 512, 0, stream>>>(
            h1, wf + OW1 + (unsigned)l*262144u, wf + OW2 + (unsigned)l*262144u,
            b1 + l*1024, b2 + l*256, n2g + l*256, n2b + l*256,
            res, h0, (l == 3) ? outp : (float*)nullptr, t0);
      }
    }
  } else if (ws_size >= (size_t)WS_ELEMS * 2) {
    __hip_bfloat16* wsb = (__hip_bfloat16*)d_ws;
    gb_prep_kernel<<<1536, 256, 0, stream>>>(Wqkv, Wo, W1, W2, wsb);
    gb_mfma_kernel<<<8192, 256, 0, stream>>>(
        x, W_raw, b_raw, wl_emb, pos_emb, hop_emb, ln_g, ln_b,
        bqkv, bo, n1g, n1b, b1, b2, n2g, n2b, W_res, b_res,
        wsb, (float*)d_out);
  } else {
    gb_fused_fallback<<<8192, 256, 0, stream>>>(
        x, W_raw, b_raw, wl_emb, pos_emb, hop_emb, ln_g, ln_b,
        Wqkv, bqkv, Wo, bo, n1g, n1b, W1, b1, W2, b2, n2g, n2b,
        W_res, b_res, (float*)d_out);
  }
}